// Round 1
// baseline (10832.272 us; speedup 1.0000x reference)
//
#include <hip/hip_runtime.h>
#include <math.h>

#define NATOMS 16384
#define NEDGES 524288
#define DIM 128
#define HIDDEN 256
#define NLAYERS 4
#define TE 32      // edges per block in msg kernel
#define HC 64      // hidden-chunk cols held in LDS

__device__ __forceinline__ float silu_f(float x) {
  return x / (1.0f + __expf(-x));
}

// ---------------- embedding: h = mlp2(x, emb) ----------------
__global__ __launch_bounds__(128) void embed_kernel(
    const float* __restrict__ x, const float* __restrict__ W1,
    const float* __restrict__ b1, const float* __restrict__ W2,
    const float* __restrict__ b2, float* __restrict__ h)
{
  int n = blockIdx.x;
  int j = threadIdx.x;  // 0..127
  __shared__ float xs[26];
  __shared__ float hid[128];
  if (j < 26) xs[j] = x[n * 26 + j];
  __syncthreads();
  float acc = b1[j];
  #pragma unroll
  for (int k = 0; k < 26; k++) acc += xs[k] * W1[k * 128 + j];
  hid[j] = silu_f(acc);
  __syncthreads();
  float acc2 = b2[j];
  #pragma unroll 8
  for (int k = 0; k < 128; k++) acc2 += hid[k] * W2[k * 128 + j];
  h[(size_t)n * 128 + j] = acc2;
}

// ---------------- edge RBF features ----------------
__global__ __launch_bounds__(256) void rbf_kernel(
    const float* __restrict__ pos, const int* __restrict__ src,
    const int* __restrict__ dst, float* __restrict__ ef)
{
  int e = blockIdx.x * 256 + threadIdx.x;
  int s = src[e], d = dst[e];
  float dx = pos[d * 3 + 0] - pos[s * 3 + 0];
  float dy = pos[d * 3 + 1] - pos[s * 3 + 1];
  float dz = pos[d * 3 + 2] - pos[s * 3 + 2];
  float dist = sqrtf(dx * dx + dy * dy + dz * dz + 1e-12f);
  float env = (dist < 10.0f)
                  ? 0.5f * (cosf(3.14159265358979f * dist * 0.1f) + 1.0f)
                  : 0.0f;
  float out[16];
  #pragma unroll
  for (int i = 0; i < 16; i++) {
    float c = (10.0f / 15.0f) * (float)i;    // linspace(0,10,16)
    float t = dist - c;
    out[i] = env * __expf(-t * t * 1.28f);   // 1/(2*(10/16)^2) = 1.28
  }
  float4* efp = (float4*)(ef + (size_t)e * 16);
  efp[0] = make_float4(out[0], out[1], out[2], out[3]);
  efp[1] = make_float4(out[4], out[5], out[6], out[7]);
  efp[2] = make_float4(out[8], out[9], out[10], out[11]);
  efp[3] = make_float4(out[12], out[13], out[14], out[15]);
}

// ---------------- fused message MLP + atomic scatter ----------------
// m_in = [h[src], h[dst], ef] (272)  -> silu(@W1 272x256) -> @W2 256x128 -> atomicAdd agg[dst]
__global__ __launch_bounds__(256, 2) void msg_kernel(
    const float* __restrict__ h, const float* __restrict__ ef,
    const int* __restrict__ src, const int* __restrict__ dst,
    const float* __restrict__ W1, const float* __restrict__ b1,
    const float* __restrict__ W2, const float* __restrict__ b2,
    float* __restrict__ agg)
{
  __shared__ float s_in[TE][280];      // 272 used, padded
  __shared__ float s_hid[TE][HC + 4];  // 64-col hidden chunk, padded
  __shared__ int s_src[TE], s_dst[TE];
  int tid = threadIdx.x;
  int e0 = blockIdx.x * TE;

  if (tid < TE) s_src[tid] = src[e0 + tid];
  else if (tid < 2 * TE) s_dst[tid - TE] = dst[e0 + tid - TE];
  __syncthreads();

  // gather m_in tile
  for (int i = tid; i < TE * 272; i += 256) {
    int el = i / 272;
    int c = i - el * 272;
    float v;
    if (c < 128)      v = h[(size_t)s_src[el] * 128 + c];
    else if (c < 256) v = h[(size_t)s_dst[el] * 128 + (c - 128)];
    else              v = ef[(size_t)(e0 + el) * 16 + (c - 256)];
    s_in[el][c] = v;
  }
  __syncthreads();

  // GEMM2 accumulators: 4 edges x 4 cols per thread
  const int cg2 = tid & 31;
  const int eg2 = tid >> 5;
  const int j2 = cg2 * 4;
  const int el2 = eg2 * 4;
  float acc2[4][4];
  {
    float4 bv = *(const float4*)(b2 + j2);
    #pragma unroll
    for (int i = 0; i < 4; i++) {
      acc2[i][0] = bv.x; acc2[i][1] = bv.y; acc2[i][2] = bv.z; acc2[i][3] = bv.w;
    }
  }

  // GEMM1 mapping: 2 edges x 4 cols per thread per chunk
  const int cg1 = tid & 15;
  const int eg1 = tid >> 4;
  const int c1 = cg1 * 4;
  const int el1 = eg1 * 2;

  for (int hc = 0; hc < HIDDEN; hc += HC) {
    float a1[2][4];
    {
      float4 bv = *(const float4*)(b1 + hc + c1);
      #pragma unroll
      for (int i = 0; i < 2; i++) {
        a1[i][0] = bv.x; a1[i][1] = bv.y; a1[i][2] = bv.z; a1[i][3] = bv.w;
      }
    }
    for (int k = 0; k < 272; k += 4) {
      float4 w0 = *(const float4*)(W1 + (size_t)(k + 0) * 256 + hc + c1);
      float4 w1 = *(const float4*)(W1 + (size_t)(k + 1) * 256 + hc + c1);
      float4 w2 = *(const float4*)(W1 + (size_t)(k + 2) * 256 + hc + c1);
      float4 w3 = *(const float4*)(W1 + (size_t)(k + 3) * 256 + hc + c1);
      #pragma unroll
      for (int i = 0; i < 2; i++) {
        float4 a = *(const float4*)&s_in[el1 + i][k];
        a1[i][0] += a.x * w0.x + a.y * w1.x + a.z * w2.x + a.w * w3.x;
        a1[i][1] += a.x * w0.y + a.y * w1.y + a.z * w2.y + a.w * w3.y;
        a1[i][2] += a.x * w0.z + a.y * w1.z + a.z * w2.z + a.w * w3.z;
        a1[i][3] += a.x * w0.w + a.y * w1.w + a.z * w2.w + a.w * w3.w;
      }
    }
    #pragma unroll
    for (int i = 0; i < 2; i++) {
      float4 o;
      o.x = silu_f(a1[i][0]); o.y = silu_f(a1[i][1]);
      o.z = silu_f(a1[i][2]); o.w = silu_f(a1[i][3]);
      *(float4*)&s_hid[el1 + i][c1] = o;
    }
    __syncthreads();

    for (int kk = 0; kk < HC; kk += 4) {
      float4 w0 = *(const float4*)(W2 + (size_t)(hc + kk + 0) * 128 + j2);
      float4 w1 = *(const float4*)(W2 + (size_t)(hc + kk + 1) * 128 + j2);
      float4 w2 = *(const float4*)(W2 + (size_t)(hc + kk + 2) * 128 + j2);
      float4 w3 = *(const float4*)(W2 + (size_t)(hc + kk + 3) * 128 + j2);
      #pragma unroll
      for (int i = 0; i < 4; i++) {
        float4 a = *(const float4*)&s_hid[el2 + i][kk];
        acc2[i][0] += a.x * w0.x + a.y * w1.x + a.z * w2.x + a.w * w3.x;
        acc2[i][1] += a.x * w0.y + a.y * w1.y + a.z * w2.y + a.w * w3.y;
        acc2[i][2] += a.x * w0.z + a.y * w1.z + a.z * w2.z + a.w * w3.z;
        acc2[i][3] += a.x * w0.w + a.y * w1.w + a.z * w2.w + a.w * w3.w;
      }
    }
    __syncthreads();
  }

  #pragma unroll
  for (int i = 0; i < 4; i++) {
    float* p = agg + (size_t)s_dst[el2 + i] * 128 + j2;
    atomicAdd(p + 0, acc2[i][0]);
    atomicAdd(p + 1, acc2[i][1]);
    atomicAdd(p + 2, acc2[i][2]);
    atomicAdd(p + 3, acc2[i][3]);
  }
}

// ---------------- node update MLP (residual), in-place on h ----------------
__global__ __launch_bounds__(256) void upd_kernel(
    float* __restrict__ h, const float* __restrict__ agg,
    const float* __restrict__ W1, const float* __restrict__ b1,
    const float* __restrict__ W2, const float* __restrict__ b2)
{
  __shared__ float s_u[16][260];
  __shared__ float s_hid[16][260];
  int tid = threadIdx.x;
  int n0 = blockIdx.x * 16;
  for (int i = tid; i < 16 * 256; i += 256) {
    int nl = i >> 8, c = i & 255;
    s_u[nl][c] = (c < 128) ? h[(size_t)(n0 + nl) * 128 + c]
                           : agg[(size_t)(n0 + nl) * 128 + (c - 128)];
  }
  __syncthreads();
  float acc[16];
  float bb = b1[tid];
  #pragma unroll
  for (int i = 0; i < 16; i++) acc[i] = bb;
  for (int k = 0; k < 256; k += 4) {
    float w0 = W1[(size_t)(k + 0) * 256 + tid];
    float w1 = W1[(size_t)(k + 1) * 256 + tid];
    float w2 = W1[(size_t)(k + 2) * 256 + tid];
    float w3 = W1[(size_t)(k + 3) * 256 + tid];
    #pragma unroll
    for (int i = 0; i < 16; i++) {
      float4 u = *(const float4*)&s_u[i][k];
      acc[i] += u.x * w0 + u.y * w1 + u.z * w2 + u.w * w3;
    }
  }
  #pragma unroll
  for (int i = 0; i < 16; i++) s_hid[i][tid] = silu_f(acc[i]);
  __syncthreads();
  int j = tid & 127, ng = tid >> 7;  // 2 node-groups of 8
  float acc2[8];
  float b2v = b2[j];
  #pragma unroll
  for (int i = 0; i < 8; i++) acc2[i] = b2v;
  for (int k = 0; k < 256; k += 4) {
    float w0 = W2[(size_t)(k + 0) * 128 + j];
    float w1 = W2[(size_t)(k + 1) * 128 + j];
    float w2 = W2[(size_t)(k + 2) * 128 + j];
    float w3 = W2[(size_t)(k + 3) * 128 + j];
    #pragma unroll
    for (int i = 0; i < 8; i++) {
      float4 u = *(const float4*)&s_hid[ng * 8 + i][k];
      acc2[i] += u.x * w0 + u.y * w1 + u.z * w2 + u.w * w3;
    }
  }
  #pragma unroll
  for (int i = 0; i < 8; i++) {
    int n = n0 + ng * 8 + i;
    h[(size_t)n * 128 + j] += acc2[i];
  }
}

// ---------------- readout: segment mean (batch sorted) ----------------
__global__ __launch_bounds__(128) void readout_sum_kernel(
    const float* __restrict__ h, const int* __restrict__ batch,
    float* __restrict__ gsum, float* __restrict__ gcnt)
{
  int j = threadIdx.x;  // 128
  int n0 = blockIdx.x * 128;
  float acc = 0.f, cacc = 0.f;
  int cur = batch[n0];
  for (int i = 0; i < 128; i++) {
    int b = batch[n0 + i];
    if (b != cur) {
      atomicAdd(&gsum[cur * 128 + j], acc);
      if (j == 0) atomicAdd(&gcnt[cur], cacc);
      acc = 0.f; cacc = 0.f; cur = b;
    }
    acc += h[(size_t)(n0 + i) * 128 + j];
    cacc += 1.f;
  }
  atomicAdd(&gsum[cur * 128 + j], acc);
  if (j == 0) atomicAdd(&gcnt[cur], cacc);
}

__global__ __launch_bounds__(256) void readout_mlp_kernel(
    const float* __restrict__ gsum, const float* __restrict__ gcnt,
    const float* __restrict__ W1, const float* __restrict__ b1,
    const float* __restrict__ W2, const float* __restrict__ b2,
    float* __restrict__ out)
{
  __shared__ float g[8][128];
  __shared__ float hid[8][256];
  int tid = threadIdx.x;
  for (int i = tid; i < 8 * 128; i += 256) {
    int b = i >> 7, c = i & 127;
    g[b][c] = gsum[i] / fmaxf(gcnt[b], 1.0f);
  }
  __syncthreads();
  {
    float bb = b1[tid];
    float a[8];
    #pragma unroll
    for (int b = 0; b < 8; b++) a[b] = bb;
    for (int k = 0; k < 128; k++) {
      float w = W1[k * 256 + tid];
      #pragma unroll
      for (int b = 0; b < 8; b++) a[b] += g[b][k] * w;
    }
    #pragma unroll
    for (int b = 0; b < 8; b++) hid[b][tid] = silu_f(a[b]);
  }
  __syncthreads();
  int j = tid & 63, bg = tid >> 6;  // 4 groups x 2 graphs
  float a0 = b2[j], a1 = b2[j];
  for (int k = 0; k < 256; k++) {
    float w = W2[k * 64 + j];
    a0 += hid[bg * 2 + 0][k] * w;
    a1 += hid[bg * 2 + 1][k] * w;
  }
  out[(bg * 2 + 0) * 64 + j] = a0;
  out[(bg * 2 + 1) * 64 + j] = a1;
}

extern "C" void kernel_launch(void* const* d_in, const int* in_sizes, int n_in,
                              void* d_out, int out_size, void* d_ws, size_t ws_size,
                              hipStream_t stream) {
  const float* pos   = (const float*)d_in[0];
  const float* xfeat = (const float*)d_in[1];
  const int*   eidx  = (const int*)d_in[2];
  const int*   batch = (const int*)d_in[3];
  const float* eW1 = (const float*)d_in[4];
  const float* eb1 = (const float*)d_in[5];
  const float* eW2 = (const float*)d_in[6];
  const float* eb2 = (const float*)d_in[7];
  const float* mW1 = (const float*)d_in[8];
  const float* mb1 = (const float*)d_in[9];
  const float* mW2 = (const float*)d_in[10];
  const float* mb2 = (const float*)d_in[11];
  const float* uW1 = (const float*)d_in[12];
  const float* ub1 = (const float*)d_in[13];
  const float* uW2 = (const float*)d_in[14];
  const float* ub2 = (const float*)d_in[15];
  const float* rW1 = (const float*)d_in[16];
  const float* rb1 = (const float*)d_in[17];
  const float* rW2 = (const float*)d_in[18];
  const float* rb2 = (const float*)d_in[19];

  const int* srcI = eidx;
  const int* dstI = eidx + NEDGES;

  float* ws   = (float*)d_ws;
  float* h    = ws;                                  // N*128
  float* ef   = h + (size_t)NATOMS * 128;            // E*16
  float* agg  = ef + (size_t)NEDGES * 16;            // N*128
  float* gsum = agg + (size_t)NATOMS * 128;          // 8*128
  float* gcnt = gsum + 8 * 128;                      // 8

  embed_kernel<<<NATOMS, 128, 0, stream>>>(xfeat, eW1, eb1, eW2, eb2, h);
  rbf_kernel<<<NEDGES / 256, 256, 0, stream>>>(pos, srcI, dstI, ef);

  for (int l = 0; l < NLAYERS; l++) {
    hipMemsetAsync(agg, 0, (size_t)NATOMS * 128 * sizeof(float), stream);
    msg_kernel<<<NEDGES / TE, 256, 0, stream>>>(
        h, ef, srcI, dstI,
        mW1 + (size_t)l * 272 * 256, mb1 + (size_t)l * 256,
        mW2 + (size_t)l * 256 * 128, mb2 + (size_t)l * 128, agg);
    upd_kernel<<<NATOMS / 16, 256, 0, stream>>>(
        h, agg,
        uW1 + (size_t)l * 256 * 256, ub1 + (size_t)l * 256,
        uW2 + (size_t)l * 256 * 128, ub2 + (size_t)l * 128);
  }

  hipMemsetAsync(gsum, 0, (8 * 128 + 8) * sizeof(float), stream);
  readout_sum_kernel<<<NATOMS / 128, 128, 0, stream>>>(h, batch, gsum, gcnt);
  readout_mlp_kernel<<<1, 256, 0, stream>>>(gsum, gcnt, rW1, rb1, rW2, rb2,
                                            (float*)d_out);
}

// Round 2
// 1773.245 us; speedup vs baseline: 6.1087x; 6.1087x over previous
//
#include <hip/hip_runtime.h>
#include <math.h>

#define NATOMS 16384
#define NEDGES 524288
#define DIM 128
#define HIDDEN 256
#define NLAYERS 4
#define TE 64      // edges per block in msg kernel

typedef __bf16 bf16x8 __attribute__((ext_vector_type(8)));
typedef float f32x4 __attribute__((ext_vector_type(4)));

__device__ __forceinline__ float silu_f(float x) {
  return x / (1.0f + __expf(-x));
}

// ---------------- weight pre-conversion to bf16, transposed [N][K] ----------------
// mW1: (L, 272, 256) -> W1t: (L, 256, 288)  (K zero-padded 272->288)
__global__ __launch_bounds__(256) void conv_w1_kernel(
    const float* __restrict__ W, __bf16* __restrict__ Wt)
{
  int l = blockIdx.y;
  int i = blockIdx.x * 256 + threadIdx.x;  // 0 .. 256*288-1
  int n = i / 288, k = i - n * 288;
  float v = (k < 272) ? W[((size_t)l * 272 + k) * 256 + n] : 0.0f;
  Wt[((size_t)l * 256 + n) * 288 + k] = (__bf16)v;
}

// mW2: (L, 256, 128) -> W2t: (L, 128, 256)
__global__ __launch_bounds__(256) void conv_w2_kernel(
    const float* __restrict__ W, __bf16* __restrict__ Wt)
{
  int l = blockIdx.y;
  int i = blockIdx.x * 256 + threadIdx.x;  // 0 .. 128*256-1
  int n = i / 256, k = i - n * 256;
  Wt[((size_t)l * 128 + n) * 256 + k] = (__bf16)W[((size_t)l * 256 + k) * 128 + n];
}

// ---------------- embedding: h = mlp2(x, emb), writes fp32 + bf16 ----------------
__global__ __launch_bounds__(128) void embed_kernel(
    const float* __restrict__ x, const float* __restrict__ W1,
    const float* __restrict__ b1, const float* __restrict__ W2,
    const float* __restrict__ b2, float* __restrict__ h,
    __bf16* __restrict__ hb)
{
  int n = blockIdx.x;
  int j = threadIdx.x;  // 0..127
  __shared__ float xs[26];
  __shared__ float hid[128];
  if (j < 26) xs[j] = x[n * 26 + j];
  __syncthreads();
  float acc = b1[j];
  #pragma unroll
  for (int k = 0; k < 26; k++) acc += xs[k] * W1[k * 128 + j];
  hid[j] = silu_f(acc);
  __syncthreads();
  float acc2 = b2[j];
  #pragma unroll 8
  for (int k = 0; k < 128; k++) acc2 += hid[k] * W2[k * 128 + j];
  h[(size_t)n * 128 + j] = acc2;
  hb[(size_t)n * 128 + j] = (__bf16)acc2;
}

// ---------------- edge RBF features (bf16 output) ----------------
__global__ __launch_bounds__(256) void rbf_kernel(
    const float* __restrict__ pos, const int* __restrict__ src,
    const int* __restrict__ dst, __bf16* __restrict__ efb)
{
  int e = blockIdx.x * 256 + threadIdx.x;
  int s = src[e], d = dst[e];
  float dx = pos[d * 3 + 0] - pos[s * 3 + 0];
  float dy = pos[d * 3 + 1] - pos[s * 3 + 1];
  float dz = pos[d * 3 + 2] - pos[s * 3 + 2];
  float dist = sqrtf(dx * dx + dy * dy + dz * dz + 1e-12f);
  float env = (dist < 10.0f)
                  ? 0.5f * (cosf(3.14159265358979f * dist * 0.1f) + 1.0f)
                  : 0.0f;
  bf16x8 o0, o1;
  #pragma unroll
  for (int i = 0; i < 16; i++) {
    float c = (10.0f / 15.0f) * (float)i;    // linspace(0,10,16)
    float t = dist - c;
    float v = env * __expf(-t * t * 1.28f);  // 1/(2*(10/16)^2) = 1.28
    if (i < 8) o0[i] = (__bf16)v; else o1[i - 8] = (__bf16)v;
  }
  *(bf16x8*)(efb + (size_t)e * 16 + 0) = o0;
  *(bf16x8*)(efb + (size_t)e * 16 + 8) = o1;
}

// ---------------- fused message MLP (bf16 MFMA) + atomic scatter ----------------
// m_in = [h[src], h[dst], ef] (272, padded 288) -> silu(@W1) -> @W2 -> atomicAdd agg[dst]
// 64 edges/block, 4 waves. Hidden processed in two 128-col halves.
__global__ __launch_bounds__(256, 2) void msg_mfma_kernel(
    const __bf16* __restrict__ hb, const __bf16* __restrict__ efb,
    const int* __restrict__ src, const int* __restrict__ dst,
    const __bf16* __restrict__ W1t, const float* __restrict__ b1,
    const __bf16* __restrict__ W2t, const float* __restrict__ b2,
    float* __restrict__ agg)
{
  __shared__ __bf16 s_a[TE][296];   // stride 296: 148 dwords % 32 = 20 -> 2-way max (free)
  __shared__ __bf16 s_h[TE][136];   // stride 136: 68 dwords % 32 = 4  -> 2-way max (free)
  __shared__ int s_dst[TE];

  int tid = threadIdx.x;
  int e0 = blockIdx.x * TE;

  // ---- gather phase: 4 threads per edge ----
  {
    int e = tid >> 2, t4 = tid & 3;
    int se = src[e0 + e];
    int de = dst[e0 + e];
    if (t4 == 0) s_dst[e] = de;
    bf16x8* arow = (bf16x8*)&s_a[e][0];
    const bf16x8* hs = (const bf16x8*)(hb + (size_t)se * 128);
    const bf16x8* hd = (const bf16x8*)(hb + (size_t)de * 128);
    #pragma unroll
    for (int c = 0; c < 4; c++) {
      arow[t4 + 4 * c] = hs[t4 + 4 * c];            // cols 0..127
      arow[16 + t4 + 4 * c] = hd[t4 + 4 * c];       // cols 128..255
    }
    if (t4 == 0) {
      const bf16x8* ep = (const bf16x8*)(efb + (size_t)(e0 + e) * 16);
      arow[32] = ep[0];                              // cols 256..271
      arow[33] = ep[1];
      float4 z4 = make_float4(0.f, 0.f, 0.f, 0.f);   // zero pad 272..287
      *(float4*)&s_a[e][272] = z4;
      *(float4*)&s_a[e][280] = z4;
    }
  }
  __syncthreads();

  const int wv = tid >> 6;   // wave 0..3 -> owns 32 output cols
  const int ln = tid & 63;
  const int lc = ln & 15;
  const int qd = ln >> 4;

  // GEMM2 accumulators: 4 M-tiles x 2 N-tiles (wave cols = wv*32 .. wv*32+31)
  f32x4 acc2[4][2];
  #pragma unroll
  for (int nt = 0; nt < 2; nt++) {
    float bv = b2[wv * 32 + nt * 16 + lc];
    #pragma unroll
    for (int mt = 0; mt < 4; mt++) {
      acc2[mt][nt][0] = bv; acc2[mt][nt][1] = bv;
      acc2[mt][nt][2] = bv; acc2[mt][nt][3] = bv;
    }
  }

  for (int hf = 0; hf < 2; hf++) {
    // ---- GEMM1: hidden cols [hf*128 + wv*32, +32), K=288 ----
    f32x4 acc1[4][2];
    #pragma unroll
    for (int nt = 0; nt < 2; nt++) {
      float bv = b1[hf * 128 + wv * 32 + nt * 16 + lc];
      #pragma unroll
      for (int mt = 0; mt < 4; mt++) {
        acc1[mt][nt][0] = bv; acc1[mt][nt][1] = bv;
        acc1[mt][nt][2] = bv; acc1[mt][nt][3] = bv;
      }
    }
    #pragma unroll
    for (int kt = 0; kt < 9; kt++) {
      bf16x8 af[4];
      #pragma unroll
      for (int mt = 0; mt < 4; mt++)
        af[mt] = *(const bf16x8*)&s_a[mt * 16 + lc][kt * 32 + qd * 8];
      bf16x8 bw[2];
      #pragma unroll
      for (int nt = 0; nt < 2; nt++)
        bw[nt] = *(const bf16x8*)(W1t +
                 (size_t)(hf * 128 + wv * 32 + nt * 16 + lc) * 288 + kt * 32 + qd * 8);
      #pragma unroll
      for (int mt = 0; mt < 4; mt++)
        #pragma unroll
        for (int nt = 0; nt < 2; nt++)
          acc1[mt][nt] = __builtin_amdgcn_mfma_f32_16x16x32_bf16(
              af[mt], bw[nt], acc1[mt][nt], 0, 0, 0);
    }

    __syncthreads();  // prev-half GEMM2 readers done with s_h
    // silu -> s_h (C-layout -> A-layout round trip through LDS)
    #pragma unroll
    for (int mt = 0; mt < 4; mt++)
      #pragma unroll
      for (int nt = 0; nt < 2; nt++) {
        int c = wv * 32 + nt * 16 + lc;
        #pragma unroll
        for (int r = 0; r < 4; r++) {
          int m = mt * 16 + qd * 4 + r;
          s_h[m][c] = (__bf16)silu_f(acc1[mt][nt][r]);
        }
      }
    __syncthreads();

    // ---- GEMM2 partial: K = this half's 128 hidden cols ----
    #pragma unroll
    for (int kt = 0; kt < 4; kt++) {
      bf16x8 a2[4];
      #pragma unroll
      for (int mt = 0; mt < 4; mt++)
        a2[mt] = *(const bf16x8*)&s_h[mt * 16 + lc][kt * 32 + qd * 8];
      bf16x8 b2w[2];
      #pragma unroll
      for (int nt = 0; nt < 2; nt++)
        b2w[nt] = *(const bf16x8*)(W2t +
                  (size_t)(wv * 32 + nt * 16 + lc) * 256 + hf * 128 + kt * 32 + qd * 8);
      #pragma unroll
      for (int mt = 0; mt < 4; mt++)
        #pragma unroll
        for (int nt = 0; nt < 2; nt++)
          acc2[mt][nt] = __builtin_amdgcn_mfma_f32_16x16x32_bf16(
              a2[mt], b2w[nt], acc2[mt][nt], 0, 0, 0);
    }
  }

  // ---- epilogue: atomic scatter into agg[dst] ----
  #pragma unroll
  for (int mt = 0; mt < 4; mt++) {
    #pragma unroll
    for (int r = 0; r < 4; r++) {
      int m = mt * 16 + qd * 4 + r;
      int d = s_dst[m];
      float* p = agg + (size_t)d * 128 + wv * 32 + lc;
      atomicAdd(p, acc2[mt][0][r]);
      atomicAdd(p + 16, acc2[mt][1][r]);
    }
  }
}

// ---------------- node update MLP (fp32, residual), writes h + hb ----------------
__global__ __launch_bounds__(256) void upd_kernel(
    float* __restrict__ h, __bf16* __restrict__ hb,
    const float* __restrict__ agg,
    const float* __restrict__ W1, const float* __restrict__ b1,
    const float* __restrict__ W2, const float* __restrict__ b2)
{
  __shared__ float s_u[16][260];
  __shared__ float s_hid[16][260];
  int tid = threadIdx.x;
  int n0 = blockIdx.x * 16;
  for (int i = tid; i < 16 * 256; i += 256) {
    int nl = i >> 8, c = i & 255;
    s_u[nl][c] = (c < 128) ? h[(size_t)(n0 + nl) * 128 + c]
                           : agg[(size_t)(n0 + nl) * 128 + (c - 128)];
  }
  __syncthreads();
  float acc[16];
  float bb = b1[tid];
  #pragma unroll
  for (int i = 0; i < 16; i++) acc[i] = bb;
  for (int k = 0; k < 256; k += 4) {
    float w0 = W1[(size_t)(k + 0) * 256 + tid];
    float w1 = W1[(size_t)(k + 1) * 256 + tid];
    float w2 = W1[(size_t)(k + 2) * 256 + tid];
    float w3 = W1[(size_t)(k + 3) * 256 + tid];
    #pragma unroll
    for (int i = 0; i < 16; i++) {
      float4 u = *(const float4*)&s_u[i][k];
      acc[i] += u.x * w0 + u.y * w1 + u.z * w2 + u.w * w3;
    }
  }
  #pragma unroll
  for (int i = 0; i < 16; i++) s_hid[i][tid] = silu_f(acc[i]);
  __syncthreads();
  int j = tid & 127, ng = tid >> 7;  // 2 node-groups of 8
  float acc2[8];
  float b2v = b2[j];
  #pragma unroll
  for (int i = 0; i < 8; i++) acc2[i] = b2v;
  for (int k = 0; k < 256; k += 4) {
    float w0 = W2[(size_t)(k + 0) * 128 + j];
    float w1 = W2[(size_t)(k + 1) * 128 + j];
    float w2 = W2[(size_t)(k + 2) * 128 + j];
    float w3 = W2[(size_t)(k + 3) * 128 + j];
    #pragma unroll
    for (int i = 0; i < 8; i++) {
      float4 u = *(const float4*)&s_hid[ng * 8 + i][k];
      acc2[i] += u.x * w0 + u.y * w1 + u.z * w2 + u.w * w3;
    }
  }
  #pragma unroll
  for (int i = 0; i < 8; i++) {
    int n = n0 + ng * 8 + i;
    float v = h[(size_t)n * 128 + j] + acc2[i];
    h[(size_t)n * 128 + j] = v;
    hb[(size_t)n * 128 + j] = (__bf16)v;
  }
}

// ---------------- readout: segment mean (batch sorted) ----------------
__global__ __launch_bounds__(128) void readout_sum_kernel(
    const float* __restrict__ h, const int* __restrict__ batch,
    float* __restrict__ gsum, float* __restrict__ gcnt)
{
  int j = threadIdx.x;  // 128
  int n0 = blockIdx.x * 128;
  float acc = 0.f, cacc = 0.f;
  int cur = batch[n0];
  for (int i = 0; i < 128; i++) {
    int b = batch[n0 + i];
    if (b != cur) {
      atomicAdd(&gsum[cur * 128 + j], acc);
      if (j == 0) atomicAdd(&gcnt[cur], cacc);
      acc = 0.f; cacc = 0.f; cur = b;
    }
    acc += h[(size_t)(n0 + i) * 128 + j];
    cacc += 1.f;
  }
  atomicAdd(&gsum[cur * 128 + j], acc);
  if (j == 0) atomicAdd(&gcnt[cur], cacc);
}

__global__ __launch_bounds__(256) void readout_mlp_kernel(
    const float* __restrict__ gsum, const float* __restrict__ gcnt,
    const float* __restrict__ W1, const float* __restrict__ b1,
    const float* __restrict__ W2, const float* __restrict__ b2,
    float* __restrict__ out)
{
  __shared__ float g[8][128];
  __shared__ float hid[8][256];
  int tid = threadIdx.x;
  for (int i = tid; i < 8 * 128; i += 256) {
    int b = i >> 7, c = i & 127;
    g[b][c] = gsum[i] / fmaxf(gcnt[b], 1.0f);
  }
  __syncthreads();
  {
    float bb = b1[tid];
    float a[8];
    #pragma unroll
    for (int b = 0; b < 8; b++) a[b] = bb;
    for (int k = 0; k < 128; k++) {
      float w = W1[k * 256 + tid];
      #pragma unroll
      for (int b = 0; b < 8; b++) a[b] += g[b][k] * w;
    }
    #pragma unroll
    for (int b = 0; b < 8; b++) hid[b][tid] = silu_f(a[b]);
  }
  __syncthreads();
  int j = tid & 63, bg = tid >> 6;  // 4 groups x 2 graphs
  float a0 = b2[j], a1 = b2[j];
  for (int k = 0; k < 256; k++) {
    float w = W2[k * 64 + j];
    a0 += hid[bg * 2 + 0][k] * w;
    a1 += hid[bg * 2 + 1][k] * w;
  }
  out[(bg * 2 + 0) * 64 + j] = a0;
  out[(bg * 2 + 1) * 64 + j] = a1;
}

extern "C" void kernel_launch(void* const* d_in, const int* in_sizes, int n_in,
                              void* d_out, int out_size, void* d_ws, size_t ws_size,
                              hipStream_t stream) {
  const float* pos   = (const float*)d_in[0];
  const float* xfeat = (const float*)d_in[1];
  const int*   eidx  = (const int*)d_in[2];
  const int*   batch = (const int*)d_in[3];
  const float* eW1 = (const float*)d_in[4];
  const float* eb1 = (const float*)d_in[5];
  const float* eW2 = (const float*)d_in[6];
  const float* eb2 = (const float*)d_in[7];
  const float* mW1 = (const float*)d_in[8];
  const float* mb1 = (const float*)d_in[9];
  const float* mW2 = (const float*)d_in[10];
  const float* mb2 = (const float*)d_in[11];
  const float* uW1 = (const float*)d_in[12];
  const float* ub1 = (const float*)d_in[13];
  const float* uW2 = (const float*)d_in[14];
  const float* ub2 = (const float*)d_in[15];
  const float* rW1 = (const float*)d_in[16];
  const float* rb1 = (const float*)d_in[17];
  const float* rW2 = (const float*)d_in[18];
  const float* rb2 = (const float*)d_in[19];

  const int* srcI = eidx;
  const int* dstI = eidx + NEDGES;

  char* base = (char*)d_ws;
  float* h    = (float*)base;  base += (size_t)NATOMS * 128 * 4;
  float* agg  = (float*)base;  base += (size_t)NATOMS * 128 * 4;
  float* gsum = (float*)base;  base += (8 * 128 + 8) * 4;
  float* gcnt = gsum + 8 * 128;
  __bf16* hb  = (__bf16*)base; base += (size_t)NATOMS * 128 * 2;
  __bf16* efb = (__bf16*)base; base += (size_t)NEDGES * 16 * 2;
  __bf16* W1t = (__bf16*)base; base += (size_t)NLAYERS * 256 * 288 * 2;
  __bf16* W2t = (__bf16*)base;

  conv_w1_kernel<<<dim3(288, NLAYERS), 256, 0, stream>>>(mW1, W1t);
  conv_w2_kernel<<<dim3(128, NLAYERS), 256, 0, stream>>>(mW2, W2t);
  embed_kernel<<<NATOMS, 128, 0, stream>>>(xfeat, eW1, eb1, eW2, eb2, h, hb);
  rbf_kernel<<<NEDGES / 256, 256, 0, stream>>>(pos, srcI, dstI, efb);

  for (int l = 0; l < NLAYERS; l++) {
    hipMemsetAsync(agg, 0, (size_t)NATOMS * 128 * sizeof(float), stream);
    msg_mfma_kernel<<<NEDGES / TE, 256, 0, stream>>>(
        hb, efb, srcI, dstI,
        W1t + (size_t)l * 256 * 288, mb1 + (size_t)l * 256,
        W2t + (size_t)l * 128 * 256, mb2 + (size_t)l * 128, agg);
    upd_kernel<<<NATOMS / 16, 256, 0, stream>>>(
        h, hb, agg,
        uW1 + (size_t)l * 256 * 256, ub1 + (size_t)l * 256,
        uW2 + (size_t)l * 256 * 128, ub2 + (size_t)l * 128);
  }

  hipMemsetAsync(gsum, 0, (8 * 128 + 8) * sizeof(float), stream);
  readout_sum_kernel<<<NATOMS / 128, 128, 0, stream>>>(h, batch, gsum, gcnt);
  readout_mlp_kernel<<<1, 256, 0, stream>>>(gsum, gcnt, rW1, rb1, rW2, rb2,
                                            (float*)d_out);
}

// Round 3
// 1580.159 us; speedup vs baseline: 6.8552x; 1.1222x over previous
//
#include <hip/hip_runtime.h>
#include <math.h>

#define NATOMS 16384
#define NEDGES 524288
#define DIM 128
#define HIDDEN 256
#define NLAYERS 4
#define TE 64      // edges per block in msg kernel

typedef __bf16 bf16x8 __attribute__((ext_vector_type(8)));
typedef float f32x4 __attribute__((ext_vector_type(4)));

__device__ __forceinline__ float silu_f(float x) {
  return x / (1.0f + __expf(-x));
}

// ---------------- CSR preprocessing ----------------
__global__ __launch_bounds__(256) void hist_kernel(
    const int* __restrict__ dst, int* __restrict__ counts)
{
  int e = blockIdx.x * 256 + threadIdx.x;
  atomicAdd(&counts[dst[e]], 1);
}

// single block, 1024 threads: exclusive scan of counts[16384] -> cursor
__global__ __launch_bounds__(1024) void scan_kernel(
    const int* __restrict__ counts, int* __restrict__ cursor)
{
  __shared__ int buf[1024];
  __shared__ int carry_s;
  int tid = threadIdx.x;
  if (tid == 0) carry_s = 0;
  __syncthreads();
  for (int c = 0; c < 16; c++) {
    int v = counts[c * 1024 + tid];
    buf[tid] = v;
    __syncthreads();
    for (int off = 1; off < 1024; off <<= 1) {
      int t = (tid >= off) ? buf[tid - off] : 0;
      __syncthreads();
      buf[tid] += t;
      __syncthreads();
    }
    cursor[c * 1024 + tid] = buf[tid] - v + carry_s;
    __syncthreads();
    if (tid == 1023) carry_s += buf[1023];
    __syncthreads();
  }
}

__global__ __launch_bounds__(256) void scatter_kernel(
    const int* __restrict__ src, const int* __restrict__ dst,
    int* __restrict__ cursor, int* __restrict__ esrc, int* __restrict__ edst)
{
  int e = blockIdx.x * 256 + threadIdx.x;
  int d = dst[e];
  int p = atomicAdd(&cursor[d], 1);
  esrc[p] = src[e];
  edst[p] = d;
}

// ---------------- weight pre-conversion to bf16, transposed [N][K] ----------------
__global__ __launch_bounds__(256) void conv_w1_kernel(
    const float* __restrict__ W, __bf16* __restrict__ Wt)
{
  int l = blockIdx.y;
  int i = blockIdx.x * 256 + threadIdx.x;  // 0 .. 256*288-1
  int n = i / 288, k = i - n * 288;
  float v = (k < 272) ? W[((size_t)l * 272 + k) * 256 + n] : 0.0f;
  Wt[((size_t)l * 256 + n) * 288 + k] = (__bf16)v;
}

__global__ __launch_bounds__(256) void conv_w2_kernel(
    const float* __restrict__ W, __bf16* __restrict__ Wt)
{
  int l = blockIdx.y;
  int i = blockIdx.x * 256 + threadIdx.x;  // 0 .. 128*256-1
  int n = i / 256, k = i - n * 256;
  Wt[((size_t)l * 128 + n) * 256 + k] = (__bf16)W[((size_t)l * 256 + k) * 128 + n];
}

// ---------------- embedding: h = mlp2(x, emb), writes fp32 + bf16 ----------------
__global__ __launch_bounds__(128) void embed_kernel(
    const float* __restrict__ x, const float* __restrict__ W1,
    const float* __restrict__ b1, const float* __restrict__ W2,
    const float* __restrict__ b2, float* __restrict__ h,
    __bf16* __restrict__ hb)
{
  int n = blockIdx.x;
  int j = threadIdx.x;  // 0..127
  __shared__ float xs[26];
  __shared__ float hid[128];
  if (j < 26) xs[j] = x[n * 26 + j];
  __syncthreads();
  float acc = b1[j];
  #pragma unroll
  for (int k = 0; k < 26; k++) acc += xs[k] * W1[k * 128 + j];
  hid[j] = silu_f(acc);
  __syncthreads();
  float acc2 = b2[j];
  #pragma unroll 8
  for (int k = 0; k < 128; k++) acc2 += hid[k] * W2[k * 128 + j];
  h[(size_t)n * 128 + j] = acc2;
  hb[(size_t)n * 128 + j] = (__bf16)acc2;
}

// ---------------- edge RBF features, computed in SORTED slot order ----------------
__global__ __launch_bounds__(256) void rbf_kernel(
    const float* __restrict__ pos, const int* __restrict__ esrc,
    const int* __restrict__ edst, __bf16* __restrict__ efb)
{
  int e = blockIdx.x * 256 + threadIdx.x;
  int s = esrc[e], d = edst[e];
  float dx = pos[d * 3 + 0] - pos[s * 3 + 0];
  float dy = pos[d * 3 + 1] - pos[s * 3 + 1];
  float dz = pos[d * 3 + 2] - pos[s * 3 + 2];
  float dist = sqrtf(dx * dx + dy * dy + dz * dz + 1e-12f);
  float env = (dist < 10.0f)
                  ? 0.5f * (cosf(3.14159265358979f * dist * 0.1f) + 1.0f)
                  : 0.0f;
  bf16x8 o0, o1;
  #pragma unroll
  for (int i = 0; i < 16; i++) {
    float c = (10.0f / 15.0f) * (float)i;    // linspace(0,10,16)
    float t = dist - c;
    float v = env * __expf(-t * t * 1.28f);  // 1/(2*(10/16)^2) = 1.28
    if (i < 8) o0[i] = (__bf16)v; else o1[i - 8] = (__bf16)v;
  }
  *(bf16x8*)(efb + (size_t)e * 16 + 0) = o0;
  *(bf16x8*)(efb + (size_t)e * 16 + 8) = o1;
}

// ---------------- fused message MLP (bf16 MFMA) on dst-sorted edges ----------------
// Epilogue: segmented column-scan over the 64 sorted rows -> one atomicAdd per
// (distinct dst x column) instead of per (edge x column).
#define SA_BYTES (TE * 296 * 2)          // 37888
#define SH_BYTES (TE * 136 * 2)          // 17408
#define SMEM_BYTES (SA_BYTES + SH_BYTES + TE * 4)

__global__ __launch_bounds__(256, 2) void msg_mfma_kernel(
    const __bf16* __restrict__ hb, const __bf16* __restrict__ efb,
    const int* __restrict__ esrc, const int* __restrict__ edst,
    const __bf16* __restrict__ W1t, const float* __restrict__ b1,
    const __bf16* __restrict__ W2t, const float* __restrict__ b2,
    float* __restrict__ agg)
{
  __shared__ __align__(16) char smem[SMEM_BYTES];
  __bf16 (*s_a)[296] = (__bf16(*)[296])smem;                 // stride 296: 2-way max
  __bf16 (*s_h)[136] = (__bf16(*)[136])(smem + SA_BYTES);    // stride 136
  int* s_dst = (int*)(smem + SA_BYTES + SH_BYTES);
  float (*s_msg)[132] = (float(*)[132])smem;                 // aliases s_a (epilogue only)

  int tid = threadIdx.x;
  int e0 = blockIdx.x * TE;

  // ---- gather phase: 4 threads per edge (sorted slots) ----
  {
    int e = tid >> 2, t4 = tid & 3;
    int se = esrc[e0 + e];
    int de = edst[e0 + e];
    if (t4 == 0) s_dst[e] = de;
    bf16x8* arow = (bf16x8*)&s_a[e][0];
    const bf16x8* hs = (const bf16x8*)(hb + (size_t)se * 128);
    const bf16x8* hd = (const bf16x8*)(hb + (size_t)de * 128);
    #pragma unroll
    for (int c = 0; c < 4; c++) {
      arow[t4 + 4 * c] = hs[t4 + 4 * c];            // cols 0..127
      arow[16 + t4 + 4 * c] = hd[t4 + 4 * c];       // cols 128..255
    }
    if (t4 == 0) {
      const bf16x8* ep = (const bf16x8*)(efb + (size_t)(e0 + e) * 16);
      arow[32] = ep[0];                              // cols 256..271
      arow[33] = ep[1];
      float4 z4 = make_float4(0.f, 0.f, 0.f, 0.f);   // zero pad 272..287
      *(float4*)&s_a[e][272] = z4;
      *(float4*)&s_a[e][280] = z4;
    }
  }
  __syncthreads();

  const int wv = tid >> 6;   // wave 0..3 -> owns 32 output cols
  const int ln = tid & 63;
  const int lc = ln & 15;
  const int qd = ln >> 4;

  f32x4 acc2[4][2];
  #pragma unroll
  for (int nt = 0; nt < 2; nt++) {
    float bv = b2[wv * 32 + nt * 16 + lc];
    #pragma unroll
    for (int mt = 0; mt < 4; mt++) {
      acc2[mt][nt][0] = bv; acc2[mt][nt][1] = bv;
      acc2[mt][nt][2] = bv; acc2[mt][nt][3] = bv;
    }
  }

  for (int hf = 0; hf < 2; hf++) {
    f32x4 acc1[4][2];
    #pragma unroll
    for (int nt = 0; nt < 2; nt++) {
      float bv = b1[hf * 128 + wv * 32 + nt * 16 + lc];
      #pragma unroll
      for (int mt = 0; mt < 4; mt++) {
        acc1[mt][nt][0] = bv; acc1[mt][nt][1] = bv;
        acc1[mt][nt][2] = bv; acc1[mt][nt][3] = bv;
      }
    }
    #pragma unroll
    for (int kt = 0; kt < 9; kt++) {
      bf16x8 af[4];
      #pragma unroll
      for (int mt = 0; mt < 4; mt++)
        af[mt] = *(const bf16x8*)&s_a[mt * 16 + lc][kt * 32 + qd * 8];
      bf16x8 bw[2];
      #pragma unroll
      for (int nt = 0; nt < 2; nt++)
        bw[nt] = *(const bf16x8*)(W1t +
                 (size_t)(hf * 128 + wv * 32 + nt * 16 + lc) * 288 + kt * 32 + qd * 8);
      #pragma unroll
      for (int mt = 0; mt < 4; mt++)
        #pragma unroll
        for (int nt = 0; nt < 2; nt++)
          acc1[mt][nt] = __builtin_amdgcn_mfma_f32_16x16x32_bf16(
              af[mt], bw[nt], acc1[mt][nt], 0, 0, 0);
    }

    __syncthreads();  // prev-half GEMM2 readers done with s_h
    #pragma unroll
    for (int mt = 0; mt < 4; mt++)
      #pragma unroll
      for (int nt = 0; nt < 2; nt++) {
        int c = wv * 32 + nt * 16 + lc;
        #pragma unroll
        for (int r = 0; r < 4; r++) {
          int m = mt * 16 + qd * 4 + r;
          s_h[m][c] = (__bf16)silu_f(acc1[mt][nt][r]);
        }
      }
    __syncthreads();

    #pragma unroll
    for (int kt = 0; kt < 4; kt++) {
      bf16x8 a2[4];
      #pragma unroll
      for (int mt = 0; mt < 4; mt++)
        a2[mt] = *(const bf16x8*)&s_h[mt * 16 + lc][kt * 32 + qd * 8];
      bf16x8 b2w[2];
      #pragma unroll
      for (int nt = 0; nt < 2; nt++)
        b2w[nt] = *(const bf16x8*)(W2t +
                  (size_t)(wv * 32 + nt * 16 + lc) * 256 + hf * 128 + kt * 32 + qd * 8);
      #pragma unroll
      for (int mt = 0; mt < 4; mt++)
        #pragma unroll
        for (int nt = 0; nt < 2; nt++)
          acc2[mt][nt] = __builtin_amdgcn_mfma_f32_16x16x32_bf16(
              a2[mt], b2w[nt], acc2[mt][nt], 0, 0, 0);
    }
  }

  // ---- epilogue: C-layout -> LDS (fp32), segmented scan per column ----
  // s_msg aliases s_a; all s_a reads finished before the hf=1 s_h-write barrier.
  #pragma unroll
  for (int mt = 0; mt < 4; mt++)
    #pragma unroll
    for (int nt = 0; nt < 2; nt++) {
      int c = wv * 32 + nt * 16 + lc;
      #pragma unroll
      for (int r = 0; r < 4; r++)
        s_msg[mt * 16 + qd * 4 + r][c] = acc2[mt][nt][r];
    }
  __syncthreads();

  if (tid < 128) {
    int j = tid;
    float acc = 0.0f;
    int cur = s_dst[0];
    for (int m = 0; m < 64; m++) {
      int d = s_dst[m];           // uniform across lanes -> scalar branch
      if (d != cur) {
        atomicAdd(&agg[(size_t)cur * 128 + j], acc);
        acc = 0.0f;
        cur = d;
      }
      acc += s_msg[m][j];
    }
    atomicAdd(&agg[(size_t)cur * 128 + j], acc);
  }
}

// ---------------- node update MLP (fp32, residual), writes h + hb ----------------
__global__ __launch_bounds__(256) void upd_kernel(
    float* __restrict__ h, __bf16* __restrict__ hb,
    const float* __restrict__ agg,
    const float* __restrict__ W1, const float* __restrict__ b1,
    const float* __restrict__ W2, const float* __restrict__ b2)
{
  __shared__ float s_u[16][260];
  __shared__ float s_hid[16][260];
  int tid = threadIdx.x;
  int n0 = blockIdx.x * 16;
  for (int i = tid; i < 16 * 256; i += 256) {
    int nl = i >> 8, c = i & 255;
    s_u[nl][c] = (c < 128) ? h[(size_t)(n0 + nl) * 128 + c]
                           : agg[(size_t)(n0 + nl) * 128 + (c - 128)];
  }
  __syncthreads();
  float acc[16];
  float bb = b1[tid];
  #pragma unroll
  for (int i = 0; i < 16; i++) acc[i] = bb;
  for (int k = 0; k < 256; k += 4) {
    float w0 = W1[(size_t)(k + 0) * 256 + tid];
    float w1 = W1[(size_t)(k + 1) * 256 + tid];
    float w2 = W1[(size_t)(k + 2) * 256 + tid];
    float w3 = W1[(size_t)(k + 3) * 256 + tid];
    #pragma unroll
    for (int i = 0; i < 16; i++) {
      float4 u = *(const float4*)&s_u[i][k];
      acc[i] += u.x * w0 + u.y * w1 + u.z * w2 + u.w * w3;
    }
  }
  #pragma unroll
  for (int i = 0; i < 16; i++) s_hid[i][tid] = silu_f(acc[i]);
  __syncthreads();
  int j = tid & 127, ng = tid >> 7;  // 2 node-groups of 8
  float acc2[8];
  float b2v = b2[j];
  #pragma unroll
  for (int i = 0; i < 8; i++) acc2[i] = b2v;
  for (int k = 0; k < 256; k += 4) {
    float w0 = W2[(size_t)(k + 0) * 128 + j];
    float w1 = W2[(size_t)(k + 1) * 128 + j];
    float w2 = W2[(size_t)(k + 2) * 128 + j];
    float w3 = W2[(size_t)(k + 3) * 128 + j];
    #pragma unroll
    for (int i = 0; i < 8; i++) {
      float4 u = *(const float4*)&s_hid[ng * 8 + i][k];
      acc2[i] += u.x * w0 + u.y * w1 + u.z * w2 + u.w * w3;
    }
  }
  #pragma unroll
  for (int i = 0; i < 8; i++) {
    int n = n0 + ng * 8 + i;
    float v = h[(size_t)n * 128 + j] + acc2[i];
    h[(size_t)n * 128 + j] = v;
    hb[(size_t)n * 128 + j] = (__bf16)v;
  }
}

// ---------------- readout: segment mean (batch sorted) ----------------
__global__ __launch_bounds__(128) void readout_sum_kernel(
    const float* __restrict__ h, const int* __restrict__ batch,
    float* __restrict__ gsum, float* __restrict__ gcnt)
{
  int j = threadIdx.x;  // 128
  int n0 = blockIdx.x * 128;
  float acc = 0.f, cacc = 0.f;
  int cur = batch[n0];
  for (int i = 0; i < 128; i++) {
    int b = batch[n0 + i];
    if (b != cur) {
      atomicAdd(&gsum[cur * 128 + j], acc);
      if (j == 0) atomicAdd(&gcnt[cur], cacc);
      acc = 0.f; cacc = 0.f; cur = b;
    }
    acc += h[(size_t)(n0 + i) * 128 + j];
    cacc += 1.f;
  }
  atomicAdd(&gsum[cur * 128 + j], acc);
  if (j == 0) atomicAdd(&gcnt[cur], cacc);
}

__global__ __launch_bounds__(256) void readout_mlp_kernel(
    const float* __restrict__ gsum, const float* __restrict__ gcnt,
    const float* __restrict__ W1, const float* __restrict__ b1,
    const float* __restrict__ W2, const float* __restrict__ b2,
    float* __restrict__ out)
{
  __shared__ float g[8][128];
  __shared__ float hid[8][256];
  int tid = threadIdx.x;
  for (int i = tid; i < 8 * 128; i += 256) {
    int b = i >> 7, c = i & 127;
    g[b][c] = gsum[i] / fmaxf(gcnt[b], 1.0f);
  }
  __syncthreads();
  {
    float bb = b1[tid];
    float a[8];
    #pragma unroll
    for (int b = 0; b < 8; b++) a[b] = bb;
    for (int k = 0; k < 128; k++) {
      float w = W1[k * 256 + tid];
      #pragma unroll
      for (int b = 0; b < 8; b++) a[b] += g[b][k] * w;
    }
    #pragma unroll
    for (int b = 0; b < 8; b++) hid[b][tid] = silu_f(a[b]);
  }
  __syncthreads();
  int j = tid & 63, bg = tid >> 6;  // 4 groups x 2 graphs
  float a0 = b2[j], a1 = b2[j];
  for (int k = 0; k < 256; k++) {
    float w = W2[k * 64 + j];
    a0 += hid[bg * 2 + 0][k] * w;
    a1 += hid[bg * 2 + 1][k] * w;
  }
  out[(bg * 2 + 0) * 64 + j] = a0;
  out[(bg * 2 + 1) * 64 + j] = a1;
}

extern "C" void kernel_launch(void* const* d_in, const int* in_sizes, int n_in,
                              void* d_out, int out_size, void* d_ws, size_t ws_size,
                              hipStream_t stream) {
  const float* pos   = (const float*)d_in[0];
  const float* xfeat = (const float*)d_in[1];
  const int*   eidx  = (const int*)d_in[2];
  const int*   batch = (const int*)d_in[3];
  const float* eW1 = (const float*)d_in[4];
  const float* eb1 = (const float*)d_in[5];
  const float* eW2 = (const float*)d_in[6];
  const float* eb2 = (const float*)d_in[7];
  const float* mW1 = (const float*)d_in[8];
  const float* mb1 = (const float*)d_in[9];
  const float* mW2 = (const float*)d_in[10];
  const float* mb2 = (const float*)d_in[11];
  const float* uW1 = (const float*)d_in[12];
  const float* ub1 = (const float*)d_in[13];
  const float* uW2 = (const float*)d_in[14];
  const float* ub2 = (const float*)d_in[15];
  const float* rW1 = (const float*)d_in[16];
  const float* rb1 = (const float*)d_in[17];
  const float* rW2 = (const float*)d_in[18];
  const float* rb2 = (const float*)d_in[19];

  const int* srcI = eidx;
  const int* dstI = eidx + NEDGES;

  char* base = (char*)d_ws;
  float* h    = (float*)base;  base += (size_t)NATOMS * 128 * 4;
  float* agg  = (float*)base;  base += (size_t)NATOMS * 128 * 4;
  float* gsum = (float*)base;  base += (8 * 128 + 8) * 4;
  float* gcnt = gsum + 8 * 128;
  __bf16* hb  = (__bf16*)base; base += (size_t)NATOMS * 128 * 2;
  __bf16* efb = (__bf16*)base; base += (size_t)NEDGES * 16 * 2;
  __bf16* W1t = (__bf16*)base; base += (size_t)NLAYERS * 256 * 288 * 2;
  __bf16* W2t = (__bf16*)base; base += (size_t)NLAYERS * 128 * 256 * 2;
  int* counts = (int*)base;    base += (size_t)NATOMS * 4;
  int* cursor = (int*)base;    base += (size_t)NATOMS * 4;
  int* esrc   = (int*)base;    base += (size_t)NEDGES * 4;
  int* edst   = (int*)base;    base += (size_t)NEDGES * 4;

  // --- CSR preprocessing (once per launch) ---
  hipMemsetAsync(counts, 0, NATOMS * sizeof(int), stream);
  hist_kernel<<<NEDGES / 256, 256, 0, stream>>>(dstI, counts);
  scan_kernel<<<1, 1024, 0, stream>>>(counts, cursor);
  scatter_kernel<<<NEDGES / 256, 256, 0, stream>>>(srcI, dstI, cursor, esrc, edst);

  conv_w1_kernel<<<dim3(288, NLAYERS), 256, 0, stream>>>(mW1, W1t);
  conv_w2_kernel<<<dim3(128, NLAYERS), 256, 0, stream>>>(mW2, W2t);
  embed_kernel<<<NATOMS, 128, 0, stream>>>(xfeat, eW1, eb1, eW2, eb2, h, hb);
  rbf_kernel<<<NEDGES / 256, 256, 0, stream>>>(pos, esrc, edst, efb);

  for (int l = 0; l < NLAYERS; l++) {
    hipMemsetAsync(agg, 0, (size_t)NATOMS * 128 * sizeof(float), stream);
    msg_mfma_kernel<<<NEDGES / TE, 256, 0, stream>>>(
        hb, efb, esrc, edst,
        W1t + (size_t)l * 256 * 288, mb1 + (size_t)l * 256,
        W2t + (size_t)l * 128 * 256, mb2 + (size_t)l * 128, agg);
    upd_kernel<<<NATOMS / 16, 256, 0, stream>>>(
        h, hb, agg,
        uW1 + (size_t)l * 256 * 256, ub1 + (size_t)l * 256,
        uW2 + (size_t)l * 256 * 128, ub2 + (size_t)l * 128);
  }

  hipMemsetAsync(gsum, 0, (8 * 128 + 8) * sizeof(float), stream);
  readout_sum_kernel<<<NATOMS / 128, 128, 0, stream>>>(h, batch, gsum, gcnt);
  readout_mlp_kernel<<<1, 256, 0, stream>>>(gsum, gcnt, rW1, rb1, rW2, rb2,
                                            (float*)d_out);
}

// Round 4
// 1047.900 us; speedup vs baseline: 10.3371x; 1.5079x over previous
//
#include <hip/hip_runtime.h>
#include <math.h>

#define NATOMS 16384
#define NEDGES 524288
#define NLAYERS 4
#define TE 64      // edges per block in msg kernel

typedef __bf16 bf16x8 __attribute__((ext_vector_type(8)));
typedef __bf16 bf16x4 __attribute__((ext_vector_type(4)));
typedef float f32x4 __attribute__((ext_vector_type(4)));

__device__ __forceinline__ float silu_f(float x) {
  return x / (1.0f + __expf(-x));
}

// ---------------- CSR preprocessing ----------------
__global__ __launch_bounds__(256) void hist_kernel(
    const int* __restrict__ dst, int* __restrict__ counts)
{
  int e = blockIdx.x * 256 + threadIdx.x;
  atomicAdd(&counts[dst[e]], 1);
}

__global__ __launch_bounds__(1024) void scan_kernel(
    const int* __restrict__ counts, int* __restrict__ cursor)
{
  __shared__ int buf[1024];
  __shared__ int carry_s;
  int tid = threadIdx.x;
  if (tid == 0) carry_s = 0;
  __syncthreads();
  for (int c = 0; c < 16; c++) {
    int v = counts[c * 1024 + tid];
    buf[tid] = v;
    __syncthreads();
    for (int off = 1; off < 1024; off <<= 1) {
      int t = (tid >= off) ? buf[tid - off] : 0;
      __syncthreads();
      buf[tid] += t;
      __syncthreads();
    }
    cursor[c * 1024 + tid] = buf[tid] - v + carry_s;
    __syncthreads();
    if (tid == 1023) carry_s += buf[1023];
    __syncthreads();
  }
}

__global__ __launch_bounds__(256) void scatter_kernel(
    const int* __restrict__ src, const int* __restrict__ dst,
    int* __restrict__ cursor, int* __restrict__ esrc, int* __restrict__ edst)
{
  int e = blockIdx.x * 256 + threadIdx.x;
  int d = dst[e];
  int p = atomicAdd(&cursor[d], 1);
  esrc[p] = src[e];
  edst[p] = d;
}

// ---------------- generic weight transpose+convert ----------------
// W slice rows [k0, k0+Kin) x N cols (row-major, leading dim ldN) -> Wt [N][Kpad] bf16
__global__ __launch_bounds__(256) void conv_t_kernel(
    const float* __restrict__ W, __bf16* __restrict__ Wt,
    int ldN, int k0, int Kin, int Kpad, long lsrc, long ldst)
{
  long l = blockIdx.y;
  int i = blockIdx.x * 256 + threadIdx.x;
  int n = i / Kpad, k = i - n * Kpad;
  float v = (k < Kin) ? W[l * lsrc + (size_t)(k0 + k) * ldN + n] : 0.0f;
  Wt[l * ldst + (size_t)n * Kpad + k] = (__bf16)v;
}

// ---------------- embedding: h = mlp2(x, emb), writes fp32 + bf16 ----------------
__global__ __launch_bounds__(128) void embed_kernel(
    const float* __restrict__ x, const float* __restrict__ W1,
    const float* __restrict__ b1, const float* __restrict__ W2,
    const float* __restrict__ b2, float* __restrict__ h,
    __bf16* __restrict__ hb)
{
  int n = blockIdx.x;
  int j = threadIdx.x;  // 0..127
  __shared__ float xs[26];
  __shared__ float hid[128];
  if (j < 26) xs[j] = x[n * 26 + j];
  __syncthreads();
  float acc = b1[j];
  #pragma unroll
  for (int k = 0; k < 26; k++) acc += xs[k] * W1[k * 128 + j];
  hid[j] = silu_f(acc);
  __syncthreads();
  float acc2 = b2[j];
  #pragma unroll 8
  for (int k = 0; k < 128; k++) acc2 += hid[k] * W2[k * 128 + j];
  h[(size_t)n * 128 + j] = acc2;
  hb[(size_t)n * 128 + j] = (__bf16)acc2;
}

// ---------------- edge RBF features (sorted slot order) ----------------
__global__ __launch_bounds__(256) void rbf_kernel(
    const float* __restrict__ pos, const int* __restrict__ esrc,
    const int* __restrict__ edst, __bf16* __restrict__ efb)
{
  int e = blockIdx.x * 256 + threadIdx.x;
  int s = esrc[e], d = edst[e];
  float dx = pos[d * 3 + 0] - pos[s * 3 + 0];
  float dy = pos[d * 3 + 1] - pos[s * 3 + 1];
  float dz = pos[d * 3 + 2] - pos[s * 3 + 2];
  float dist = sqrtf(dx * dx + dy * dy + dz * dz + 1e-12f);
  float env = (dist < 10.0f)
                  ? 0.5f * (cosf(3.14159265358979f * dist * 0.1f) + 1.0f)
                  : 0.0f;
  bf16x8 o0, o1;
  #pragma unroll
  for (int i = 0; i < 16; i++) {
    float c = (10.0f / 15.0f) * (float)i;    // linspace(0,10,16)
    float t = dist - c;
    float v = env * __expf(-t * t * 1.28f);  // 1/(2*(10/16)^2) = 1.28
    if (i < 8) o0[i] = (__bf16)v; else o1[i - 8] = (__bf16)v;
  }
  *(bf16x8*)(efb + (size_t)e * 16 + 0) = o0;
  *(bf16x8*)(efb + (size_t)e * 16 + 8) = o1;
}

// ---------------- zprep: z1 = h@W1a, z2 = h@W1b + b1 (per layer); zeros agg ----------------
__global__ __launch_bounds__(256) void zprep_kernel(
    const __bf16* __restrict__ hb, const float* __restrict__ b1,
    const __bf16* __restrict__ W1at, const __bf16* __restrict__ W1bt,
    float* __restrict__ z1, float* __restrict__ z2, float* __restrict__ agg)
{
  __shared__ __bf16 s_n[64][136];   // 272 B rows: 16-aligned; 68 dw stride -> 2-way (free)
  int tid = threadIdx.x, n0 = blockIdx.x * 64;
  {
    int n = tid >> 2, t4 = tid & 3;
    const bf16x8* hr = (const bf16x8*)(hb + (size_t)(n0 + n) * 128);
    #pragma unroll
    for (int i = 0; i < 4; i++)
      *(bf16x8*)&s_n[n][t4 * 8 + 32 * i] = hr[t4 + 4 * i];
  }
  {
    float4 zz = make_float4(0.f, 0.f, 0.f, 0.f);
    float4* ap = (float4*)(agg + (size_t)n0 * 128);
    for (int i = tid; i < 64 * 128 / 4; i += 256) ap[i] = zz;
  }
  __syncthreads();
  const int wv = tid >> 6, ln = tid & 63, lc = ln & 15, qd = ln >> 4;
  for (int cp = 0; cp < 2; cp++) {
    f32x4 aA[4][2], aB[4][2];
    #pragma unroll
    for (int nt = 0; nt < 2; nt++) {
      float bv = b1[cp * 128 + wv * 32 + nt * 16 + lc];
      #pragma unroll
      for (int mt = 0; mt < 4; mt++) {
        aA[mt][nt][0] = 0.f; aA[mt][nt][1] = 0.f;
        aA[mt][nt][2] = 0.f; aA[mt][nt][3] = 0.f;
        aB[mt][nt][0] = bv; aB[mt][nt][1] = bv;
        aB[mt][nt][2] = bv; aB[mt][nt][3] = bv;
      }
    }
    #pragma unroll
    for (int kt = 0; kt < 4; kt++) {
      bf16x8 af[4];
      #pragma unroll
      for (int mt = 0; mt < 4; mt++)
        af[mt] = *(const bf16x8*)&s_n[mt * 16 + lc][kt * 32 + qd * 8];
      bf16x8 bwA[2], bwB[2];
      #pragma unroll
      for (int nt = 0; nt < 2; nt++) {
        int c = cp * 128 + wv * 32 + nt * 16 + lc;
        bwA[nt] = *(const bf16x8*)(W1at + (size_t)c * 128 + kt * 32 + qd * 8);
        bwB[nt] = *(const bf16x8*)(W1bt + (size_t)c * 128 + kt * 32 + qd * 8);
      }
      #pragma unroll
      for (int mt = 0; mt < 4; mt++)
        #pragma unroll
        for (int nt = 0; nt < 2; nt++) {
          aA[mt][nt] = __builtin_amdgcn_mfma_f32_16x16x32_bf16(af[mt], bwA[nt], aA[mt][nt], 0, 0, 0);
          aB[mt][nt] = __builtin_amdgcn_mfma_f32_16x16x32_bf16(af[mt], bwB[nt], aB[mt][nt], 0, 0, 0);
        }
    }
    #pragma unroll
    for (int mt = 0; mt < 4; mt++)
      #pragma unroll
      for (int nt = 0; nt < 2; nt++) {
        int c = cp * 128 + wv * 32 + nt * 16 + lc;
        #pragma unroll
        for (int r = 0; r < 4; r++) {
          int n = n0 + mt * 16 + qd * 4 + r;
          z1[(size_t)n * 256 + c] = aA[mt][nt][r];
          z2[(size_t)n * 256 + c] = aB[mt][nt][r];
        }
      }
  }
}

// ---------------- fused message MLP: acc-init gather + K16 ef-MFMA + GEMM2 ----------------
#define MS_H_OFF 5120                      // s_ef: 64*40*2 = 5120
#define MS_DST_OFF 33792                   // s_h: 64*136*2 = 17408 (ends 22528); s_msg 64*132*4 = 33792
#define MS_SRC_OFF 34048
#define MS_BYTES 34304                     // 4 blocks/CU

__global__ __launch_bounds__(256, 4) void msg_mfma_kernel(
    const float* __restrict__ z1, const float* __restrict__ z2,
    const __bf16* __restrict__ efb,
    const int* __restrict__ esrc, const int* __restrict__ edst,
    const __bf16* __restrict__ W1ct, const __bf16* __restrict__ W2t,
    const float* __restrict__ b2, float* __restrict__ agg)
{
  __shared__ __align__(16) char smem[MS_BYTES];
  __bf16 (*s_ef)[40] = (__bf16(*)[40])(smem);             // 80 B rows, 16-aligned
  __bf16 (*s_h)[136] = (__bf16(*)[136])(smem + MS_H_OFF); // 272 B rows
  float (*s_msg)[132] = (float(*)[132])(smem);            // epilogue alias
  int* s_dst = (int*)(smem + MS_DST_OFF);
  int* s_src = (int*)(smem + MS_SRC_OFF);

  int tid = threadIdx.x, e0 = blockIdx.x * TE;
  if (tid < TE) s_dst[tid] = edst[e0 + tid];
  else if (tid < 2 * TE) s_src[tid - TE] = esrc[e0 + tid - TE];
  {
    int e = tid >> 2, t4 = tid & 3;
    bf16x8* er = (bf16x8*)&s_ef[e][0];
    if (t4 < 2) {
      er[t4] = *(const bf16x8*)(efb + (size_t)(e0 + e) * 16 + t4 * 8);
    } else {
      bf16x8 zz;
      #pragma unroll
      for (int j = 0; j < 8; j++) zz[j] = (__bf16)0.0f;
      er[t4] = zz;                                        // zero pad k=16..31
    }
  }
  __syncthreads();

  const int wv = tid >> 6, ln = tid & 63, lc = ln & 15, qd = ln >> 4;

  f32x4 acc2[4][2];
  #pragma unroll
  for (int nt = 0; nt < 2; nt++) {
    float bv = b2[wv * 32 + nt * 16 + lc];
    #pragma unroll
    for (int mt = 0; mt < 4; mt++) {
      acc2[mt][nt][0] = bv; acc2[mt][nt][1] = bv;
      acc2[mt][nt][2] = bv; acc2[mt][nt][3] = bv;
    }
  }

  for (int hf = 0; hf < 2; hf++) {
    // hid_pre init = z1[src] + z2[dst]  (C-layout accumulator init)
    f32x4 acc1[4][2];
    #pragma unroll
    for (int mt = 0; mt < 4; mt++)
      #pragma unroll
      for (int nt = 0; nt < 2; nt++) {
        int c = hf * 128 + wv * 32 + nt * 16 + lc;
        #pragma unroll
        for (int r = 0; r < 4; r++) {
          int m = mt * 16 + qd * 4 + r;
          acc1[mt][nt][r] = z1[(size_t)s_src[m] * 256 + c] +
                            z2[(size_t)s_dst[m] * 256 + c];
        }
      }
    // += ef @ W1c  (single K32 MFMA step, k>=16 zero-padded)
    {
      bf16x8 bwc[2];
      #pragma unroll
      for (int nt = 0; nt < 2; nt++) {
        int c = hf * 128 + wv * 32 + nt * 16 + lc;
        bwc[nt] = *(const bf16x8*)(W1ct + (size_t)c * 32 + qd * 8);
      }
      #pragma unroll
      for (int mt = 0; mt < 4; mt++) {
        bf16x8 aef = *(const bf16x8*)&s_ef[mt * 16 + lc][qd * 8];
        #pragma unroll
        for (int nt = 0; nt < 2; nt++)
          acc1[mt][nt] = __builtin_amdgcn_mfma_f32_16x16x32_bf16(aef, bwc[nt], acc1[mt][nt], 0, 0, 0);
      }
    }
    __syncthreads();  // prev-hf GEMM2 done reading s_h
    #pragma unroll
    for (int mt = 0; mt < 4; mt++)
      #pragma unroll
      for (int nt = 0; nt < 2; nt++) {
        int cc = wv * 32 + nt * 16 + lc;
        #pragma unroll
        for (int r = 0; r < 4; r++)
          s_h[mt * 16 + qd * 4 + r][cc] = (__bf16)silu_f(acc1[mt][nt][r]);
      }
    __syncthreads();

    #pragma unroll
    for (int kt = 0; kt < 4; kt++) {
      bf16x8 a2[4];
      #pragma unroll
      for (int mt = 0; mt < 4; mt++)
        a2[mt] = *(const bf16x8*)&s_h[mt * 16 + lc][kt * 32 + qd * 8];
      bf16x8 b2w[2];
      #pragma unroll
      for (int nt = 0; nt < 2; nt++)
        b2w[nt] = *(const bf16x8*)(W2t +
                  (size_t)(wv * 32 + nt * 16 + lc) * 256 + hf * 128 + kt * 32 + qd * 8);
      #pragma unroll
      for (int mt = 0; mt < 4; mt++)
        #pragma unroll
        for (int nt = 0; nt < 2; nt++)
          acc2[mt][nt] = __builtin_amdgcn_mfma_f32_16x16x32_bf16(a2[mt], b2w[nt], acc2[mt][nt], 0, 0, 0);
    }
  }

  // ---- epilogue: C-layout -> LDS fp32, segmented column-scan ----
  __syncthreads();
  #pragma unroll
  for (int mt = 0; mt < 4; mt++)
    #pragma unroll
    for (int nt = 0; nt < 2; nt++) {
      int c = wv * 32 + nt * 16 + lc;
      #pragma unroll
      for (int r = 0; r < 4; r++)
        s_msg[mt * 16 + qd * 4 + r][c] = acc2[mt][nt][r];
    }
  __syncthreads();

  if (tid < 128) {
    int j = tid;
    float acc = 0.0f;
    int cur = s_dst[0];
    for (int m = 0; m < 64; m++) {
      int d = s_dst[m];           // wave-uniform -> scalar branch
      if (d != cur) {
        atomicAdd(&agg[(size_t)cur * 128 + j], acc);
        acc = 0.0f;
        cur = d;
      }
      acc += s_msg[m][j];
    }
    atomicAdd(&agg[(size_t)cur * 128 + j], acc);
  }
}

// ---------------- node update MLP (bf16 MFMA, residual) ----------------
__global__ __launch_bounds__(256, 3) void upd_mfma_kernel(
    float* __restrict__ h, __bf16* __restrict__ hb,
    const float* __restrict__ agg,
    const __bf16* __restrict__ uW1t, const float* __restrict__ b1,
    const __bf16* __restrict__ uW2t, const float* __restrict__ b2)
{
  __shared__ __bf16 s_u[64][264];    // 528 B rows, 16-aligned; 132 dw -> 2-way (free)
  __shared__ __bf16 s_uh[64][136];
  int tid = threadIdx.x, n0 = blockIdx.x * 64;
  {
    int n = tid >> 2, t4 = tid & 3;
    const bf16x8* hr = (const bf16x8*)(hb + (size_t)(n0 + n) * 128);
    #pragma unroll
    for (int i = 0; i < 4; i++)
      *(bf16x8*)&s_u[n][t4 * 8 + 32 * i] = hr[t4 + 4 * i];
    const float4* ar = (const float4*)(agg + (size_t)(n0 + n) * 128);
    #pragma unroll
    for (int i = 0; i < 8; i++) {
      float4 v = ar[t4 + 4 * i];
      bf16x4 bv;
      bv[0] = (__bf16)v.x; bv[1] = (__bf16)v.y;
      bv[2] = (__bf16)v.z; bv[3] = (__bf16)v.w;
      *(bf16x4*)&s_u[n][128 + (t4 + 4 * i) * 4] = bv;
    }
  }
  __syncthreads();
  const int wv = tid >> 6, ln = tid & 63, lc = ln & 15, qd = ln >> 4;

  f32x4 acc2[4][2];
  #pragma unroll
  for (int nt = 0; nt < 2; nt++) {
    float bv = b2[wv * 32 + nt * 16 + lc];
    #pragma unroll
    for (int mt = 0; mt < 4; mt++) {
      acc2[mt][nt][0] = bv; acc2[mt][nt][1] = bv;
      acc2[mt][nt][2] = bv; acc2[mt][nt][3] = bv;
    }
  }

  for (int hf = 0; hf < 2; hf++) {
    f32x4 acc1[4][2];
    #pragma unroll
    for (int nt = 0; nt < 2; nt++) {
      float bv = b1[hf * 128 + wv * 32 + nt * 16 + lc];
      #pragma unroll
      for (int mt = 0; mt < 4; mt++) {
        acc1[mt][nt][0] = bv; acc1[mt][nt][1] = bv;
        acc1[mt][nt][2] = bv; acc1[mt][nt][3] = bv;
      }
    }
    #pragma unroll
    for (int kt = 0; kt < 8; kt++) {
      bf16x8 af[4];
      #pragma unroll
      for (int mt = 0; mt < 4; mt++)
        af[mt] = *(const bf16x8*)&s_u[mt * 16 + lc][kt * 32 + qd * 8];
      bf16x8 bw[2];
      #pragma unroll
      for (int nt = 0; nt < 2; nt++)
        bw[nt] = *(const bf16x8*)(uW1t +
                 (size_t)(hf * 128 + wv * 32 + nt * 16 + lc) * 256 + kt * 32 + qd * 8);
      #pragma unroll
      for (int mt = 0; mt < 4; mt++)
        #pragma unroll
        for (int nt = 0; nt < 2; nt++)
          acc1[mt][nt] = __builtin_amdgcn_mfma_f32_16x16x32_bf16(af[mt], bw[nt], acc1[mt][nt], 0, 0, 0);
    }
    __syncthreads();
    #pragma unroll
    for (int mt = 0; mt < 4; mt++)
      #pragma unroll
      for (int nt = 0; nt < 2; nt++) {
        int cc = wv * 32 + nt * 16 + lc;
        #pragma unroll
        for (int r = 0; r < 4; r++)
          s_uh[mt * 16 + qd * 4 + r][cc] = (__bf16)silu_f(acc1[mt][nt][r]);
      }
    __syncthreads();
    #pragma unroll
    for (int kt = 0; kt < 4; kt++) {
      bf16x8 a2[4];
      #pragma unroll
      for (int mt = 0; mt < 4; mt++)
        a2[mt] = *(const bf16x8*)&s_uh[mt * 16 + lc][kt * 32 + qd * 8];
      bf16x8 b2w[2];
      #pragma unroll
      for (int nt = 0; nt < 2; nt++)
        b2w[nt] = *(const bf16x8*)(uW2t +
                  (size_t)(wv * 32 + nt * 16 + lc) * 256 + hf * 128 + kt * 32 + qd * 8);
      #pragma unroll
      for (int mt = 0; mt < 4; mt++)
        #pragma unroll
        for (int nt = 0; nt < 2; nt++)
          acc2[mt][nt] = __builtin_amdgcn_mfma_f32_16x16x32_bf16(a2[mt], b2w[nt], acc2[mt][nt], 0, 0, 0);
    }
  }

  // residual epilogue
  #pragma unroll
  for (int mt = 0; mt < 4; mt++)
    #pragma unroll
    for (int nt = 0; nt < 2; nt++) {
      int c = wv * 32 + nt * 16 + lc;
      #pragma unroll
      for (int r = 0; r < 4; r++) {
        int n = n0 + mt * 16 + qd * 4 + r;
        float v = h[(size_t)n * 128 + c] + acc2[mt][nt][r];
        h[(size_t)n * 128 + c] = v;
        hb[(size_t)n * 128 + c] = (__bf16)v;
      }
    }
}

// ---------------- readout ----------------
__global__ __launch_bounds__(128) void readout_sum_kernel(
    const float* __restrict__ h, const int* __restrict__ batch,
    float* __restrict__ gsum, float* __restrict__ gcnt)
{
  int j = threadIdx.x;  // 128
  int n0 = blockIdx.x * 128;
  float acc = 0.f, cacc = 0.f;
  int cur = batch[n0];
  for (int i = 0; i < 128; i++) {
    int b = batch[n0 + i];
    if (b != cur) {
      atomicAdd(&gsum[cur * 128 + j], acc);
      if (j == 0) atomicAdd(&gcnt[cur], cacc);
      acc = 0.f; cacc = 0.f; cur = b;
    }
    acc += h[(size_t)(n0 + i) * 128 + j];
    cacc += 1.f;
  }
  atomicAdd(&gsum[cur * 128 + j], acc);
  if (j == 0) atomicAdd(&gcnt[cur], cacc);
}

__global__ __launch_bounds__(256) void readout_mlp_kernel(
    const float* __restrict__ gsum, const float* __restrict__ gcnt,
    const float* __restrict__ W1, const float* __restrict__ b1,
    const float* __restrict__ W2, const float* __restrict__ b2,
    float* __restrict__ out)
{
  __shared__ float g[8][128];
  __shared__ float hid[8][256];
  int tid = threadIdx.x;
  for (int i = tid; i < 8 * 128; i += 256) {
    int b = i >> 7, c = i & 127;
    g[b][c] = gsum[i] / fmaxf(gcnt[b], 1.0f);
  }
  __syncthreads();
  {
    float bb = b1[tid];
    float a[8];
    #pragma unroll
    for (int b = 0; b < 8; b++) a[b] = bb;
    for (int k = 0; k < 128; k++) {
      float w = W1[k * 256 + tid];
      #pragma unroll
      for (int b = 0; b < 8; b++) a[b] += g[b][k] * w;
    }
    #pragma unroll
    for (int b = 0; b < 8; b++) hid[b][tid] = silu_f(a[b]);
  }
  __syncthreads();
  int j = tid & 63, bg = tid >> 6;
  float a0 = b2[j], a1 = b2[j];
  for (int k = 0; k < 256; k++) {
    float w = W2[k * 64 + j];
    a0 += hid[bg * 2 + 0][k] * w;
    a1 += hid[bg * 2 + 1][k] * w;
  }
  out[(bg * 2 + 0) * 64 + j] = a0;
  out[(bg * 2 + 1) * 64 + j] = a1;
}

extern "C" void kernel_launch(void* const* d_in, const int* in_sizes, int n_in,
                              void* d_out, int out_size, void* d_ws, size_t ws_size,
                              hipStream_t stream) {
  const float* pos   = (const float*)d_in[0];
  const float* xfeat = (const float*)d_in[1];
  const int*   eidx  = (const int*)d_in[2];
  const int*   batch = (const int*)d_in[3];
  const float* eW1 = (const float*)d_in[4];
  const float* eb1 = (const float*)d_in[5];
  const float* eW2 = (const float*)d_in[6];
  const float* eb2 = (const float*)d_in[7];
  const float* mW1 = (const float*)d_in[8];
  const float* mb1 = (const float*)d_in[9];
  const float* mW2 = (const float*)d_in[10];
  const float* mb2 = (const float*)d_in[11];
  const float* uW1 = (const float*)d_in[12];
  const float* ub1 = (const float*)d_in[13];
  const float* uW2 = (const float*)d_in[14];
  const float* ub2 = (const float*)d_in[15];
  const float* rW1 = (const float*)d_in[16];
  const float* rb1 = (const float*)d_in[17];
  const float* rW2 = (const float*)d_in[18];
  const float* rb2 = (const float*)d_in[19];

  const int* srcI = eidx;
  const int* dstI = eidx + NEDGES;

  char* base = (char*)d_ws;
  float* h    = (float*)base;  base += (size_t)NATOMS * 128 * 4;
  float* agg  = (float*)base;  base += (size_t)NATOMS * 128 * 4;
  float* z1   = (float*)base;  base += (size_t)NATOMS * 256 * 4;
  float* z2   = (float*)base;  base += (size_t)NATOMS * 256 * 4;
  __bf16* hb  = (__bf16*)base; base += (size_t)NATOMS * 128 * 2;
  __bf16* efb = (__bf16*)base; base += (size_t)NEDGES * 16 * 2;
  __bf16* W1at = (__bf16*)base; base += (size_t)NLAYERS * 256 * 128 * 2;
  __bf16* W1bt = (__bf16*)base; base += (size_t)NLAYERS * 256 * 128 * 2;
  __bf16* W1ct = (__bf16*)base; base += (size_t)NLAYERS * 256 * 32 * 2;
  __bf16* W2t  = (__bf16*)base; base += (size_t)NLAYERS * 128 * 256 * 2;
  __bf16* uW1t = (__bf16*)base; base += (size_t)NLAYERS * 256 * 256 * 2;
  __bf16* uW2t = (__bf16*)base; base += (size_t)NLAYERS * 128 * 256 * 2;
  float* gsum = (float*)base;  base += 8 * 128 * 4;
  float* gcnt = (float*)base;  base += 8 * 4;
  int* counts = (int*)base;    base += (size_t)NATOMS * 4;
  int* cursor = (int*)base;    base += (size_t)NATOMS * 4;
  int* esrc   = (int*)base;    base += (size_t)NEDGES * 4;
  int* edst   = (int*)base;    base += (size_t)NEDGES * 4;

  // --- CSR preprocessing ---
  hipMemsetAsync(counts, 0, NATOMS * sizeof(int), stream);
  hist_kernel<<<NEDGES / 256, 256, 0, stream>>>(dstI, counts);
  scan_kernel<<<1, 1024, 0, stream>>>(counts, cursor);
  scatter_kernel<<<NEDGES / 256, 256, 0, stream>>>(srcI, dstI, cursor, esrc, edst);

  // --- weight conversion ---
  conv_t_kernel<<<dim3(128, NLAYERS), 256, 0, stream>>>(mW1, W1at, 256,   0, 128, 128, 272L*256, 256L*128);
  conv_t_kernel<<<dim3(128, NLAYERS), 256, 0, stream>>>(mW1, W1bt, 256, 128, 128, 128, 272L*256, 256L*128);
  conv_t_kernel<<<dim3( 32, NLAYERS), 256, 0, stream>>>(mW1, W1ct, 256, 256,  16,  32, 272L*256, 256L*32);
  conv_t_kernel<<<dim3(128, NLAYERS), 256, 0, stream>>>(mW2, W2t,  128,   0, 256, 256, 256L*128, 128L*256);
  conv_t_kernel<<<dim3(256, NLAYERS), 256, 0, stream>>>(uW1, uW1t, 256,   0, 256, 256, 256L*256, 256L*256);
  conv_t_kernel<<<dim3(128, NLAYERS), 256, 0, stream>>>(uW2, uW2t, 128,   0, 256, 256, 256L*128, 128L*256);

  embed_kernel<<<NATOMS, 128, 0, stream>>>(xfeat, eW1, eb1, eW2, eb2, h, hb);
  rbf_kernel<<<NEDGES / 256, 256, 0, stream>>>(pos, esrc, edst, efb);

  for (int l = 0; l < NLAYERS; l++) {
    zprep_kernel<<<NATOMS / 64, 256, 0, stream>>>(
        hb, mb1 + (size_t)l * 256,
        W1at + (size_t)l * 256 * 128, W1bt + (size_t)l * 256 * 128,
        z1, z2, agg);
    msg_mfma_kernel<<<NEDGES / TE, 256, 0, stream>>>(
        z1, z2, efb, esrc, edst,
        W1ct + (size_t)l * 256 * 32, W2t + (size_t)l * 128 * 256,
        mb2 + (size_t)l * 128, agg);
    upd_mfma_kernel<<<NATOMS / 64, 256, 0, stream>>>(
        h, hb, agg,
        uW1t + (size_t)l * 256 * 256, ub1 + (size_t)l * 256,
        uW2t + (size_t)l * 128 * 256, ub2 + (size_t)l * 128);
  }

  hipMemsetAsync(gsum, 0, (8 * 128 + 8) * sizeof(float), stream);
  readout_sum_kernel<<<NATOMS / 128, 128, 0, stream>>>(h, batch, gsum, gcnt);
  readout_mlp_kernel<<<1, 256, 0, stream>>>(gsum, gcnt, rW1, rb1, rW2, rb2,
                                            (float*)d_out);
}

// Round 5
// 986.587 us; speedup vs baseline: 10.9795x; 1.0621x over previous
//
#include <hip/hip_runtime.h>
#include <math.h>

#define NATOMS 16384
#define NEDGES 524288
#define NLAYERS 4
#define TE 64      // edges per block in msg kernel

typedef __bf16 bf16x8 __attribute__((ext_vector_type(8)));
typedef __bf16 bf16x4 __attribute__((ext_vector_type(4)));
typedef float f32x4 __attribute__((ext_vector_type(4)));

__device__ __forceinline__ float silu_f(float x) {
  return x / (1.0f + __expf(-x));
}

// ---------------- CSR preprocessing ----------------
__global__ __launch_bounds__(256) void hist_kernel(
    const int* __restrict__ dst, int* __restrict__ counts)
{
  int e = blockIdx.x * 256 + threadIdx.x;
  atomicAdd(&counts[dst[e]], 1);
}

__global__ __launch_bounds__(1024) void scan_kernel(
    const int* __restrict__ counts, int* __restrict__ cursor)
{
  __shared__ int buf[1024];
  __shared__ int carry_s;
  int tid = threadIdx.x;
  if (tid == 0) carry_s = 0;
  __syncthreads();
  for (int c = 0; c < 16; c++) {
    int v = counts[c * 1024 + tid];
    buf[tid] = v;
    __syncthreads();
    for (int off = 1; off < 1024; off <<= 1) {
      int t = (tid >= off) ? buf[tid - off] : 0;
      __syncthreads();
      buf[tid] += t;
      __syncthreads();
    }
    cursor[c * 1024 + tid] = buf[tid] - v + carry_s;
    __syncthreads();
    if (tid == 1023) carry_s += buf[1023];
    __syncthreads();
  }
}

__global__ __launch_bounds__(256) void scatter_kernel(
    const int* __restrict__ src, const int* __restrict__ dst,
    int* __restrict__ cursor, int* __restrict__ esrc, int* __restrict__ edst)
{
  int e = blockIdx.x * 256 + threadIdx.x;
  int d = dst[e];
  int p = atomicAdd(&cursor[d], 1);
  esrc[p] = src[e];
  edst[p] = d;
}

// ---------------- generic weight transpose+convert ----------------
__global__ __launch_bounds__(256) void conv_t_kernel(
    const float* __restrict__ W, __bf16* __restrict__ Wt,
    int ldN, int k0, int Kin, int Kpad, long lsrc, long ldst)
{
  long l = blockIdx.y;
  int i = blockIdx.x * 256 + threadIdx.x;
  int n = i / Kpad, k = i - n * Kpad;
  float v = (k < Kin) ? W[l * lsrc + (size_t)(k0 + k) * ldN + n] : 0.0f;
  Wt[l * ldst + (size_t)n * Kpad + k] = (__bf16)v;
}

// B1c[c][k]: k<16 -> identity delta(k, c%16); k>=16 -> mW1 row (256+k-16), col c
__global__ __launch_bounds__(256) void build_b1c_kernel(
    const float* __restrict__ mW1, __bf16* __restrict__ Bc)
{
  long l = blockIdx.y;
  int i = blockIdx.x * 256 + threadIdx.x;  // 256*32
  int c = i >> 5, k = i & 31;
  float v = (k < 16) ? ((k == (c & 15)) ? 1.0f : 0.0f)
                     : mW1[l * (272L * 256) + (size_t)(256 + k - 16) * 256 + c];
  Bc[l * (256L * 32) + i] = (__bf16)v;
}

// ---------------- embedding ----------------
__global__ __launch_bounds__(128) void embed_kernel(
    const float* __restrict__ x, const float* __restrict__ W1,
    const float* __restrict__ b1, const float* __restrict__ W2,
    const float* __restrict__ b2, float* __restrict__ h,
    __bf16* __restrict__ hb)
{
  int n = blockIdx.x;
  int j = threadIdx.x;
  __shared__ float xs[26];
  __shared__ float hid[128];
  if (j < 26) xs[j] = x[n * 26 + j];
  __syncthreads();
  float acc = b1[j];
  #pragma unroll
  for (int k = 0; k < 26; k++) acc += xs[k] * W1[k * 128 + j];
  hid[j] = silu_f(acc);
  __syncthreads();
  float acc2 = b2[j];
  #pragma unroll 8
  for (int k = 0; k < 128; k++) acc2 += hid[k] * W2[k * 128 + j];
  h[(size_t)n * 128 + j] = acc2;
  hb[(size_t)n * 128 + j] = (__bf16)acc2;
}

// ---------------- edge RBF (sorted slot order) ----------------
__global__ __launch_bounds__(256) void rbf_kernel(
    const float* __restrict__ pos, const int* __restrict__ esrc,
    const int* __restrict__ edst, __bf16* __restrict__ efb)
{
  int e = blockIdx.x * 256 + threadIdx.x;
  int s = esrc[e], d = edst[e];
  float dx = pos[d * 3 + 0] - pos[s * 3 + 0];
  float dy = pos[d * 3 + 1] - pos[s * 3 + 1];
  float dz = pos[d * 3 + 2] - pos[s * 3 + 2];
  float dist = sqrtf(dx * dx + dy * dy + dz * dz + 1e-12f);
  float env = (dist < 10.0f)
                  ? 0.5f * (cosf(3.14159265358979f * dist * 0.1f) + 1.0f)
                  : 0.0f;
  bf16x8 o0, o1;
  #pragma unroll
  for (int i = 0; i < 16; i++) {
    float c = (10.0f / 15.0f) * (float)i;
    float t = dist - c;
    float v = env * __expf(-t * t * 1.28f);
    if (i < 8) o0[i] = (__bf16)v; else o1[i - 8] = (__bf16)v;
  }
  *(bf16x8*)(efb + (size_t)e * 16 + 0) = o0;
  *(bf16x8*)(efb + (size_t)e * 16 + 8) = o1;
}

// ---------------- zprep: z1b = bf16(h@W1a), z2b = bf16(h@W1b + b1); zeros agg ----------------
__global__ __launch_bounds__(256) void zprep_kernel(
    const __bf16* __restrict__ hb, const float* __restrict__ b1,
    const __bf16* __restrict__ W1at, const __bf16* __restrict__ W1bt,
    __bf16* __restrict__ z1b, __bf16* __restrict__ z2b, float* __restrict__ agg)
{
  __shared__ __bf16 s_n[64][136];
  int tid = threadIdx.x, n0 = blockIdx.x * 64;
  {
    int n = tid >> 2, t4 = tid & 3;
    const bf16x8* hr = (const bf16x8*)(hb + (size_t)(n0 + n) * 128);
    #pragma unroll
    for (int i = 0; i < 4; i++)
      *(bf16x8*)&s_n[n][t4 * 8 + 32 * i] = hr[t4 + 4 * i];
  }
  {
    float4 zz = make_float4(0.f, 0.f, 0.f, 0.f);
    float4* ap = (float4*)(agg + (size_t)n0 * 128);
    for (int i = tid; i < 64 * 128 / 4; i += 256) ap[i] = zz;
  }
  __syncthreads();
  const int wv = tid >> 6, ln = tid & 63, lc = ln & 15, qd = ln >> 4;
  for (int cp = 0; cp < 2; cp++) {
    f32x4 aA[4][2], aB[4][2];
    #pragma unroll
    for (int nt = 0; nt < 2; nt++) {
      float bv = b1[cp * 128 + wv * 32 + nt * 16 + lc];
      #pragma unroll
      for (int mt = 0; mt < 4; mt++) {
        aA[mt][nt][0] = 0.f; aA[mt][nt][1] = 0.f;
        aA[mt][nt][2] = 0.f; aA[mt][nt][3] = 0.f;
        aB[mt][nt][0] = bv; aB[mt][nt][1] = bv;
        aB[mt][nt][2] = bv; aB[mt][nt][3] = bv;
      }
    }
    #pragma unroll
    for (int kt = 0; kt < 4; kt++) {
      bf16x8 af[4];
      #pragma unroll
      for (int mt = 0; mt < 4; mt++)
        af[mt] = *(const bf16x8*)&s_n[mt * 16 + lc][kt * 32 + qd * 8];
      bf16x8 bwA[2], bwB[2];
      #pragma unroll
      for (int nt = 0; nt < 2; nt++) {
        int c = cp * 128 + wv * 32 + nt * 16 + lc;
        bwA[nt] = *(const bf16x8*)(W1at + (size_t)c * 128 + kt * 32 + qd * 8);
        bwB[nt] = *(const bf16x8*)(W1bt + (size_t)c * 128 + kt * 32 + qd * 8);
      }
      #pragma unroll
      for (int mt = 0; mt < 4; mt++)
        #pragma unroll
        for (int nt = 0; nt < 2; nt++) {
          aA[mt][nt] = __builtin_amdgcn_mfma_f32_16x16x32_bf16(af[mt], bwA[nt], aA[mt][nt], 0, 0, 0);
          aB[mt][nt] = __builtin_amdgcn_mfma_f32_16x16x32_bf16(af[mt], bwB[nt], aB[mt][nt], 0, 0, 0);
        }
    }
    #pragma unroll
    for (int mt = 0; mt < 4; mt++)
      #pragma unroll
      for (int nt = 0; nt < 2; nt++) {
        int c = cp * 128 + wv * 32 + nt * 16 + lc;
        #pragma unroll
        for (int r = 0; r < 4; r++) {
          int n = n0 + mt * 16 + qd * 4 + r;
          z1b[(size_t)n * 256 + c] = (__bf16)aA[mt][nt][r];
          z2b[(size_t)n * 256 + c] = (__bf16)aB[mt][nt][r];
        }
      }
  }
}

// ---------------- fused message MLP v3 ----------------
// zs = z1b[src]+z2b[dst] staged in LDS (bf16); GEMM1 tile = ONE K32 MFMA with
// A = [zs_cols | ef] and B = [I16 ; W1c] (precomputed B1c)  ->  C = zs + ef@W1c.
// LDS map (bytes):
//   s_zs  [64][136] bf16 :     0 .. 17408
//   s_h   [64][136] bf16 : 17408 .. 34816
//   s_msg [64][132] f32  :     0 .. 33792   (epilogue alias of s_zs+s_h)
//   s_ef  [64][24]  bf16 : 34816 .. 37888
//   s_dst [64] int       : 37888 .. 38144
//   s_src [64] int       : 38144 .. 38400   -> 4 blocks/CU
#define MS_H_OFF   17408
#define MS_EF_OFF  34816
#define MS_DST_OFF 37888
#define MS_SRC_OFF 38144
#define MS_BYTES   38400

__global__ __launch_bounds__(256, 4) void msg_mfma_kernel(
    const __bf16* __restrict__ z1b, const __bf16* __restrict__ z2b,
    const __bf16* __restrict__ efb,
    const int* __restrict__ esrc, const int* __restrict__ edst,
    const __bf16* __restrict__ B1c, const __bf16* __restrict__ W2t,
    const float* __restrict__ b2, float* __restrict__ agg)
{
  __shared__ __align__(16) char smem[MS_BYTES];
  __bf16 (*s_zs)[136] = (__bf16(*)[136])(smem);
  __bf16 (*s_h)[136]  = (__bf16(*)[136])(smem + MS_H_OFF);
  __bf16 (*s_ef)[24]  = (__bf16(*)[24])(smem + MS_EF_OFF);
  float (*s_msg)[132] = (float(*)[132])(smem);
  int* s_dst = (int*)(smem + MS_DST_OFF);
  int* s_src = (int*)(smem + MS_SRC_OFF);

  int tid = threadIdx.x, e0 = blockIdx.x * TE;
  if (tid < TE) s_dst[tid] = edst[e0 + tid];
  else if (tid < 2 * TE) s_src[tid - TE] = esrc[e0 + tid - TE];
  {
    int e = tid >> 2, t4 = tid & 3;
    if (t4 < 2)
      *(bf16x8*)&s_ef[e][t4 * 8] =
          *(const bf16x8*)(efb + (size_t)(e0 + e) * 16 + t4 * 8);
  }
  __syncthreads();

  const int wv = tid >> 6, ln = tid & 63, lc = ln & 15, qd = ln >> 4;
  const int m_row = tid >> 2, t4 = tid & 3;   // staging assignment
  const int sidx = s_src[m_row], didx = s_dst[m_row];

  f32x4 acc2[4][2];
  #pragma unroll
  for (int nt = 0; nt < 2; nt++) {
    float bv = b2[wv * 32 + nt * 16 + lc];
    #pragma unroll
    for (int mt = 0; mt < 4; mt++) {
      acc2[mt][nt][0] = bv; acc2[mt][nt][1] = bv;
      acc2[mt][nt][2] = bv; acc2[mt][nt][3] = bv;
    }
  }

  for (int hf = 0; hf < 2; hf++) {
    // ---- stage zs = z1b[src] + z2b[dst] for this 128-col half ----
    {
      const __bf16* z1r = z1b + (size_t)sidx * 256 + hf * 128;
      const __bf16* z2r = z2b + (size_t)didx * 256 + hf * 128;
      #pragma unroll
      for (int cc = 0; cc < 4; cc++) {
        int col = cc * 32 + t4 * 8;
        bf16x8 a = *(const bf16x8*)(z1r + col);
        bf16x8 b = *(const bf16x8*)(z2r + col);
        bf16x8 o;
        #pragma unroll
        for (int j = 0; j < 8; j++) o[j] = (__bf16)((float)a[j] + (float)b[j]);
        *(bf16x8*)&s_zs[m_row][col] = o;
      }
    }
    __syncthreads();

    // ---- GEMM1: one MFMA per 16x16 tile (identity|W1c trick) ----
    f32x4 acc1[4][2];
    bf16x8 bfrag[2];
    #pragma unroll
    for (int nt = 0; nt < 2; nt++) {
      int c = hf * 128 + wv * 32 + nt * 16 + lc;
      bfrag[nt] = *(const bf16x8*)(B1c + (size_t)c * 32 + qd * 8);
    }
    #pragma unroll
    for (int mt = 0; mt < 4; mt++) {
      #pragma unroll
      for (int nt = 0; nt < 2; nt++) {
        const __bf16* ap = (qd < 2)
            ? &s_zs[mt * 16 + lc][wv * 32 + nt * 16 + qd * 8]
            : &s_ef[mt * 16 + lc][(qd - 2) * 8];
        bf16x8 af = *(const bf16x8*)ap;
        f32x4 z; z[0] = 0.f; z[1] = 0.f; z[2] = 0.f; z[3] = 0.f;
        acc1[mt][nt] = __builtin_amdgcn_mfma_f32_16x16x32_bf16(af, bfrag[nt], z, 0, 0, 0);
      }
    }

    // ---- silu -> s_h (C-layout -> A-layout) ----
    #pragma unroll
    for (int mt = 0; mt < 4; mt++)
      #pragma unroll
      for (int nt = 0; nt < 2; nt++) {
        int cc = wv * 32 + nt * 16 + lc;
        #pragma unroll
        for (int r = 0; r < 4; r++)
          s_h[mt * 16 + qd * 4 + r][cc] = (__bf16)silu_f(acc1[mt][nt][r]);
      }
    __syncthreads();

    // ---- GEMM2 partial over this half's 128 hidden cols ----
    #pragma unroll
    for (int kt = 0; kt < 4; kt++) {
      bf16x8 a2[4];
      #pragma unroll
      for (int mt = 0; mt < 4; mt++)
        a2[mt] = *(const bf16x8*)&s_h[mt * 16 + lc][kt * 32 + qd * 8];
      bf16x8 b2w[2];
      #pragma unroll
      for (int nt = 0; nt < 2; nt++)
        b2w[nt] = *(const bf16x8*)(W2t +
                  (size_t)(wv * 32 + nt * 16 + lc) * 256 + hf * 128 + kt * 32 + qd * 8);
      #pragma unroll
      for (int mt = 0; mt < 4; mt++)
        #pragma unroll
        for (int nt = 0; nt < 2; nt++)
          acc2[mt][nt] = __builtin_amdgcn_mfma_f32_16x16x32_bf16(a2[mt], b2w[nt], acc2[mt][nt], 0, 0, 0);
    }
  }

  // ---- epilogue: C-layout -> LDS fp32, segmented column-scan ----
  __syncthreads();
  #pragma unroll
  for (int mt = 0; mt < 4; mt++)
    #pragma unroll
    for (int nt = 0; nt < 2; nt++) {
      int c = wv * 32 + nt * 16 + lc;
      #pragma unroll
      for (int r = 0; r < 4; r++)
        s_msg[mt * 16 + qd * 4 + r][c] = acc2[mt][nt][r];
    }
  __syncthreads();

  if (tid < 128) {
    int j = tid;
    float acc = 0.0f;
    int cur = s_dst[0];
    for (int m = 0; m < 64; m++) {
      int d = s_dst[m];
      if (d != cur) {
        atomicAdd(&agg[(size_t)cur * 128 + j], acc);
        acc = 0.0f;
        cur = d;
      }
      acc += s_msg[m][j];
    }
    atomicAdd(&agg[(size_t)cur * 128 + j], acc);
  }
}

// ---------------- node update MLP (bf16 MFMA, residual) ----------------
__global__ __launch_bounds__(256, 3) void upd_mfma_kernel(
    float* __restrict__ h, __bf16* __restrict__ hb,
    const float* __restrict__ agg,
    const __bf16* __restrict__ uW1t, const float* __restrict__ b1,
    const __bf16* __restrict__ uW2t, const float* __restrict__ b2)
{
  __shared__ __bf16 s_u[64][264];
  __shared__ __bf16 s_uh[64][136];
  int tid = threadIdx.x, n0 = blockIdx.x * 64;
  {
    int n = tid >> 2, t4 = tid & 3;
    const bf16x8* hr = (const bf16x8*)(hb + (size_t)(n0 + n) * 128);
    #pragma unroll
    for (int i = 0; i < 4; i++)
      *(bf16x8*)&s_u[n][t4 * 8 + 32 * i] = hr[t4 + 4 * i];
    const float4* ar = (const float4*)(agg + (size_t)(n0 + n) * 128);
    #pragma unroll
    for (int i = 0; i < 8; i++) {
      float4 v = ar[t4 + 4 * i];
      bf16x4 bv;
      bv[0] = (__bf16)v.x; bv[1] = (__bf16)v.y;
      bv[2] = (__bf16)v.z; bv[3] = (__bf16)v.w;
      *(bf16x4*)&s_u[n][128 + (t4 + 4 * i) * 4] = bv;
    }
  }
  __syncthreads();
  const int wv = tid >> 6, ln = tid & 63, lc = ln & 15, qd = ln >> 4;

  f32x4 acc2[4][2];
  #pragma unroll
  for (int nt = 0; nt < 2; nt++) {
    float bv = b2[wv * 32 + nt * 16 + lc];
    #pragma unroll
    for (int mt = 0; mt < 4; mt++) {
      acc2[mt][nt][0] = bv; acc2[mt][nt][1] = bv;
      acc2[mt][nt][2] = bv; acc2[mt][nt][3] = bv;
    }
  }

  for (int hf = 0; hf < 2; hf++) {
    f32x4 acc1[4][2];
    #pragma unroll
    for (int nt = 0; nt < 2; nt++) {
      float bv = b1[hf * 128 + wv * 32 + nt * 16 + lc];
      #pragma unroll
      for (int mt = 0; mt < 4; mt++) {
        acc1[mt][nt][0] = bv; acc1[mt][nt][1] = bv;
        acc1[mt][nt][2] = bv; acc1[mt][nt][3] = bv;
      }
    }
    #pragma unroll
    for (int kt = 0; kt < 8; kt++) {
      bf16x8 af[4];
      #pragma unroll
      for (int mt = 0; mt < 4; mt++)
        af[mt] = *(const bf16x8*)&s_u[mt * 16 + lc][kt * 32 + qd * 8];
      bf16x8 bw[2];
      #pragma unroll
      for (int nt = 0; nt < 2; nt++)
        bw[nt] = *(const bf16x8*)(uW1t +
                 (size_t)(hf * 128 + wv * 32 + nt * 16 + lc) * 256 + kt * 32 + qd * 8);
      #pragma unroll
      for (int mt = 0; mt < 4; mt++)
        #pragma unroll
        for (int nt = 0; nt < 2; nt++)
          acc1[mt][nt] = __builtin_amdgcn_mfma_f32_16x16x32_bf16(af[mt], bw[nt], acc1[mt][nt], 0, 0, 0);
    }
    __syncthreads();
    #pragma unroll
    for (int mt = 0; mt < 4; mt++)
      #pragma unroll
      for (int nt = 0; nt < 2; nt++) {
        int cc = wv * 32 + nt * 16 + lc;
        #pragma unroll
        for (int r = 0; r < 4; r++)
          s_uh[mt * 16 + qd * 4 + r][cc] = (__bf16)silu_f(acc1[mt][nt][r]);
      }
    __syncthreads();
    #pragma unroll
    for (int kt = 0; kt < 4; kt++) {
      bf16x8 a2[4];
      #pragma unroll
      for (int mt = 0; mt < 4; mt++)
        a2[mt] = *(const bf16x8*)&s_uh[mt * 16 + lc][kt * 32 + qd * 8];
      bf16x8 b2w[2];
      #pragma unroll
      for (int nt = 0; nt < 2; nt++)
        b2w[nt] = *(const bf16x8*)(uW2t +
                  (size_t)(wv * 32 + nt * 16 + lc) * 256 + hf * 128 + kt * 32 + qd * 8);
      #pragma unroll
      for (int mt = 0; mt < 4; mt++)
        #pragma unroll
        for (int nt = 0; nt < 2; nt++)
          acc2[mt][nt] = __builtin_amdgcn_mfma_f32_16x16x32_bf16(a2[mt], b2w[nt], acc2[mt][nt], 0, 0, 0);
    }
  }

  #pragma unroll
  for (int mt = 0; mt < 4; mt++)
    #pragma unroll
    for (int nt = 0; nt < 2; nt++) {
      int c = wv * 32 + nt * 16 + lc;
      #pragma unroll
      for (int r = 0; r < 4; r++) {
        int n = n0 + mt * 16 + qd * 4 + r;
        float v = h[(size_t)n * 128 + c] + acc2[mt][nt][r];
        h[(size_t)n * 128 + c] = v;
        hb[(size_t)n * 128 + c] = (__bf16)v;
      }
    }
}

// ---------------- readout ----------------
__global__ __launch_bounds__(128) void readout_sum_kernel(
    const float* __restrict__ h, const int* __restrict__ batch,
    float* __restrict__ gsum, float* __restrict__ gcnt)
{
  int j = threadIdx.x;
  int n0 = blockIdx.x * 128;
  float acc = 0.f, cacc = 0.f;
  int cur = batch[n0];
  for (int i = 0; i < 128; i++) {
    int b = batch[n0 + i];
    if (b != cur) {
      atomicAdd(&gsum[cur * 128 + j], acc);
      if (j == 0) atomicAdd(&gcnt[cur], cacc);
      acc = 0.f; cacc = 0.f; cur = b;
    }
    acc += h[(size_t)(n0 + i) * 128 + j];
    cacc += 1.f;
  }
  atomicAdd(&gsum[cur * 128 + j], acc);
  if (j == 0) atomicAdd(&gcnt[cur], cacc);
}

__global__ __launch_bounds__(256) void readout_mlp_kernel(
    const float* __restrict__ gsum, const float* __restrict__ gcnt,
    const float* __restrict__ W1, const float* __restrict__ b1,
    const float* __restrict__ W2, const float* __restrict__ b2,
    float* __restrict__ out)
{
  __shared__ float g[8][128];
  __shared__ float hid[8][256];
  int tid = threadIdx.x;
  for (int i = tid; i < 8 * 128; i += 256) {
    int b = i >> 7, c = i & 127;
    g[b][c] = gsum[i] / fmaxf(gcnt[b], 1.0f);
  }
  __syncthreads();
  {
    float bb = b1[tid];
    float a[8];
    #pragma unroll
    for (int b = 0; b < 8; b++) a[b] = bb;
    for (int k = 0; k < 128; k++) {
      float w = W1[k * 256 + tid];
      #pragma unroll
      for (int b = 0; b < 8; b++) a[b] += g[b][k] * w;
    }
    #pragma unroll
    for (int b = 0; b < 8; b++) hid[b][tid] = silu_f(a[b]);
  }
  __syncthreads();
  int j = tid & 63, bg = tid >> 6;
  float a0 = b2[j], a1 = b2[j];
  for (int k = 0; k < 256; k++) {
    float w = W2[k * 64 + j];
    a0 += hid[bg * 2 + 0][k] * w;
    a1 += hid[bg * 2 + 1][k] * w;
  }
  out[(bg * 2 + 0) * 64 + j] = a0;
  out[(bg * 2 + 1) * 64 + j] = a1;
}

extern "C" void kernel_launch(void* const* d_in, const int* in_sizes, int n_in,
                              void* d_out, int out_size, void* d_ws, size_t ws_size,
                              hipStream_t stream) {
  const float* pos   = (const float*)d_in[0];
  const float* xfeat = (const float*)d_in[1];
  const int*   eidx  = (const int*)d_in[2];
  const int*   batch = (const int*)d_in[3];
  const float* eW1 = (const float*)d_in[4];
  const float* eb1 = (const float*)d_in[5];
  const float* eW2 = (const float*)d_in[6];
  const float* eb2 = (const float*)d_in[7];
  const float* mW1 = (const float*)d_in[8];
  const float* mb1 = (const float*)d_in[9];
  const float* mW2 = (const float*)d_in[10];
  const float* mb2 = (const float*)d_in[11];
  const float* uW1 = (const float*)d_in[12];
  const float* ub1 = (const float*)d_in[13];
  const float* uW2 = (const float*)d_in[14];
  const float* ub2 = (const float*)d_in[15];
  const float* rW1 = (const float*)d_in[16];
  const float* rb1 = (const float*)d_in[17];
  const float* rW2 = (const float*)d_in[18];
  const float* rb2 = (const float*)d_in[19];

  const int* srcI = eidx;
  const int* dstI = eidx + NEDGES;

  char* base = (char*)d_ws;
  float* h    = (float*)base;  base += (size_t)NATOMS * 128 * 4;
  float* agg  = (float*)base;  base += (size_t)NATOMS * 128 * 4;
  __bf16* z1b = (__bf16*)base; base += (size_t)NATOMS * 256 * 2;
  __bf16* z2b = (__bf16*)base; base += (size_t)NATOMS * 256 * 2;
  __bf16* hb  = (__bf16*)base; base += (size_t)NATOMS * 128 * 2;
  __bf16* efb = (__bf16*)base; base += (size_t)NEDGES * 16 * 2;
  __bf16* W1at = (__bf16*)base; base += (size_t)NLAYERS * 256 * 128 * 2;
  __bf16* W1bt = (__bf16*)base; base += (size_t)NLAYERS * 256 * 128 * 2;
  __bf16* B1c  = (__bf16*)base; base += (size_t)NLAYERS * 256 * 32 * 2;
  __bf16* W2t  = (__bf16*)base; base += (size_t)NLAYERS * 128 * 256 * 2;
  __bf16* uW1t = (__bf16*)base; base += (size_t)NLAYERS * 256 * 256 * 2;
  __bf16* uW2t = (__bf16*)base; base += (size_t)NLAYERS * 128 * 256 * 2;
  float* gsum = (float*)base;  base += 8 * 128 * 4;
  float* gcnt = (float*)base;  base += 8 * 4;
  int* counts = (int*)base;    base += (size_t)NATOMS * 4;
  int* cursor = (int*)base;    base += (size_t)NATOMS * 4;
  int* esrc   = (int*)base;    base += (size_t)NEDGES * 4;
  int* edst   = (int*)base;    base += (size_t)NEDGES * 4;

  // --- CSR preprocessing ---
  hipMemsetAsync(counts, 0, NATOMS * sizeof(int), stream);
  hist_kernel<<<NEDGES / 256, 256, 0, stream>>>(dstI, counts);
  scan_kernel<<<1, 1024, 0, stream>>>(counts, cursor);
  scatter_kernel<<<NEDGES / 256, 256, 0, stream>>>(srcI, dstI, cursor, esrc, edst);

  // --- weight conversion ---
  conv_t_kernel<<<dim3(128, NLAYERS), 256, 0, stream>>>(mW1, W1at, 256,   0, 128, 128, 272L*256, 256L*128);
  conv_t_kernel<<<dim3(128, NLAYERS), 256, 0, stream>>>(mW1, W1bt, 256, 128, 128, 128, 272L*256, 256L*128);
  build_b1c_kernel<<<dim3(32, NLAYERS), 256, 0, stream>>>(mW1, B1c);
  conv_t_kernel<<<dim3(128, NLAYERS), 256, 0, stream>>>(mW2, W2t,  128,   0, 256, 256, 256L*128, 128L*256);
  conv_t_kernel<<<dim3(256, NLAYERS), 256, 0, stream>>>(uW1, uW1t, 256,   0, 256, 256, 256L*256, 256L*256);
  conv_t_kernel<<<dim3(128, NLAYERS), 256, 0, stream>>>(uW2, uW2t, 128,   0, 256, 256, 256L*128, 128L*256);

  embed_kernel<<<NATOMS, 128, 0, stream>>>(xfeat, eW1, eb1, eW2, eb2, h, hb);
  rbf_kernel<<<NEDGES / 256, 256, 0, stream>>>(pos, esrc, edst, efb);

  for (int l = 0; l < NLAYERS; l++) {
    zprep_kernel<<<NATOMS / 64, 256, 0, stream>>>(
        hb, mb1 + (size_t)l * 256,
        W1at + (size_t)l * 256 * 128, W1bt + (size_t)l * 256 * 128,
        z1b, z2b, agg);
    msg_mfma_kernel<<<NEDGES / TE, 256, 0, stream>>>(
        z1b, z2b, efb, esrc, edst,
        B1c + (size_t)l * 256 * 32, W2t + (size_t)l * 128 * 256,
        mb2 + (size_t)l * 128, agg);
    upd_mfma_kernel<<<NATOMS / 64, 256, 0, stream>>>(
        h, hb, agg,
        uW1t + (size_t)l * 256 * 256, ub1 + (size_t)l * 256,
        uW2t + (size_t)l * 128 * 256, ub2 + (size_t)l * 128);
  }

  hipMemsetAsync(gsum, 0, (8 * 128 + 8) * sizeof(float), stream);
  readout_sum_kernel<<<NATOMS / 128, 128, 0, stream>>>(h, batch, gsum, gcnt);
  readout_mlp_kernel<<<1, 256, 0, stream>>>(gsum, gcnt, rW1, rb1, rW2, rb2,
                                            (float*)d_out);
}

// Round 6
// 871.661 us; speedup vs baseline: 12.4272x; 1.1318x over previous
//
#include <hip/hip_runtime.h>
#include <math.h>

#define NATOMS 16384
#define NEDGES 524288
#define NLAYERS 4
#define TE 64      // edges per block in msg kernel

typedef __bf16 bf16x8 __attribute__((ext_vector_type(8)));
typedef __bf16 bf16x4 __attribute__((ext_vector_type(4)));
typedef float f32x4 __attribute__((ext_vector_type(4)));

__device__ __forceinline__ float silu_f(float x) {
  return x / (1.0f + __expf(-x));
}

// ---------------- CSR preprocessing ----------------
__global__ __launch_bounds__(256) void hist_kernel(
    const int* __restrict__ dst, int* __restrict__ counts)
{
  int e = blockIdx.x * 256 + threadIdx.x;
  atomicAdd(&counts[dst[e]], 1);
}

__global__ __launch_bounds__(1024) void scan_kernel(
    const int* __restrict__ counts, int* __restrict__ cursor)
{
  __shared__ int buf[1024];
  __shared__ int carry_s;
  int tid = threadIdx.x;
  if (tid == 0) carry_s = 0;
  __syncthreads();
  for (int c = 0; c < 16; c++) {
    int v = counts[c * 1024 + tid];
    buf[tid] = v;
    __syncthreads();
    for (int off = 1; off < 1024; off <<= 1) {
      int t = (tid >= off) ? buf[tid - off] : 0;
      __syncthreads();
      buf[tid] += t;
      __syncthreads();
    }
    cursor[c * 1024 + tid] = buf[tid] - v + carry_s;
    __syncthreads();
    if (tid == 1023) carry_s += buf[1023];
    __syncthreads();
  }
}

__global__ __launch_bounds__(256) void scatter_kernel(
    const int* __restrict__ src, const int* __restrict__ dst,
    int* __restrict__ cursor, int* __restrict__ esrc, int* __restrict__ edst)
{
  int e = blockIdx.x * 256 + threadIdx.x;
  int d = dst[e];
  int p = atomicAdd(&cursor[d], 1);
  esrc[p] = src[e];
  edst[p] = d;
}

__global__ __launch_bounds__(256) void degf_kernel(
    const int* __restrict__ counts, float* __restrict__ degf)
{
  int n = blockIdx.x * 256 + threadIdx.x;
  degf[n] = (float)counts[n];
}

// ---------------- weight prep ----------------
__global__ __launch_bounds__(256) void conv_t_kernel(
    const float* __restrict__ W, __bf16* __restrict__ Wt,
    int ldN, int k0, int Kin, int Kpad, long lsrc, long ldst)
{
  long l = blockIdx.y;
  int i = blockIdx.x * 256 + threadIdx.x;
  int n = i / Kpad, k = i - n * Kpad;
  float v = (k < Kin) ? W[l * lsrc + (size_t)(k0 + k) * ldN + n] : 0.0f;
  Wt[l * ldst + (size_t)n * Kpad + k] = (__bf16)v;
}

// B1c[c][k]: k<16 -> identity delta(k, c%16); k>=16 -> mW1 row (256+k-16), col c
__global__ __launch_bounds__(256) void build_b1c_kernel(
    const float* __restrict__ mW1, __bf16* __restrict__ Bc)
{
  long l = blockIdx.y;
  int i = blockIdx.x * 256 + threadIdx.x;  // 256*32
  int c = i >> 5, k = i & 31;
  float v = (k < 16) ? ((k == (c & 15)) ? 1.0f : 0.0f)
                     : mW1[l * (272L * 256) + (size_t)(256 + k - 16) * 256 + c];
  Bc[l * (256L * 32) + i] = (__bf16)v;
}

// W2u[l] = mW2[l] (256x128) @ uW1[l][128:256,:] (128x256)  -> fp32 (256x256)
__global__ __launch_bounds__(256) void w2u_kernel(
    const float* __restrict__ mW2, const float* __restrict__ uW1,
    float* __restrict__ W2u)
{
  long l = blockIdx.y;
  int r = blockIdx.x, c = threadIdx.x;
  float acc = 0.0f;
  for (int k = 0; k < 128; k++)
    acc += mW2[(l * 256 + r) * 128 + k] *
           uW1[l * 65536 + (size_t)(128 + k) * 256 + c];
  W2u[(l * 256 + r) * 256 + c] = acc;
}

// b2u[l][c] = sum_k mb2[l][k] * uW1[l][128+k][c]
__global__ __launch_bounds__(256) void b2u_kernel(
    const float* __restrict__ mb2, const float* __restrict__ uW1,
    float* __restrict__ b2u)
{
  long l = blockIdx.x;
  int c = threadIdx.x;
  float acc = 0.0f;
  for (int k = 0; k < 128; k++)
    acc += mb2[l * 128 + k] * uW1[l * 65536 + (size_t)(128 + k) * 256 + c];
  b2u[l * 256 + c] = acc;
}

// uW1ft[l][n][kk] (256 x 384): kk<128 -> uW1[l][kk][n]; else W2u[l][kk-128][n]
__global__ __launch_bounds__(256) void build_uw1ft_kernel(
    const float* __restrict__ uW1, const float* __restrict__ W2u,
    __bf16* __restrict__ Wt)
{
  long l = blockIdx.y;
  int i = blockIdx.x * 256 + threadIdx.x;  // 256*384
  int n = i / 384, k = i - n * 384;
  float v = (k < 128) ? uW1[l * 65536 + (size_t)k * 256 + n]
                      : W2u[l * 65536 + (size_t)(k - 128) * 256 + n];
  Wt[l * (256L * 384) + i] = (__bf16)v;
}

// ---------------- embedding ----------------
__global__ __launch_bounds__(128) void embed_kernel(
    const float* __restrict__ x, const float* __restrict__ W1,
    const float* __restrict__ b1, const float* __restrict__ W2,
    const float* __restrict__ b2, float* __restrict__ h,
    __bf16* __restrict__ hb)
{
  int n = blockIdx.x;
  int j = threadIdx.x;
  __shared__ float xs[26];
  __shared__ float hid[128];
  if (j < 26) xs[j] = x[n * 26 + j];
  __syncthreads();
  float acc = b1[j];
  #pragma unroll
  for (int k = 0; k < 26; k++) acc += xs[k] * W1[k * 128 + j];
  hid[j] = silu_f(acc);
  __syncthreads();
  float acc2 = b2[j];
  #pragma unroll 8
  for (int k = 0; k < 128; k++) acc2 += hid[k] * W2[k * 128 + j];
  h[(size_t)n * 128 + j] = acc2;
  hb[(size_t)n * 128 + j] = (__bf16)acc2;
}

// ---------------- edge RBF (sorted slot order) ----------------
__global__ __launch_bounds__(256) void rbf_kernel(
    const float* __restrict__ pos, const int* __restrict__ esrc,
    const int* __restrict__ edst, __bf16* __restrict__ efb)
{
  int e = blockIdx.x * 256 + threadIdx.x;
  int s = esrc[e], d = edst[e];
  float dx = pos[d * 3 + 0] - pos[s * 3 + 0];
  float dy = pos[d * 3 + 1] - pos[s * 3 + 1];
  float dz = pos[d * 3 + 2] - pos[s * 3 + 2];
  float dist = sqrtf(dx * dx + dy * dy + dz * dz + 1e-12f);
  float env = (dist < 10.0f)
                  ? 0.5f * (cosf(3.14159265358979f * dist * 0.1f) + 1.0f)
                  : 0.0f;
  bf16x8 o0, o1;
  #pragma unroll
  for (int i = 0; i < 16; i++) {
    float c = (10.0f / 15.0f) * (float)i;
    float t = dist - c;
    float v = env * __expf(-t * t * 1.28f);
    if (i < 8) o0[i] = (__bf16)v; else o1[i - 8] = (__bf16)v;
  }
  *(bf16x8*)(efb + (size_t)e * 16 + 0) = o0;
  *(bf16x8*)(efb + (size_t)e * 16 + 8) = o1;
}

// ---------------- zprep: z1b = bf16(h@W1a), z2b = bf16(h@W1b + b1); zeros aggH ----------------
__global__ __launch_bounds__(256) void zprep_kernel(
    const __bf16* __restrict__ hb, const float* __restrict__ b1,
    const __bf16* __restrict__ W1at, const __bf16* __restrict__ W1bt,
    __bf16* __restrict__ z1b, __bf16* __restrict__ z2b, float* __restrict__ aggH)
{
  __shared__ __bf16 s_n[64][136];
  int tid = threadIdx.x, n0 = blockIdx.x * 64;
  {
    int n = tid >> 2, t4 = tid & 3;
    const bf16x8* hr = (const bf16x8*)(hb + (size_t)(n0 + n) * 128);
    #pragma unroll
    for (int i = 0; i < 4; i++)
      *(bf16x8*)&s_n[n][t4 * 8 + 32 * i] = hr[t4 + 4 * i];
  }
  {
    float4 zz = make_float4(0.f, 0.f, 0.f, 0.f);
    float4* ap = (float4*)(aggH + (size_t)n0 * 256);
    for (int i = tid; i < 64 * 256 / 4; i += 256) ap[i] = zz;
  }
  __syncthreads();
  const int wv = tid >> 6, ln = tid & 63, lc = ln & 15, qd = ln >> 4;
  for (int cp = 0; cp < 2; cp++) {
    f32x4 aA[4][2], aB[4][2];
    #pragma unroll
    for (int nt = 0; nt < 2; nt++) {
      float bv = b1[cp * 128 + wv * 32 + nt * 16 + lc];
      #pragma unroll
      for (int mt = 0; mt < 4; mt++) {
        aA[mt][nt][0] = 0.f; aA[mt][nt][1] = 0.f;
        aA[mt][nt][2] = 0.f; aA[mt][nt][3] = 0.f;
        aB[mt][nt][0] = bv; aB[mt][nt][1] = bv;
        aB[mt][nt][2] = bv; aB[mt][nt][3] = bv;
      }
    }
    #pragma unroll
    for (int kt = 0; kt < 4; kt++) {
      bf16x8 af[4];
      #pragma unroll
      for (int mt = 0; mt < 4; mt++)
        af[mt] = *(const bf16x8*)&s_n[mt * 16 + lc][kt * 32 + qd * 8];
      bf16x8 bwA[2], bwB[2];
      #pragma unroll
      for (int nt = 0; nt < 2; nt++) {
        int c = cp * 128 + wv * 32 + nt * 16 + lc;
        bwA[nt] = *(const bf16x8*)(W1at + (size_t)c * 128 + kt * 32 + qd * 8);
        bwB[nt] = *(const bf16x8*)(W1bt + (size_t)c * 128 + kt * 32 + qd * 8);
      }
      #pragma unroll
      for (int mt = 0; mt < 4; mt++)
        #pragma unroll
        for (int nt = 0; nt < 2; nt++) {
          aA[mt][nt] = __builtin_amdgcn_mfma_f32_16x16x32_bf16(af[mt], bwA[nt], aA[mt][nt], 0, 0, 0);
          aB[mt][nt] = __builtin_amdgcn_mfma_f32_16x16x32_bf16(af[mt], bwB[nt], aB[mt][nt], 0, 0, 0);
        }
    }
    #pragma unroll
    for (int mt = 0; mt < 4; mt++)
      #pragma unroll
      for (int nt = 0; nt < 2; nt++) {
        int c = cp * 128 + wv * 32 + nt * 16 + lc;
        #pragma unroll
        for (int r = 0; r < 4; r++) {
          int n = n0 + mt * 16 + qd * 4 + r;
          z1b[(size_t)n * 256 + c] = (__bf16)aA[mt][nt][r];
          z2b[(size_t)n * 256 + c] = (__bf16)aB[mt][nt][r];
        }
      }
  }
}

// ---------------- fused message kernel v4: hid + silu + segmented silu-sum ----------------
// hid = zs + ef@W1c via one K32 MFMA per 16x16 tile (identity|W1c trick).
// aggH[d] += sum of silu(hid) rows (256-dim, fp32 atomics); W2 applied later (fused into upd).
// LDS: s_zs[64][136] bf16 (17408) | s_h[64][136] bf16 (17408) | s_ef[64][24] (3072)
//      | s_dst[64] | s_src[64]  -> 38400 B, 4 blocks/CU
#define MS_H_OFF   17408
#define MS_EF_OFF  34816
#define MS_DST_OFF 37888
#define MS_SRC_OFF 38144
#define MS_BYTES   38400

__global__ __launch_bounds__(256, 4) void msg_mfma_kernel(
    const __bf16* __restrict__ z1b, const __bf16* __restrict__ z2b,
    const __bf16* __restrict__ efb,
    const int* __restrict__ esrc, const int* __restrict__ edst,
    const __bf16* __restrict__ B1c, float* __restrict__ aggH)
{
  __shared__ __align__(16) char smem[MS_BYTES];
  __bf16 (*s_zs)[136] = (__bf16(*)[136])(smem);
  __bf16 (*s_h)[136]  = (__bf16(*)[136])(smem + MS_H_OFF);
  __bf16 (*s_ef)[24]  = (__bf16(*)[24])(smem + MS_EF_OFF);
  int* s_dst = (int*)(smem + MS_DST_OFF);
  int* s_src = (int*)(smem + MS_SRC_OFF);

  int tid = threadIdx.x, e0 = blockIdx.x * TE;
  if (tid < TE) s_dst[tid] = edst[e0 + tid];
  else if (tid < 2 * TE) s_src[tid - TE] = esrc[e0 + tid - TE];
  {
    int e = tid >> 2, t4 = tid & 3;
    if (t4 < 2)
      *(bf16x8*)&s_ef[e][t4 * 8] =
          *(const bf16x8*)(efb + (size_t)(e0 + e) * 16 + t4 * 8);
  }
  __syncthreads();

  const int wv = tid >> 6, ln = tid & 63, lc = ln & 15, qd = ln >> 4;
  const int m_row = tid >> 2, t4 = tid & 3;
  const int sidx = s_src[m_row], didx = s_dst[m_row];
  const int jcol = tid & 127, rh = tid >> 7;   // scan assignment

  for (int hf = 0; hf < 2; hf++) {
    // ---- stage zs = z1b[src] + z2b[dst] for this 128-col half ----
    {
      const __bf16* z1r = z1b + (size_t)sidx * 256 + hf * 128;
      const __bf16* z2r = z2b + (size_t)didx * 256 + hf * 128;
      #pragma unroll
      for (int cc = 0; cc < 4; cc++) {
        int col = cc * 32 + t4 * 8;
        bf16x8 a = *(const bf16x8*)(z1r + col);
        bf16x8 b = *(const bf16x8*)(z2r + col);
        bf16x8 o;
        #pragma unroll
        for (int j = 0; j < 8; j++) o[j] = (__bf16)((float)a[j] + (float)b[j]);
        *(bf16x8*)&s_zs[m_row][col] = o;
      }
    }
    __syncthreads();   // zs ready; prev-half scan done before s_h overwrite below

    // ---- GEMM1 (identity|W1c trick) + silu -> s_h ----
    bf16x8 bfrag[2];
    #pragma unroll
    for (int nt = 0; nt < 2; nt++) {
      int c = hf * 128 + wv * 32 + nt * 16 + lc;
      bfrag[nt] = *(const bf16x8*)(B1c + (size_t)c * 32 + qd * 8);
    }
    #pragma unroll
    for (int mt = 0; mt < 4; mt++) {
      #pragma unroll
      for (int nt = 0; nt < 2; nt++) {
        const __bf16* ap = (qd < 2)
            ? &s_zs[mt * 16 + lc][wv * 32 + nt * 16 + qd * 8]
            : &s_ef[mt * 16 + lc][(qd - 2) * 8];
        bf16x8 af = *(const bf16x8*)ap;
        f32x4 z; z[0] = 0.f; z[1] = 0.f; z[2] = 0.f; z[3] = 0.f;
        f32x4 acc1 = __builtin_amdgcn_mfma_f32_16x16x32_bf16(af, bfrag[nt], z, 0, 0, 0);
        int cc = wv * 32 + nt * 16 + lc;
        #pragma unroll
        for (int r = 0; r < 4; r++)
          s_h[mt * 16 + qd * 4 + r][cc] = (__bf16)silu_f(acc1[r]);
      }
    }
    __syncthreads();

    // ---- segmented column-sum of silu rows (256 threads: 128 cols x 2 row-halves) ----
    {
      float acc = 0.0f;
      int cur = s_dst[rh * 32];
      #pragma unroll 8
      for (int i = 0; i < 32; i++) {
        int m = rh * 32 + i;
        int d = s_dst[m];           // wave-uniform -> scalar branch
        if (d != cur) {
          atomicAdd(&aggH[(size_t)cur * 256 + hf * 128 + jcol], acc);
          acc = 0.0f;
          cur = d;
        }
        acc += (float)s_h[m][jcol];
      }
      atomicAdd(&aggH[(size_t)cur * 256 + hf * 128 + jcol], acc);
    }
  }
}

// ---------------- fused node update MLP: u = [h | s], K=384 (W2 folded in) ----------------
__global__ __launch_bounds__(256, 2) void upd_mfma_kernel(
    float* __restrict__ h, __bf16* __restrict__ hb,
    const float* __restrict__ aggH, const float* __restrict__ degf,
    const __bf16* __restrict__ uW1ft, const float* __restrict__ b1,
    const float* __restrict__ b2u,
    const __bf16* __restrict__ uW2t, const float* __restrict__ b2)
{
  __shared__ __bf16 s_u[64][392];    // 384 + 8 pad
  __shared__ __bf16 s_uh[64][136];
  int tid = threadIdx.x, n0 = blockIdx.x * 64;
  {
    int n = tid >> 2, t4 = tid & 3;
    const bf16x8* hr = (const bf16x8*)(hb + (size_t)(n0 + n) * 128);
    #pragma unroll
    for (int i = 0; i < 4; i++)
      *(bf16x8*)&s_u[n][t4 * 8 + 32 * i] = hr[t4 + 4 * i];
    const float* sr = aggH + (size_t)(n0 + n) * 256;
    #pragma unroll
    for (int i = 0; i < 8; i++) {
      int col = t4 * 8 + i * 32;
      float4 a = *(const float4*)(sr + col);
      float4 b = *(const float4*)(sr + col + 4);
      bf16x8 o;
      o[0] = (__bf16)a.x; o[1] = (__bf16)a.y; o[2] = (__bf16)a.z; o[3] = (__bf16)a.w;
      o[4] = (__bf16)b.x; o[5] = (__bf16)b.y; o[6] = (__bf16)b.z; o[7] = (__bf16)b.w;
      *(bf16x8*)&s_u[n][128 + col] = o;
    }
  }
  __syncthreads();
  const int wv = tid >> 6, ln = tid & 63, lc = ln & 15, qd = ln >> 4;

  float dg[4][4];
  #pragma unroll
  for (int mt = 0; mt < 4; mt++)
    #pragma unroll
    for (int r = 0; r < 4; r++)
      dg[mt][r] = degf[n0 + mt * 16 + qd * 4 + r];

  f32x4 acc2[4][2];
  #pragma unroll
  for (int nt = 0; nt < 2; nt++) {
    float bv = b2[wv * 32 + nt * 16 + lc];
    #pragma unroll
    for (int mt = 0; mt < 4; mt++) {
      acc2[mt][nt][0] = bv; acc2[mt][nt][1] = bv;
      acc2[mt][nt][2] = bv; acc2[mt][nt][3] = bv;
    }
  }

  for (int hf = 0; hf < 2; hf++) {
    f32x4 acc1[4][2];
    #pragma unroll
    for (int nt = 0; nt < 2; nt++) {
      int c = hf * 128 + wv * 32 + nt * 16 + lc;
      float bv = b1[c];
      float b2uv = b2u[c];
      #pragma unroll
      for (int mt = 0; mt < 4; mt++)
        #pragma unroll
        for (int r = 0; r < 4; r++)
          acc1[mt][nt][r] = bv + dg[mt][r] * b2uv;
    }
    #pragma unroll
    for (int kt = 0; kt < 12; kt++) {
      bf16x8 af[4];
      #pragma unroll
      for (int mt = 0; mt < 4; mt++)
        af[mt] = *(const bf16x8*)&s_u[mt * 16 + lc][kt * 32 + qd * 8];
      bf16x8 bw[2];
      #pragma unroll
      for (int nt = 0; nt < 2; nt++)
        bw[nt] = *(const bf16x8*)(uW1ft +
                 (size_t)(hf * 128 + wv * 32 + nt * 16 + lc) * 384 + kt * 32 + qd * 8);
      #pragma unroll
      for (int mt = 0; mt < 4; mt++)
        #pragma unroll
        for (int nt = 0; nt < 2; nt++)
          acc1[mt][nt] = __builtin_amdgcn_mfma_f32_16x16x32_bf16(af[mt], bw[nt], acc1[mt][nt], 0, 0, 0);
    }
    __syncthreads();
    #pragma unroll
    for (int mt = 0; mt < 4; mt++)
      #pragma unroll
      for (int nt = 0; nt < 2; nt++) {
        int cc = wv * 32 + nt * 16 + lc;
        #pragma unroll
        for (int r = 0; r < 4; r++)
          s_uh[mt * 16 + qd * 4 + r][cc] = (__bf16)silu_f(acc1[mt][nt][r]);
      }
    __syncthreads();
    #pragma unroll
    for (int kt = 0; kt < 4; kt++) {
      bf16x8 a2[4];
      #pragma unroll
      for (int mt = 0; mt < 4; mt++)
        a2[mt] = *(const bf16x8*)&s_uh[mt * 16 + lc][kt * 32 + qd * 8];
      bf16x8 b2w[2];
      #pragma unroll
      for (int nt = 0; nt < 2; nt++)
        b2w[nt] = *(const bf16x8*)(uW2t +
                  (size_t)(wv * 32 + nt * 16 + lc) * 256 + hf * 128 + kt * 32 + qd * 8);
      #pragma unroll
      for (int mt = 0; mt < 4; mt++)
        #pragma unroll
        for (int nt = 0; nt < 2; nt++)
          acc2[mt][nt] = __builtin_amdgcn_mfma_f32_16x16x32_bf16(a2[mt], b2w[nt], acc2[mt][nt], 0, 0, 0);
    }
  }

  #pragma unroll
  for (int mt = 0; mt < 4; mt++)
    #pragma unroll
    for (int nt = 0; nt < 2; nt++) {
      int c = wv * 32 + nt * 16 + lc;
      #pragma unroll
      for (int r = 0; r < 4; r++) {
        int n = n0 + mt * 16 + qd * 4 + r;
        float v = h[(size_t)n * 128 + c] + acc2[mt][nt][r];
        h[(size_t)n * 128 + c] = v;
        hb[(size_t)n * 128 + c] = (__bf16)v;
      }
    }
}

// ---------------- readout ----------------
__global__ __launch_bounds__(128) void readout_sum_kernel(
    const float* __restrict__ h, const int* __restrict__ batch,
    float* __restrict__ gsum, float* __restrict__ gcnt)
{
  int j = threadIdx.x;
  int n0 = blockIdx.x * 128;
  float acc = 0.f, cacc = 0.f;
  int cur = batch[n0];
  for (int i = 0; i < 128; i++) {
    int b = batch[n0 + i];
    if (b != cur) {
      atomicAdd(&gsum[cur * 128 + j], acc);
      if (j == 0) atomicAdd(&gcnt[cur], cacc);
      acc = 0.f; cacc = 0.f; cur = b;
    }
    acc += h[(size_t)(n0 + i) * 128 + j];
    cacc += 1.f;
  }
  atomicAdd(&gsum[cur * 128 + j], acc);
  if (j == 0) atomicAdd(&gcnt[cur], cacc);
}

__global__ __launch_bounds__(256) void readout_mlp_kernel(
    const float* __restrict__ gsum, const float* __restrict__ gcnt,
    const float* __restrict__ W1, const float* __restrict__ b1,
    const float* __restrict__ W2, const float* __restrict__ b2,
    float* __restrict__ out)
{
  __shared__ float g[8][128];
  __shared__ float hid[8][256];
  int tid = threadIdx.x;
  for (int i = tid; i < 8 * 128; i += 256) {
    int b = i >> 7, c = i & 127;
    g[b][c] = gsum[i] / fmaxf(gcnt[b], 1.0f);
  }
  __syncthreads();
  {
    float bb = b1[tid];
    float a[8];
    #pragma unroll
    for (int b = 0; b < 8; b++) a[b] = bb;
    for (int k = 0; k < 128; k++) {
      float w = W1[k * 256 + tid];
      #pragma unroll
      for (int b = 0; b < 8; b++) a[b] += g[b][k] * w;
    }
    #pragma unroll
    for (int b = 0; b < 8; b++) hid[b][tid] = silu_f(a[b]);
  }
  __syncthreads();
  int j = tid & 63, bg = tid >> 6;
  float a0 = b2[j], a1 = b2[j];
  for (int k = 0; k < 256; k++) {
    float w = W2[k * 64 + j];
    a0 += hid[bg * 2 + 0][k] * w;
    a1 += hid[bg * 2 + 1][k] * w;
  }
  out[(bg * 2 + 0) * 64 + j] = a0;
  out[(bg * 2 + 1) * 64 + j] = a1;
}

extern "C" void kernel_launch(void* const* d_in, const int* in_sizes, int n_in,
                              void* d_out, int out_size, void* d_ws, size_t ws_size,
                              hipStream_t stream) {
  const float* pos   = (const float*)d_in[0];
  const float* xfeat = (const float*)d_in[1];
  const int*   eidx  = (const int*)d_in[2];
  const int*   batch = (const int*)d_in[3];
  const float* eW1 = (const float*)d_in[4];
  const float* eb1 = (const float*)d_in[5];
  const float* eW2 = (const float*)d_in[6];
  const float* eb2 = (const float*)d_in[7];
  const float* mW1 = (const float*)d_in[8];
  const float* mb1 = (const float*)d_in[9];
  const float* mW2 = (const float*)d_in[10];
  const float* mb2 = (const float*)d_in[11];
  const float* uW1 = (const float*)d_in[12];
  const float* ub1 = (const float*)d_in[13];
  const float* uW2 = (const float*)d_in[14];
  const float* ub2 = (const float*)d_in[15];
  const float* rW1 = (const float*)d_in[16];
  const float* rb1 = (const float*)d_in[17];
  const float* rW2 = (const float*)d_in[18];
  const float* rb2 = (const float*)d_in[19];

  const int* srcI = eidx;
  const int* dstI = eidx + NEDGES;

  char* base = (char*)d_ws;
  float* h    = (float*)base;  base += (size_t)NATOMS * 128 * 4;
  float* aggH = (float*)base;  base += (size_t)NATOMS * 256 * 4;
  __bf16* z1b = (__bf16*)base; base += (size_t)NATOMS * 256 * 2;
  __bf16* z2b = (__bf16*)base; base += (size_t)NATOMS * 256 * 2;
  __bf16* hb  = (__bf16*)base; base += (size_t)NATOMS * 128 * 2;
  __bf16* efb = (__bf16*)base; base += (size_t)NEDGES * 16 * 2;
  __bf16* W1at = (__bf16*)base; base += (size_t)NLAYERS * 256 * 128 * 2;
  __bf16* W1bt = (__bf16*)base; base += (size_t)NLAYERS * 256 * 128 * 2;
  __bf16* B1c  = (__bf16*)base; base += (size_t)NLAYERS * 256 * 32 * 2;
  __bf16* uW1ft = (__bf16*)base; base += (size_t)NLAYERS * 256 * 384 * 2;
  __bf16* uW2t = (__bf16*)base; base += (size_t)NLAYERS * 128 * 256 * 2;
  float* W2u  = (float*)base;  base += (size_t)NLAYERS * 256 * 256 * 4;
  float* b2u  = (float*)base;  base += (size_t)NLAYERS * 256 * 4;
  float* degf = (float*)base;  base += (size_t)NATOMS * 4;
  float* gsum = (float*)base;  base += 8 * 128 * 4;
  float* gcnt = (float*)base;  base += 8 * 4;
  int* counts = (int*)base;    base += (size_t)NATOMS * 4;
  int* cursor = (int*)base;    base += (size_t)NATOMS * 4;
  int* esrc   = (int*)base;    base += (size_t)NEDGES * 4;
  int* edst   = (int*)base;    base += (size_t)NEDGES * 4;

  // --- CSR preprocessing ---
  hipMemsetAsync(counts, 0, NATOMS * sizeof(int), stream);
  hist_kernel<<<NEDGES / 256, 256, 0, stream>>>(dstI, counts);
  scan_kernel<<<1, 1024, 0, stream>>>(counts, cursor);
  scatter_kernel<<<NEDGES / 256, 256, 0, stream>>>(srcI, dstI, cursor, esrc, edst);
  degf_kernel<<<NATOMS / 256, 256, 0, stream>>>(counts, degf);

  // --- weight prep ---
  conv_t_kernel<<<dim3(128, NLAYERS), 256, 0, stream>>>(mW1, W1at, 256,   0, 128, 128, 272L*256, 256L*128);
  conv_t_kernel<<<dim3(128, NLAYERS), 256, 0, stream>>>(mW1, W1bt, 256, 128, 128, 128, 272L*256, 256L*128);
  build_b1c_kernel<<<dim3(32, NLAYERS), 256, 0, stream>>>(mW1, B1c);
  w2u_kernel<<<dim3(256, NLAYERS), 256, 0, stream>>>(mW2, uW1, W2u);
  b2u_kernel<<<NLAYERS, 256, 0, stream>>>(mb2, uW1, b2u);
  build_uw1ft_kernel<<<dim3(384, NLAYERS), 256, 0, stream>>>(uW1, W2u, uW1ft);
  conv_t_kernel<<<dim3(128, NLAYERS), 256, 0, stream>>>(uW2, uW2t, 128,   0, 256, 256, 256L*128, 128L*256);

  embed_kernel<<<NATOMS, 128, 0, stream>>>(xfeat, eW1, eb1, eW2, eb2, h, hb);
  rbf_kernel<<<NEDGES / 256, 256, 0, stream>>>(pos, esrc, edst, efb);

  for (int l = 0; l < NLAYERS; l++) {
    zprep_kernel<<<NATOMS / 64, 256, 0, stream>>>(
        hb, mb1 + (size_t)l * 256,
        W1at + (size_t)l * 256 * 128, W1bt + (size_t)l * 256 * 128,
        z1b, z2b, aggH);
    msg_mfma_kernel<<<NEDGES / TE, 256, 0, stream>>>(
        z1b, z2b, efb, esrc, edst,
        B1c + (size_t)l * 256 * 32, aggH);
    upd_mfma_kernel<<<NATOMS / 64, 256, 0, stream>>>(
        h, hb, aggH, degf,
        uW1ft + (size_t)l * 256 * 384, ub1 + (size_t)l * 256,
        b2u + (size_t)l * 256,
        uW2t + (size_t)l * 128 * 256, ub2 + (size_t)l * 128);
  }

  hipMemsetAsync(gsum, 0, (8 * 128 + 8) * sizeof(float), stream);
  readout_sum_kernel<<<NATOMS / 128, 128, 0, stream>>>(h, batch, gsum, gcnt);
  readout_mlp_kernel<<<1, 256, 0, stream>>>(gsum, gcnt, rW1, rb1, rW2, rb2,
                                            (float*)d_out);
}

// Round 7
// 817.375 us; speedup vs baseline: 13.2525x; 1.0664x over previous
//
#include <hip/hip_runtime.h>
#include <math.h>

#define NATOMS 16384
#define NEDGES 524288
#define NLAYERS 4
#define TE 64      // edges per block in msg kernel

typedef __bf16 bf16x8 __attribute__((ext_vector_type(8)));
typedef __bf16 bf16x4 __attribute__((ext_vector_type(4)));
typedef float f32x4 __attribute__((ext_vector_type(4)));

__device__ __forceinline__ float silu_f(float x) {
  return x / (1.0f + __expf(-x));
}

// ---------------- CSR preprocessing ----------------
__global__ __launch_bounds__(256) void hist_kernel(
    const int* __restrict__ dst, int* __restrict__ counts)
{
  int e = blockIdx.x * 256 + threadIdx.x;
  atomicAdd(&counts[dst[e]], 1);
}

__global__ __launch_bounds__(1024) void scan_kernel(
    const int* __restrict__ counts, int* __restrict__ cursor)
{
  __shared__ int buf[1024];
  __shared__ int carry_s;
  int tid = threadIdx.x;
  if (tid == 0) carry_s = 0;
  __syncthreads();
  for (int c = 0; c < 16; c++) {
    int v = counts[c * 1024 + tid];
    buf[tid] = v;
    __syncthreads();
    for (int off = 1; off < 1024; off <<= 1) {
      int t = (tid >= off) ? buf[tid - off] : 0;
      __syncthreads();
      buf[tid] += t;
      __syncthreads();
    }
    cursor[c * 1024 + tid] = buf[tid] - v + carry_s;
    __syncthreads();
    if (tid == 1023) carry_s += buf[1023];
    __syncthreads();
  }
}

__global__ __launch_bounds__(256) void scatter_kernel(
    const int* __restrict__ src, const int* __restrict__ dst,
    int* __restrict__ cursor, int* __restrict__ esrc, int* __restrict__ edst)
{
  int e = blockIdx.x * 256 + threadIdx.x;
  int d = dst[e];
  int p = atomicAdd(&cursor[d], 1);
  esrc[p] = src[e];
  edst[p] = d;
}

__global__ __launch_bounds__(256) void degf_kernel(
    const int* __restrict__ counts, float* __restrict__ degf)
{
  int n = blockIdx.x * 256 + threadIdx.x;
  degf[n] = (float)counts[n];
}

// ---------------- weight prep ----------------
__global__ __launch_bounds__(256) void conv_t_kernel(
    const float* __restrict__ W, __bf16* __restrict__ Wt,
    int ldN, int k0, int Kin, int Kpad, long lsrc, long ldst)
{
  long l = blockIdx.y;
  int i = blockIdx.x * 256 + threadIdx.x;
  int n = i / Kpad, k = i - n * Kpad;
  float v = (k < Kin) ? W[l * lsrc + (size_t)(k0 + k) * ldN + n] : 0.0f;
  Wt[l * ldst + (size_t)n * Kpad + k] = (__bf16)v;
}

// B2c[c][k]: k<16 -> mW1 row (256+k), col c (the ef rows); k>=16 -> 0
__global__ __launch_bounds__(256) void build_b2c_kernel(
    const float* __restrict__ mW1, __bf16* __restrict__ Bc)
{
  long l = blockIdx.y;
  int i = blockIdx.x * 256 + threadIdx.x;  // 256*32
  int c = i >> 5, k = i & 31;
  float v = (k < 16) ? mW1[l * (272L * 256) + (size_t)(256 + k) * 256 + c] : 0.0f;
  Bc[l * (256L * 32) + i] = (__bf16)v;
}

// W2u[l] = mW2[l] (256x128) @ uW1[l][128:256,:] (128x256)  -> fp32 (256x256)
__global__ __launch_bounds__(256) void w2u_kernel(
    const float* __restrict__ mW2, const float* __restrict__ uW1,
    float* __restrict__ W2u)
{
  long l = blockIdx.y;
  int r = blockIdx.x, c = threadIdx.x;
  float acc = 0.0f;
  for (int k = 0; k < 128; k++)
    acc += mW2[(l * 256 + r) * 128 + k] *
           uW1[l * 65536 + (size_t)(128 + k) * 256 + c];
  W2u[(l * 256 + r) * 256 + c] = acc;
}

// b2u[l][c] = sum_k mb2[l][k] * uW1[l][128+k][c]
__global__ __launch_bounds__(256) void b2u_kernel(
    const float* __restrict__ mb2, const float* __restrict__ uW1,
    float* __restrict__ b2u)
{
  long l = blockIdx.x;
  int c = threadIdx.x;
  float acc = 0.0f;
  for (int k = 0; k < 128; k++)
    acc += mb2[l * 128 + k] * uW1[l * 65536 + (size_t)(128 + k) * 256 + c];
  b2u[l * 256 + c] = acc;
}

// uW1ft[l][n][kk] (256 x 384): kk<128 -> uW1[l][kk][n]; else W2u[l][kk-128][n]
__global__ __launch_bounds__(256) void build_uw1ft_kernel(
    const float* __restrict__ uW1, const float* __restrict__ W2u,
    __bf16* __restrict__ Wt)
{
  long l = blockIdx.y;
  int i = blockIdx.x * 256 + threadIdx.x;  // 256*384
  int n = i / 384, k = i - n * 384;
  float v = (k < 128) ? uW1[l * 65536 + (size_t)k * 256 + n]
                      : W2u[l * 65536 + (size_t)(k - 128) * 256 + n];
  Wt[l * (256L * 384) + i] = (__bf16)v;
}

// ---------------- embedding ----------------
__global__ __launch_bounds__(128) void embed_kernel(
    const float* __restrict__ x, const float* __restrict__ W1,
    const float* __restrict__ b1, const float* __restrict__ W2,
    const float* __restrict__ b2, float* __restrict__ h,
    __bf16* __restrict__ hb)
{
  int n = blockIdx.x;
  int j = threadIdx.x;
  __shared__ float xs[26];
  __shared__ float hid[128];
  if (j < 26) xs[j] = x[n * 26 + j];
  __syncthreads();
  float acc = b1[j];
  #pragma unroll
  for (int k = 0; k < 26; k++) acc += xs[k] * W1[k * 128 + j];
  hid[j] = silu_f(acc);
  __syncthreads();
  float acc2 = b2[j];
  #pragma unroll 8
  for (int k = 0; k < 128; k++) acc2 += hid[k] * W2[k * 128 + j];
  h[(size_t)n * 128 + j] = acc2;
  hb[(size_t)n * 128 + j] = (__bf16)acc2;
}

// ---------------- edge RBF (sorted slot order) ----------------
__global__ __launch_bounds__(256) void rbf_kernel(
    const float* __restrict__ pos, const int* __restrict__ esrc,
    const int* __restrict__ edst, __bf16* __restrict__ efb)
{
  int e = blockIdx.x * 256 + threadIdx.x;
  int s = esrc[e], d = edst[e];
  float dx = pos[d * 3 + 0] - pos[s * 3 + 0];
  float dy = pos[d * 3 + 1] - pos[s * 3 + 1];
  float dz = pos[d * 3 + 2] - pos[s * 3 + 2];
  float dist = sqrtf(dx * dx + dy * dy + dz * dz + 1e-12f);
  float env = (dist < 10.0f)
                  ? 0.5f * (cosf(3.14159265358979f * dist * 0.1f) + 1.0f)
                  : 0.0f;
  bf16x8 o0, o1;
  #pragma unroll
  for (int i = 0; i < 16; i++) {
    float c = (10.0f / 15.0f) * (float)i;
    float t = dist - c;
    float v = env * __expf(-t * t * 1.28f);
    if (i < 8) o0[i] = (__bf16)v; else o1[i - 8] = (__bf16)v;
  }
  *(bf16x8*)(efb + (size_t)e * 16 + 0) = o0;
  *(bf16x8*)(efb + (size_t)e * 16 + 8) = o1;
}

// ---------------- zprep: z1b = bf16(h@W1a), z2b = bf16(h@W1b + b1); zeros aggH ----------------
__global__ __launch_bounds__(256) void zprep_kernel(
    const __bf16* __restrict__ hb, const float* __restrict__ b1,
    const __bf16* __restrict__ W1at, const __bf16* __restrict__ W1bt,
    __bf16* __restrict__ z1b, __bf16* __restrict__ z2b, float* __restrict__ aggH)
{
  __shared__ __bf16 s_n[64][136];
  int tid = threadIdx.x, n0 = blockIdx.x * 64;
  {
    int n = tid >> 2, t4 = tid & 3;
    const bf16x8* hr = (const bf16x8*)(hb + (size_t)(n0 + n) * 128);
    #pragma unroll
    for (int i = 0; i < 4; i++)
      *(bf16x8*)&s_n[n][t4 * 8 + 32 * i] = hr[t4 + 4 * i];
  }
  {
    float4 zz = make_float4(0.f, 0.f, 0.f, 0.f);
    float4* ap = (float4*)(aggH + (size_t)n0 * 256);
    for (int i = tid; i < 64 * 256 / 4; i += 256) ap[i] = zz;
  }
  __syncthreads();
  const int wv = tid >> 6, ln = tid & 63, lc = ln & 15, qd = ln >> 4;
  for (int cp = 0; cp < 2; cp++) {
    f32x4 aA[4][2], aB[4][2];
    #pragma unroll
    for (int nt = 0; nt < 2; nt++) {
      float bv = b1[cp * 128 + wv * 32 + nt * 16 + lc];
      #pragma unroll
      for (int mt = 0; mt < 4; mt++) {
        aA[mt][nt][0] = 0.f; aA[mt][nt][1] = 0.f;
        aA[mt][nt][2] = 0.f; aA[mt][nt][3] = 0.f;
        aB[mt][nt][0] = bv; aB[mt][nt][1] = bv;
        aB[mt][nt][2] = bv; aB[mt][nt][3] = bv;
      }
    }
    #pragma unroll
    for (int kt = 0; kt < 4; kt++) {
      bf16x8 af[4];
      #pragma unroll
      for (int mt = 0; mt < 4; mt++)
        af[mt] = *(const bf16x8*)&s_n[mt * 16 + lc][kt * 32 + qd * 8];
      bf16x8 bwA[2], bwB[2];
      #pragma unroll
      for (int nt = 0; nt < 2; nt++) {
        int c = cp * 128 + wv * 32 + nt * 16 + lc;
        bwA[nt] = *(const bf16x8*)(W1at + (size_t)c * 128 + kt * 32 + qd * 8);
        bwB[nt] = *(const bf16x8*)(W1bt + (size_t)c * 128 + kt * 32 + qd * 8);
      }
      #pragma unroll
      for (int mt = 0; mt < 4; mt++)
        #pragma unroll
        for (int nt = 0; nt < 2; nt++) {
          aA[mt][nt] = __builtin_amdgcn_mfma_f32_16x16x32_bf16(af[mt], bwA[nt], aA[mt][nt], 0, 0, 0);
          aB[mt][nt] = __builtin_amdgcn_mfma_f32_16x16x32_bf16(af[mt], bwB[nt], aB[mt][nt], 0, 0, 0);
        }
    }
    #pragma unroll
    for (int mt = 0; mt < 4; mt++)
      #pragma unroll
      for (int nt = 0; nt < 2; nt++) {
        int c = cp * 128 + wv * 32 + nt * 16 + lc;
        #pragma unroll
        for (int r = 0; r < 4; r++) {
          int n = n0 + mt * 16 + qd * 4 + r;
          z1b[(size_t)n * 256 + c] = (__bf16)aA[mt][nt][r];
          z2b[(size_t)n * 256 + c] = (__bf16)aB[mt][nt][r];
        }
      }
  }
}

// ---------------- fused message kernel v5 ----------------
// hid = (z1[src] + z2[dst]) + ef@W1c via TWO MFMAs per 16x16 tile:
//   MFMA-A: B = [I16;I16] (in-register), A lanes qd<2 load z1b rows, qd>=2 z2b rows
//           (raw bf16 global_load_dwordx4 straight into the A-fragment, fp32 add in MFMA)
//   MFMA-B: B = [W1c;0] (B2c), A lanes read ef from LDS.
// silu -> transposed fp32 s_hT[col][row] (float2 writes), segmented column-sum with
// SGPR boundary bitmask, atomics into aggH.
// LDS: s_hT 128*66*4 = 33792 | s_ef 64*24*2 = 3072 | s_src 256 | s_dst 256 | mask 8
#define MS_EF_OFF   33792
#define MS_SRC_OFF  36864
#define MS_DST_OFF  37120
#define MS_MASK_OFF 37376
#define MS_BYTES    37392

__global__ __launch_bounds__(256, 4) void msg_mfma_kernel(
    const __bf16* __restrict__ z1b, const __bf16* __restrict__ z2b,
    const __bf16* __restrict__ efb,
    const int* __restrict__ esrc, const int* __restrict__ edst,
    const __bf16* __restrict__ B2c, float* __restrict__ aggH)
{
  __shared__ __align__(16) char smem[MS_BYTES];
  float (*s_hT)[66] = (float(*)[66])(smem);            // [128 cols][64 rows + 2 pad]
  __bf16 (*s_ef)[24] = (__bf16(*)[24])(smem + MS_EF_OFF);
  int* s_src = (int*)(smem + MS_SRC_OFF);
  int* s_dst = (int*)(smem + MS_DST_OFF);
  unsigned int* s_mask = (unsigned int*)(smem + MS_MASK_OFF);

  int tid = threadIdx.x, e0 = blockIdx.x * TE;

  // ---- setup: indices, boundary mask, ef staging ----
  if (tid < TE) {
    int d = edst[e0 + tid];
    s_dst[tid] = d;
    int dp = (tid == 0) ? (d ^ 1) : edst[e0 + tid - 1];
    unsigned long long mb = __ballot(d != dp);
    if (tid == 0) { s_mask[0] = (unsigned int)mb; s_mask[1] = (unsigned int)(mb >> 32); }
  } else if (tid < 2 * TE) {
    s_src[tid - TE] = esrc[e0 + tid - TE];
  }
  {
    int e = tid >> 2, t4 = tid & 3;
    if (t4 < 2)
      *(bf16x8*)&s_ef[e][t4 * 8] =
          *(const bf16x8*)(efb + (size_t)(e0 + e) * 16 + t4 * 8);
  }
  __syncthreads();

  const int wv = tid >> 6, ln = tid & 63, lc = ln & 15, qd = ln >> 4;
  const unsigned int mlo = __builtin_amdgcn_readfirstlane(s_mask[0]);
  const unsigned int mhi = __builtin_amdgcn_readfirstlane(s_mask[1]);

  // identity B-fragment for [I16;I16]: B[k][c] = delta(k%16, c); lane holds B[qd*8+j][lc]
  bf16x8 bI;
  #pragma unroll
  for (int j = 0; j < 8; j++)
    bI[j] = (__bf16)((lc == (qd & 1) * 8 + j) ? 1.0f : 0.0f);

  // per-mt gathered-row pointers (qd<2 -> z1[src], qd>=2 -> z2[dst]), +8-col for odd qd
  const __bf16* pz[4];
  #pragma unroll
  for (int mt = 0; mt < 4; mt++) {
    int m = mt * 16 + lc;
    int row = (qd < 2) ? s_src[m] : s_dst[m];
    pz[mt] = ((qd < 2) ? z1b : z2b) + (size_t)row * 256 + (qd & 1) * 8;
  }
  const int jcol = tid & 127, r0 = (tid >> 7) * 32;

  for (int hf = 0; hf < 2; hf++) {
    const int cb = hf * 128 + wv * 32;
    bf16x8 bw[2];
    #pragma unroll
    for (int nt = 0; nt < 2; nt++)
      bw[nt] = *(const bf16x8*)(B2c + (size_t)(cb + nt * 16 + lc) * 32 + qd * 8);

    #pragma unroll
    for (int mt = 0; mt < 4; mt++) {
      bf16x8 aef = *(const bf16x8*)&s_ef[mt * 16 + lc][(qd & 1) * 8];
      #pragma unroll
      for (int nt = 0; nt < 2; nt++) {
        bf16x8 az = *(const bf16x8*)(pz[mt] + cb + nt * 16);   // global gather -> A-frag
        f32x4 z; z[0] = 0.f; z[1] = 0.f; z[2] = 0.f; z[3] = 0.f;
        f32x4 acc = __builtin_amdgcn_mfma_f32_16x16x32_bf16(az, bI, z, 0, 0, 0);
        acc = __builtin_amdgcn_mfma_f32_16x16x32_bf16(aef, bw[nt], acc, 0, 0, 0);
        // silu -> transposed LDS, float2 pairs (col = wv*32+nt*16+lc, rows mt*16+qd*4..+3)
        float2 p0, p1;
        p0.x = silu_f(acc[0]); p0.y = silu_f(acc[1]);
        p1.x = silu_f(acc[2]); p1.y = silu_f(acc[3]);
        float* wp = &s_hT[wv * 32 + nt * 16 + lc][mt * 16 + qd * 4];
        *(float2*)wp = p0;
        *(float2*)(wp + 2) = p1;
      }
    }
    __syncthreads();

    // ---- segmented column-sum: thread = (col jcol, row-half r0) ----
    {
      float2 v[16];
      #pragma unroll
      for (int c = 0; c < 16; c++)
        v[c] = *(const float2*)&s_hT[jcol][r0 + c * 2];
      float acc = 0.0f;
      int cur = s_dst[r0];
      #pragma unroll
      for (int i = 0; i < 32; i++) {
        int m = r0 + i;
        bool bnd = (m < 32) ? ((mlo >> m) & 1u) : ((mhi >> (m - 32)) & 1u);
        if (i > 0 && bnd) {
          atomicAdd(&aggH[(size_t)cur * 256 + hf * 128 + jcol], acc);
          acc = 0.0f;
          cur = s_dst[m];
        }
        acc += (i & 1) ? v[i >> 1].y : v[i >> 1].x;
      }
      atomicAdd(&aggH[(size_t)cur * 256 + hf * 128 + jcol], acc);
    }
    __syncthreads();
  }
}

// ---------------- fused node update MLP: u = [h | s], K=384 (W2 folded in) ----------------
__global__ __launch_bounds__(256, 2) void upd_mfma_kernel(
    float* __restrict__ h, __bf16* __restrict__ hb,
    const float* __restrict__ aggH, const float* __restrict__ degf,
    const __bf16* __restrict__ uW1ft, const float* __restrict__ b1,
    const float* __restrict__ b2u,
    const __bf16* __restrict__ uW2t, const float* __restrict__ b2)
{
  __shared__ __bf16 s_u[64][392];    // 384 + 8 pad
  __shared__ __bf16 s_uh[64][136];
  int tid = threadIdx.x, n0 = blockIdx.x * 64;
  {
    int n = tid >> 2, t4 = tid & 3;
    const bf16x8* hr = (const bf16x8*)(hb + (size_t)(n0 + n) * 128);
    #pragma unroll
    for (int i = 0; i < 4; i++)
      *(bf16x8*)&s_u[n][t4 * 8 + 32 * i] = hr[t4 + 4 * i];
    const float* sr = aggH + (size_t)(n0 + n) * 256;
    #pragma unroll
    for (int i = 0; i < 8; i++) {
      int col = t4 * 8 + i * 32;
      float4 a = *(const float4*)(sr + col);
      float4 b = *(const float4*)(sr + col + 4);
      bf16x8 o;
      o[0] = (__bf16)a.x; o[1] = (__bf16)a.y; o[2] = (__bf16)a.z; o[3] = (__bf16)a.w;
      o[4] = (__bf16)b.x; o[5] = (__bf16)b.y; o[6] = (__bf16)b.z; o[7] = (__bf16)b.w;
      *(bf16x8*)&s_u[n][128 + col] = o;
    }
  }
  __syncthreads();
  const int wv = tid >> 6, ln = tid & 63, lc = ln & 15, qd = ln >> 4;

  float dg[4][4];
  #pragma unroll
  for (int mt = 0; mt < 4; mt++)
    #pragma unroll
    for (int r = 0; r < 4; r++)
      dg[mt][r] = degf[n0 + mt * 16 + qd * 4 + r];

  f32x4 acc2[4][2];
  #pragma unroll
  for (int nt = 0; nt < 2; nt++) {
    float bv = b2[wv * 32 + nt * 16 + lc];
    #pragma unroll
    for (int mt = 0; mt < 4; mt++) {
      acc2[mt][nt][0] = bv; acc2[mt][nt][1] = bv;
      acc2[mt][nt][2] = bv; acc2[mt][nt][3] = bv;
    }
  }

  for (int hf = 0; hf < 2; hf++) {
    f32x4 acc1[4][2];
    #pragma unroll
    for (int nt = 0; nt < 2; nt++) {
      int c = hf * 128 + wv * 32 + nt * 16 + lc;
      float bv = b1[c];
      float b2uv = b2u[c];
      #pragma unroll
      for (int mt = 0; mt < 4; mt++)
        #pragma unroll
        for (int r = 0; r < 4; r++)
          acc1[mt][nt][r] = bv + dg[mt][r] * b2uv;
    }
    #pragma unroll
    for (int kt = 0; kt < 12; kt++) {
      bf16x8 af[4];
      #pragma unroll
      for (int mt = 0; mt < 4; mt++)
        af[mt] = *(const bf16x8*)&s_u[mt * 16 + lc][kt * 32 + qd * 8];
      bf16x8 bw[2];
      #pragma unroll
      for (int nt = 0; nt < 2; nt++)
        bw[nt] = *(const bf16x8*)(uW1ft +
                 (size_t)(hf * 128 + wv * 32 + nt * 16 + lc) * 384 + kt * 32 + qd * 8);
      #pragma unroll
      for (int mt = 0; mt < 4; mt++)
        #pragma unroll
        for (int nt = 0; nt < 2; nt++)
          acc1[mt][nt] = __builtin_amdgcn_mfma_f32_16x16x32_bf16(af[mt], bw[nt], acc1[mt][nt], 0, 0, 0);
    }
    __syncthreads();
    #pragma unroll
    for (int mt = 0; mt < 4; mt++)
      #pragma unroll
      for (int nt = 0; nt < 2; nt++) {
        int cc = wv * 32 + nt * 16 + lc;
        #pragma unroll
        for (int r = 0; r < 4; r++)
          s_uh[mt * 16 + qd * 4 + r][cc] = (__bf16)silu_f(acc1[mt][nt][r]);
      }
    __syncthreads();
    #pragma unroll
    for (int kt = 0; kt < 4; kt++) {
      bf16x8 a2[4];
      #pragma unroll
      for (int mt = 0; mt < 4; mt++)
        a2[mt] = *(const bf16x8*)&s_uh[mt * 16 + lc][kt * 32 + qd * 8];
      bf16x8 b2w[2];
      #pragma unroll
      for (int nt = 0; nt < 2; nt++)
        b2w[nt] = *(const bf16x8*)(uW2t +
                  (size_t)(wv * 32 + nt * 16 + lc) * 256 + hf * 128 + kt * 32 + qd * 8);
      #pragma unroll
      for (int mt = 0; mt < 4; mt++)
        #pragma unroll
        for (int nt = 0; nt < 2; nt++)
          acc2[mt][nt] = __builtin_amdgcn_mfma_f32_16x16x32_bf16(a2[mt], b2w[nt], acc2[mt][nt], 0, 0, 0);
    }
  }

  #pragma unroll
  for (int mt = 0; mt < 4; mt++)
    #pragma unroll
    for (int nt = 0; nt < 2; nt++) {
      int c = wv * 32 + nt * 16 + lc;
      #pragma unroll
      for (int r = 0; r < 4; r++) {
        int n = n0 + mt * 16 + qd * 4 + r;
        float v = h[(size_t)n * 128 + c] + acc2[mt][nt][r];
        h[(size_t)n * 128 + c] = v;
        hb[(size_t)n * 128 + c] = (__bf16)v;
      }
    }
}

// ---------------- readout ----------------
__global__ __launch_bounds__(128) void readout_sum_kernel(
    const float* __restrict__ h, const int* __restrict__ batch,
    float* __restrict__ gsum, float* __restrict__ gcnt)
{
  int j = threadIdx.x;
  int n0 = blockIdx.x * 128;
  float acc = 0.f, cacc = 0.f;
  int cur = batch[n0];
  for (int i = 0; i < 128; i++) {
    int b = batch[n0 + i];
    if (b != cur) {
      atomicAdd(&gsum[cur * 128 + j], acc);
      if (j == 0) atomicAdd(&gcnt[cur], cacc);
      acc = 0.f; cacc = 0.f; cur = b;
    }
    acc += h[(size_t)(n0 + i) * 128 + j];
    cacc += 1.f;
  }
  atomicAdd(&gsum[cur * 128 + j], acc);
  if (j == 0) atomicAdd(&gcnt[cur], cacc);
}

__global__ __launch_bounds__(256) void readout_mlp_kernel(
    const float* __restrict__ gsum, const float* __restrict__ gcnt,
    const float* __restrict__ W1, const float* __restrict__ b1,
    const float* __restrict__ W2, const float* __restrict__ b2,
    float* __restrict__ out)
{
  __shared__ float g[8][128];
  __shared__ float hid[8][256];
  int tid = threadIdx.x;
  for (int i = tid; i < 8 * 128; i += 256) {
    int b = i >> 7, c = i & 127;
    g[b][c] = gsum[i] / fmaxf(gcnt[b], 1.0f);
  }
  __syncthreads();
  {
    float bb = b1[tid];
    float a[8];
    #pragma unroll
    for (int b = 0; b < 8; b++) a[b] = bb;
    for (int k = 0; k < 128; k++) {
      float w = W1[k * 256 + tid];
      #pragma unroll
      for (int b = 0; b < 8; b++) a[b] += g[b][k] * w;
    }
    #pragma unroll
    for (int b = 0; b < 8; b++) hid[b][tid] = silu_f(a[b]);
  }
  __syncthreads();
  int j = tid & 63, bg = tid >> 6;
  float a0 = b2[j], a1 = b2[j];
  for (int k = 0; k < 256; k++) {
    float w = W2[k * 64 + j];
    a0 += hid[bg * 2 + 0][k] * w;
    a1 += hid[bg * 2 + 1][k] * w;
  }
  out[(bg * 2 + 0) * 64 + j] = a0;
  out[(bg * 2 + 1) * 64 + j] = a1;
}

extern "C" void kernel_launch(void* const* d_in, const int* in_sizes, int n_in,
                              void* d_out, int out_size, void* d_ws, size_t ws_size,
                              hipStream_t stream) {
  const float* pos   = (const float*)d_in[0];
  const float* xfeat = (const float*)d_in[1];
  const int*   eidx  = (const int*)d_in[2];
  const int*   batch = (const int*)d_in[3];
  const float* eW1 = (const float*)d_in[4];
  const float* eb1 = (const float*)d_in[5];
  const float* eW2 = (const float*)d_in[6];
  const float* eb2 = (const float*)d_in[7];
  const float* mW1 = (const float*)d_in[8];
  const float* mb1 = (const float*)d_in[9];
  const float* mW2 = (const float*)d_in[10];
  const float* mb2 = (const float*)d_in[11];
  const float* uW1 = (const float*)d_in[12];
  const float* ub1 = (const float*)d_in[13];
  const float* uW2 = (const float*)d_in[14];
  const float* ub2 = (const float*)d_in[15];
  const float* rW1 = (const float*)d_in[16];
  const float* rb1 = (const float*)d_in[17];
  const float* rW2 = (const float*)d_in[18];
  const float* rb2 = (const float*)d_in[19];

  const int* srcI = eidx;
  const int* dstI = eidx + NEDGES;

  char* base = (char*)d_ws;
  float* h    = (float*)base;  base += (size_t)NATOMS * 128 * 4;
  float* aggH = (float*)base;  base += (size_t)NATOMS * 256 * 4;
  __bf16* z1b = (__bf16*)base; base += (size_t)NATOMS * 256 * 2;
  __bf16* z2b = (__bf16*)base; base += (size_t)NATOMS * 256 * 2;
  __bf16* hb  = (__bf16*)base; base += (size_t)NATOMS * 128 * 2;
  __bf16* efb = (__bf16*)base; base += (size_t)NEDGES * 16 * 2;
  __bf16* W1at = (__bf16*)base; base += (size_t)NLAYERS * 256 * 128 * 2;
  __bf16* W1bt = (__bf16*)base; base += (size_t)NLAYERS * 256 * 128 * 2;
  __bf16* B2c  = (__bf16*)base; base += (size_t)NLAYERS * 256 * 32 * 2;
  __bf16* uW1ft = (__bf16*)base; base += (size_t)NLAYERS * 256 * 384 * 2;
  __bf16* uW2t = (__bf16*)base; base += (size_t)NLAYERS * 128 * 256 * 2;
  float* W2u  = (float*)base;  base += (size_t)NLAYERS * 256 * 256 * 4;
  float* b2u  = (float*)base;  base += (size_t)NLAYERS * 256 * 4;
  float* degf = (float*)base;  base += (size_t)NATOMS * 4;
  float* gsum = (float*)base;  base += 8 * 128 * 4;
  float* gcnt = (float*)base;  base += 8 * 4;
  int* counts = (int*)base;    base += (size_t)NATOMS * 4;
  int* cursor = (int*)base;    base += (size_t)NATOMS * 4;
  int* esrc   = (int*)base;    base += (size_t)NEDGES * 4;
  int* edst   = (int*)base;    base += (size_t)NEDGES * 4;

  // --- CSR preprocessing ---
  hipMemsetAsync(counts, 0, NATOMS * sizeof(int), stream);
  hist_kernel<<<NEDGES / 256, 256, 0, stream>>>(dstI, counts);
  scan_kernel<<<1, 1024, 0, stream>>>(counts, cursor);
  scatter_kernel<<<NEDGES / 256, 256, 0, stream>>>(srcI, dstI, cursor, esrc, edst);
  degf_kernel<<<NATOMS / 256, 256, 0, stream>>>(counts, degf);

  // --- weight prep ---
  conv_t_kernel<<<dim3(128, NLAYERS), 256, 0, stream>>>(mW1, W1at, 256,   0, 128, 128, 272L*256, 256L*128);
  conv_t_kernel<<<dim3(128, NLAYERS), 256, 0, stream>>>(mW1, W1bt, 256, 128, 128, 128, 272L*256, 256L*128);
  build_b2c_kernel<<<dim3(32, NLAYERS), 256, 0, stream>>>(mW1, B2c);
  w2u_kernel<<<dim3(256, NLAYERS), 256, 0, stream>>>(mW2, uW1, W2u);
  b2u_kernel<<<NLAYERS, 256, 0, stream>>>(mb2, uW1, b2u);
  build_uw1ft_kernel<<<dim3(384, NLAYERS), 256, 0, stream>>>(uW1, W2u, uW1ft);
  conv_t_kernel<<<dim3(128, NLAYERS), 256, 0, stream>>>(uW2, uW2t, 128,   0, 256, 256, 256L*128, 128L*256);

  embed_kernel<<<NATOMS, 128, 0, stream>>>(xfeat, eW1, eb1, eW2, eb2, h, hb);
  rbf_kernel<<<NEDGES / 256, 256, 0, stream>>>(pos, esrc, edst, efb);

  for (int l = 0; l < NLAYERS; l++) {
    zprep_kernel<<<NATOMS / 64, 256, 0, stream>>>(
        hb, mb1 + (size_t)l * 256,
        W1at + (size_t)l * 256 * 128, W1bt + (size_t)l * 256 * 128,
        z1b, z2b, aggH);
    msg_mfma_kernel<<<NEDGES / TE, 256, 0, stream>>>(
        z1b, z2b, efb, esrc, edst,
        B2c + (size_t)l * 256 * 32, aggH);
    upd_mfma_kernel<<<NATOMS / 64, 256, 0, stream>>>(
        h, hb, aggH, degf,
        uW1ft + (size_t)l * 256 * 384, ub1 + (size_t)l * 256,
        b2u + (size_t)l * 256,
        uW2t + (size_t)l * 128 * 256, ub2 + (size_t)l * 128);
  }

  hipMemsetAsync(gsum, 0, (8 * 128 + 8) * sizeof(float), stream);
  readout_sum_kernel<<<NATOMS / 128, 128, 0, stream>>>(h, batch, gsum, gcnt);
  readout_mlp_kernel<<<1, 256, 0, stream>>>(gsum, gcnt, rW1, rb1, rW2, rb2,
                                            (float*)d_out);
}

// Round 8
// 715.031 us; speedup vs baseline: 15.1494x; 1.1431x over previous
//
#include <hip/hip_runtime.h>
#include <math.h>

#define NATOMS 16384
#define NEDGES 524288
#define NLAYERS 4
#define TE 64      // edges per block in msg kernel

typedef __bf16 bf16x8 __attribute__((ext_vector_type(8)));
typedef __bf16 bf16x4 __attribute__((ext_vector_type(4)));
typedef float f32x4 __attribute__((ext_vector_type(4)));

// fast silu: x * rcp(1+exp(-x))  (v_exp + v_rcp, no IEEE div sequence)
__device__ __forceinline__ float silu_f(float x) {
  return x * __builtin_amdgcn_rcpf(1.0f + __expf(-x));
}

// ---------------- CSR preprocessing ----------------
__global__ __launch_bounds__(256) void hist_kernel(
    const int* __restrict__ dst, int* __restrict__ counts)
{
  int e = blockIdx.x * 256 + threadIdx.x;
  atomicAdd(&counts[dst[e]], 1);
}

__global__ __launch_bounds__(1024) void scan_kernel(
    const int* __restrict__ counts, int* __restrict__ cursor)
{
  __shared__ int buf[1024];
  __shared__ int carry_s;
  int tid = threadIdx.x;
  if (tid == 0) carry_s = 0;
  __syncthreads();
  for (int c = 0; c < 16; c++) {
    int v = counts[c * 1024 + tid];
    buf[tid] = v;
    __syncthreads();
    for (int off = 1; off < 1024; off <<= 1) {
      int t = (tid >= off) ? buf[tid - off] : 0;
      __syncthreads();
      buf[tid] += t;
      __syncthreads();
    }
    cursor[c * 1024 + tid] = buf[tid] - v + carry_s;
    __syncthreads();
    if (tid == 1023) carry_s += buf[1023];
    __syncthreads();
  }
}

__global__ __launch_bounds__(256) void scatter_kernel(
    const int* __restrict__ src, const int* __restrict__ dst,
    int* __restrict__ cursor, int* __restrict__ esrc, int* __restrict__ edst)
{
  int e = blockIdx.x * 256 + threadIdx.x;
  int d = dst[e];
  int p = atomicAdd(&cursor[d], 1);
  esrc[p] = src[e];
  edst[p] = d;
}

__global__ __launch_bounds__(256) void degf_kernel(
    const int* __restrict__ counts, float* __restrict__ degf)
{
  int n = blockIdx.x * 256 + threadIdx.x;
  degf[n] = (float)counts[n];
}

// ---------------- weight prep ----------------
__global__ __launch_bounds__(256) void conv_t_kernel(
    const float* __restrict__ W, __bf16* __restrict__ Wt,
    int ldN, int k0, int Kin, int Kpad, long lsrc, long ldst)
{
  long l = blockIdx.y;
  int i = blockIdx.x * 256 + threadIdx.x;
  int n = i / Kpad, k = i - n * Kpad;
  float v = (k < Kin) ? W[l * lsrc + (size_t)(k0 + k) * ldN + n] : 0.0f;
  Wt[l * ldst + (size_t)n * Kpad + k] = (__bf16)v;
}

// B2c[c][k]: k<16 -> mW1 row (256+k), col c (the ef rows); k>=16 -> 0
__global__ __launch_bounds__(256) void build_b2c_kernel(
    const float* __restrict__ mW1, __bf16* __restrict__ Bc)
{
  long l = blockIdx.y;
  int i = blockIdx.x * 256 + threadIdx.x;  // 256*32
  int c = i >> 5, k = i & 31;
  float v = (k < 16) ? mW1[l * (272L * 256) + (size_t)(256 + k) * 256 + c] : 0.0f;
  Bc[l * (256L * 32) + i] = (__bf16)v;
}

// W2u[l] = mW2[l] (256x128) @ uW1[l][128:256,:] (128x256)  -> fp32 (256x256)
__global__ __launch_bounds__(256) void w2u_kernel(
    const float* __restrict__ mW2, const float* __restrict__ uW1,
    float* __restrict__ W2u)
{
  long l = blockIdx.y;
  int r = blockIdx.x, c = threadIdx.x;
  float acc = 0.0f;
  for (int k = 0; k < 128; k++)
    acc += mW2[(l * 256 + r) * 128 + k] *
           uW1[l * 65536 + (size_t)(128 + k) * 256 + c];
  W2u[(l * 256 + r) * 256 + c] = acc;
}

// b2u[l][c] = sum_k mb2[l][k] * uW1[l][128+k][c]
__global__ __launch_bounds__(256) void b2u_kernel(
    const float* __restrict__ mb2, const float* __restrict__ uW1,
    float* __restrict__ b2u)
{
  long l = blockIdx.x;
  int c = threadIdx.x;
  float acc = 0.0f;
  for (int k = 0; k < 128; k++)
    acc += mb2[l * 128 + k] * uW1[l * 65536 + (size_t)(128 + k) * 256 + c];
  b2u[l * 256 + c] = acc;
}

// uW1ft[l][n][kk] (256 x 384): kk<128 -> uW1[l][kk][n]; else W2u[l][kk-128][n]
__global__ __launch_bounds__(256) void build_uw1ft_kernel(
    const float* __restrict__ uW1, const float* __restrict__ W2u,
    __bf16* __restrict__ Wt)
{
  long l = blockIdx.y;
  int i = blockIdx.x * 256 + threadIdx.x;  // 256*384
  int n = i / 384, k = i - n * 384;
  float v = (k < 128) ? uW1[l * 65536 + (size_t)k * 256 + n]
                      : W2u[l * 65536 + (size_t)(k - 128) * 256 + n];
  Wt[l * (256L * 384) + i] = (__bf16)v;
}

// ---------------- embedding ----------------
__global__ __launch_bounds__(128) void embed_kernel(
    const float* __restrict__ x, const float* __restrict__ W1,
    const float* __restrict__ b1, const float* __restrict__ W2,
    const float* __restrict__ b2, float* __restrict__ h,
    __bf16* __restrict__ hb)
{
  int n = blockIdx.x;
  int j = threadIdx.x;
  __shared__ float xs[26];
  __shared__ float hid[128];
  if (j < 26) xs[j] = x[n * 26 + j];
  __syncthreads();
  float acc = b1[j];
  #pragma unroll
  for (int k = 0; k < 26; k++) acc += xs[k] * W1[k * 128 + j];
  hid[j] = silu_f(acc);
  __syncthreads();
  float acc2 = b2[j];
  #pragma unroll 8
  for (int k = 0; k < 128; k++) acc2 += hid[k] * W2[k * 128 + j];
  h[(size_t)n * 128 + j] = acc2;
  hb[(size_t)n * 128 + j] = (__bf16)acc2;
}

// ---------------- edge RBF (sorted slot order) ----------------
__global__ __launch_bounds__(256) void rbf_kernel(
    const float* __restrict__ pos, const int* __restrict__ esrc,
    const int* __restrict__ edst, __bf16* __restrict__ efb)
{
  int e = blockIdx.x * 256 + threadIdx.x;
  int s = esrc[e], d = edst[e];
  float dx = pos[d * 3 + 0] - pos[s * 3 + 0];
  float dy = pos[d * 3 + 1] - pos[s * 3 + 1];
  float dz = pos[d * 3 + 2] - pos[s * 3 + 2];
  float dist = sqrtf(dx * dx + dy * dy + dz * dz + 1e-12f);
  float env = (dist < 10.0f)
                  ? 0.5f * (cosf(3.14159265358979f * dist * 0.1f) + 1.0f)
                  : 0.0f;
  bf16x8 o0, o1;
  #pragma unroll
  for (int i = 0; i < 16; i++) {
    float c = (10.0f / 15.0f) * (float)i;
    float t = dist - c;
    float v = env * __expf(-t * t * 1.28f);
    if (i < 8) o0[i] = (__bf16)v; else o1[i - 8] = (__bf16)v;
  }
  *(bf16x8*)(efb + (size_t)e * 16 + 0) = o0;
  *(bf16x8*)(efb + (size_t)e * 16 + 8) = o1;
}

// ---------------- zprep (layer 0 only): z1b, z2b; zeros aggH ----------------
__global__ __launch_bounds__(256) void zprep_kernel(
    const __bf16* __restrict__ hb, const float* __restrict__ b1,
    const __bf16* __restrict__ W1at, const __bf16* __restrict__ W1bt,
    __bf16* __restrict__ z1b, __bf16* __restrict__ z2b, float* __restrict__ aggH)
{
  __shared__ __bf16 s_n[64][136];
  int tid = threadIdx.x, n0 = blockIdx.x * 64;
  {
    int n = tid >> 2, t4 = tid & 3;
    const bf16x8* hr = (const bf16x8*)(hb + (size_t)(n0 + n) * 128);
    #pragma unroll
    for (int i = 0; i < 4; i++)
      *(bf16x8*)&s_n[n][t4 * 8 + 32 * i] = hr[t4 + 4 * i];
  }
  {
    float4 zz = make_float4(0.f, 0.f, 0.f, 0.f);
    float4* ap = (float4*)(aggH + (size_t)n0 * 256);
    for (int i = tid; i < 64 * 256 / 4; i += 256) ap[i] = zz;
  }
  __syncthreads();
  const int wv = tid >> 6, ln = tid & 63, lc = ln & 15, qd = ln >> 4;
  for (int cp = 0; cp < 2; cp++) {
    f32x4 aA[4][2], aB[4][2];
    #pragma unroll
    for (int nt = 0; nt < 2; nt++) {
      float bv = b1[cp * 128 + wv * 32 + nt * 16 + lc];
      #pragma unroll
      for (int mt = 0; mt < 4; mt++) {
        aA[mt][nt][0] = 0.f; aA[mt][nt][1] = 0.f;
        aA[mt][nt][2] = 0.f; aA[mt][nt][3] = 0.f;
        aB[mt][nt][0] = bv; aB[mt][nt][1] = bv;
        aB[mt][nt][2] = bv; aB[mt][nt][3] = bv;
      }
    }
    #pragma unroll
    for (int kt = 0; kt < 4; kt++) {
      bf16x8 af[4];
      #pragma unroll
      for (int mt = 0; mt < 4; mt++)
        af[mt] = *(const bf16x8*)&s_n[mt * 16 + lc][kt * 32 + qd * 8];
      bf16x8 bwA[2], bwB[2];
      #pragma unroll
      for (int nt = 0; nt < 2; nt++) {
        int c = cp * 128 + wv * 32 + nt * 16 + lc;
        bwA[nt] = *(const bf16x8*)(W1at + (size_t)c * 128 + kt * 32 + qd * 8);
        bwB[nt] = *(const bf16x8*)(W1bt + (size_t)c * 128 + kt * 32 + qd * 8);
      }
      #pragma unroll
      for (int mt = 0; mt < 4; mt++)
        #pragma unroll
        for (int nt = 0; nt < 2; nt++) {
          aA[mt][nt] = __builtin_amdgcn_mfma_f32_16x16x32_bf16(af[mt], bwA[nt], aA[mt][nt], 0, 0, 0);
          aB[mt][nt] = __builtin_amdgcn_mfma_f32_16x16x32_bf16(af[mt], bwB[nt], aB[mt][nt], 0, 0, 0);
        }
    }
    #pragma unroll
    for (int mt = 0; mt < 4; mt++)
      #pragma unroll
      for (int nt = 0; nt < 2; nt++) {
        int c = cp * 128 + wv * 32 + nt * 16 + lc;
        #pragma unroll
        for (int r = 0; r < 4; r++) {
          int n = n0 + mt * 16 + qd * 4 + r;
          z1b[(size_t)n * 256 + c] = (__bf16)aA[mt][nt][r];
          z2b[(size_t)n * 256 + c] = (__bf16)aB[mt][nt][r];
        }
      }
  }
}

// ---------------- fused message kernel v5 (unchanged structure, fast silu) ----------------
#define MS_EF_OFF   33792
#define MS_SRC_OFF  36864
#define MS_DST_OFF  37120
#define MS_MASK_OFF 37376
#define MS_BYTES    37392

__global__ __launch_bounds__(256, 4) void msg_mfma_kernel(
    const __bf16* __restrict__ z1b, const __bf16* __restrict__ z2b,
    const __bf16* __restrict__ efb,
    const int* __restrict__ esrc, const int* __restrict__ edst,
    const __bf16* __restrict__ B2c, float* __restrict__ aggH)
{
  __shared__ __align__(16) char smem[MS_BYTES];
  float (*s_hT)[66] = (float(*)[66])(smem);            // [128 cols][64 rows + 2 pad]
  __bf16 (*s_ef)[24] = (__bf16(*)[24])(smem + MS_EF_OFF);
  int* s_src = (int*)(smem + MS_SRC_OFF);
  int* s_dst = (int*)(smem + MS_DST_OFF);
  unsigned int* s_mask = (unsigned int*)(smem + MS_MASK_OFF);

  int tid = threadIdx.x, e0 = blockIdx.x * TE;

  if (tid < TE) {
    int d = edst[e0 + tid];
    s_dst[tid] = d;
    int dp = (tid == 0) ? (d ^ 1) : edst[e0 + tid - 1];
    unsigned long long mb = __ballot(d != dp);
    if (tid == 0) { s_mask[0] = (unsigned int)mb; s_mask[1] = (unsigned int)(mb >> 32); }
  } else if (tid < 2 * TE) {
    s_src[tid - TE] = esrc[e0 + tid - TE];
  }
  {
    int e = tid >> 2, t4 = tid & 3;
    if (t4 < 2)
      *(bf16x8*)&s_ef[e][t4 * 8] =
          *(const bf16x8*)(efb + (size_t)(e0 + e) * 16 + t4 * 8);
  }
  __syncthreads();

  const int wv = tid >> 6, ln = tid & 63, lc = ln & 15, qd = ln >> 4;
  const unsigned int mlo = __builtin_amdgcn_readfirstlane(s_mask[0]);
  const unsigned int mhi = __builtin_amdgcn_readfirstlane(s_mask[1]);

  bf16x8 bI;
  #pragma unroll
  for (int j = 0; j < 8; j++)
    bI[j] = (__bf16)((lc == (qd & 1) * 8 + j) ? 1.0f : 0.0f);

  const __bf16* pz[4];
  #pragma unroll
  for (int mt = 0; mt < 4; mt++) {
    int m = mt * 16 + lc;
    int row = (qd < 2) ? s_src[m] : s_dst[m];
    pz[mt] = ((qd < 2) ? z1b : z2b) + (size_t)row * 256 + (qd & 1) * 8;
  }
  const int jcol = tid & 127, r0 = (tid >> 7) * 32;

  for (int hf = 0; hf < 2; hf++) {
    const int cb = hf * 128 + wv * 32;
    bf16x8 bw[2];
    #pragma unroll
    for (int nt = 0; nt < 2; nt++)
      bw[nt] = *(const bf16x8*)(B2c + (size_t)(cb + nt * 16 + lc) * 32 + qd * 8);

    #pragma unroll
    for (int mt = 0; mt < 4; mt++) {
      bf16x8 aef = *(const bf16x8*)&s_ef[mt * 16 + lc][(qd & 1) * 8];
      #pragma unroll
      for (int nt = 0; nt < 2; nt++) {
        bf16x8 az = *(const bf16x8*)(pz[mt] + cb + nt * 16);
        f32x4 z; z[0] = 0.f; z[1] = 0.f; z[2] = 0.f; z[3] = 0.f;
        f32x4 acc = __builtin_amdgcn_mfma_f32_16x16x32_bf16(az, bI, z, 0, 0, 0);
        acc = __builtin_amdgcn_mfma_f32_16x16x32_bf16(aef, bw[nt], acc, 0, 0, 0);
        float2 p0, p1;
        p0.x = silu_f(acc[0]); p0.y = silu_f(acc[1]);
        p1.x = silu_f(acc[2]); p1.y = silu_f(acc[3]);
        float* wp = &s_hT[wv * 32 + nt * 16 + lc][mt * 16 + qd * 4];
        *(float2*)wp = p0;
        *(float2*)(wp + 2) = p1;
      }
    }
    __syncthreads();

    {
      float2 v[16];
      #pragma unroll
      for (int c = 0; c < 16; c++)
        v[c] = *(const float2*)&s_hT[jcol][r0 + c * 2];
      float acc = 0.0f;
      int cur = s_dst[r0];
      #pragma unroll
      for (int i = 0; i < 32; i++) {
        int m = r0 + i;
        bool bnd = (m < 32) ? ((mlo >> m) & 1u) : ((mhi >> (m - 32)) & 1u);
        if (i > 0 && bnd) {
          atomicAdd(&aggH[(size_t)cur * 256 + hf * 128 + jcol], acc);
          acc = 0.0f;
          cur = s_dst[m];
        }
        acc += (i & 1) ? v[i >> 1].y : v[i >> 1].x;
      }
      atomicAdd(&aggH[(size_t)cur * 256 + hf * 128 + jcol], acc);
    }
    __syncthreads();
  }
}

// ---------------- fused node update MLP + next-layer zprep ----------------
__global__ __launch_bounds__(256, 2) void upd_mfma_kernel(
    float* __restrict__ h, __bf16* __restrict__ hb,
    float* __restrict__ aggH, const float* __restrict__ degf,
    const __bf16* __restrict__ uW1ft, const float* __restrict__ b1,
    const float* __restrict__ b2u,
    const __bf16* __restrict__ uW2t, const float* __restrict__ b2,
    int do_z, const float* __restrict__ nb1,
    const __bf16* __restrict__ nW1at, const __bf16* __restrict__ nW1bt,
    __bf16* __restrict__ z1b, __bf16* __restrict__ z2b)
{
  __shared__ __bf16 s_u[64][392];    // 384 + 8 pad
  __shared__ __bf16 s_uh[64][136];
  int tid = threadIdx.x, n0 = blockIdx.x * 64;
  {
    int n = tid >> 2, t4 = tid & 3;
    const bf16x8* hr = (const bf16x8*)(hb + (size_t)(n0 + n) * 128);
    #pragma unroll
    for (int i = 0; i < 4; i++)
      *(bf16x8*)&s_u[n][t4 * 8 + 32 * i] = hr[t4 + 4 * i];
    const float* sr = aggH + (size_t)(n0 + n) * 256;
    #pragma unroll
    for (int i = 0; i < 8; i++) {
      int col = t4 * 8 + i * 32;
      float4 a = *(const float4*)(sr + col);
      float4 b = *(const float4*)(sr + col + 4);
      bf16x8 o;
      o[0] = (__bf16)a.x; o[1] = (__bf16)a.y; o[2] = (__bf16)a.z; o[3] = (__bf16)a.w;
      o[4] = (__bf16)b.x; o[5] = (__bf16)b.y; o[6] = (__bf16)b.z; o[7] = (__bf16)b.w;
      *(bf16x8*)&s_u[n][128 + col] = o;
    }
  }
  __syncthreads();
  const int wv = tid >> 6, ln = tid & 63, lc = ln & 15, qd = ln >> 4;

  float dg[4][4];
  #pragma unroll
  for (int mt = 0; mt < 4; mt++)
    #pragma unroll
    for (int r = 0; r < 4; r++)
      dg[mt][r] = degf[n0 + mt * 16 + qd * 4 + r];

  f32x4 acc2[4][2];
  #pragma unroll
  for (int nt = 0; nt < 2; nt++) {
    float bv = b2[wv * 32 + nt * 16 + lc];
    #pragma unroll
    for (int mt = 0; mt < 4; mt++) {
      acc2[mt][nt][0] = bv; acc2[mt][nt][1] = bv;
      acc2[mt][nt][2] = bv; acc2[mt][nt][3] = bv;
    }
  }

  for (int hf = 0; hf < 2; hf++) {
    f32x4 acc1[4][2];
    #pragma unroll
    for (int nt = 0; nt < 2; nt++) {
      int c = hf * 128 + wv * 32 + nt * 16 + lc;
      float bv = b1[c];
      float b2uv = b2u[c];
      #pragma unroll
      for (int mt = 0; mt < 4; mt++)
        #pragma unroll
        for (int r = 0; r < 4; r++)
          acc1[mt][nt][r] = bv + dg[mt][r] * b2uv;
    }
    #pragma unroll
    for (int kt = 0; kt < 12; kt++) {
      bf16x8 af[4];
      #pragma unroll
      for (int mt = 0; mt < 4; mt++)
        af[mt] = *(const bf16x8*)&s_u[mt * 16 + lc][kt * 32 + qd * 8];
      bf16x8 bw[2];
      #pragma unroll
      for (int nt = 0; nt < 2; nt++)
        bw[nt] = *(const bf16x8*)(uW1ft +
                 (size_t)(hf * 128 + wv * 32 + nt * 16 + lc) * 384 + kt * 32 + qd * 8);
      #pragma unroll
      for (int mt = 0; mt < 4; mt++)
        #pragma unroll
        for (int nt = 0; nt < 2; nt++)
          acc1[mt][nt] = __builtin_amdgcn_mfma_f32_16x16x32_bf16(af[mt], bw[nt], acc1[mt][nt], 0, 0, 0);
    }
    __syncthreads();
    #pragma unroll
    for (int mt = 0; mt < 4; mt++)
      #pragma unroll
      for (int nt = 0; nt < 2; nt++) {
        int cc = wv * 32 + nt * 16 + lc;
        #pragma unroll
        for (int r = 0; r < 4; r++)
          s_uh[mt * 16 + qd * 4 + r][cc] = (__bf16)silu_f(acc1[mt][nt][r]);
      }
    __syncthreads();
    #pragma unroll
    for (int kt = 0; kt < 4; kt++) {
      bf16x8 a2[4];
      #pragma unroll
      for (int mt = 0; mt < 4; mt++)
        a2[mt] = *(const bf16x8*)&s_uh[mt * 16 + lc][kt * 32 + qd * 8];
      bf16x8 b2w[2];
      #pragma unroll
      for (int nt = 0; nt < 2; nt++)
        b2w[nt] = *(const bf16x8*)(uW2t +
                  (size_t)(wv * 32 + nt * 16 + lc) * 256 + hf * 128 + kt * 32 + qd * 8);
      #pragma unroll
      for (int mt = 0; mt < 4; mt++)
        #pragma unroll
        for (int nt = 0; nt < 2; nt++)
          acc2[mt][nt] = __builtin_amdgcn_mfma_f32_16x16x32_bf16(a2[mt], b2w[nt], acc2[mt][nt], 0, 0, 0);
    }
  }

  // residual epilogue: write h (fp32) + hb (bf16)
  #pragma unroll
  for (int mt = 0; mt < 4; mt++)
    #pragma unroll
    for (int nt = 0; nt < 2; nt++) {
      int c = wv * 32 + nt * 16 + lc;
      #pragma unroll
      for (int r = 0; r < 4; r++) {
        int n = n0 + mt * 16 + qd * 4 + r;
        float v = h[(size_t)n * 128 + c] + acc2[mt][nt][r];
        h[(size_t)n * 128 + c] = v;
        hb[(size_t)n * 128 + c] = (__bf16)v;
      }
    }

  // ---- fused zprep for next layer ----
  if (do_z) {
    __syncthreads();   // drains vmem (hb writes visible within block), all s_u reads done
    {
      // zero our aggH rows for the next layer
      float4 zz = make_float4(0.f, 0.f, 0.f, 0.f);
      float4* ap = (float4*)(aggH + (size_t)n0 * 256);
      for (int i = tid; i < 64 * 256 / 4; i += 256) ap[i] = zz;
      // restage fresh hb (L1-hot) into s_u cols 0..127
      int n = tid >> 2, t4 = tid & 3;
      const bf16x8* hr = (const bf16x8*)(hb + (size_t)(n0 + n) * 128);
      #pragma unroll
      for (int i = 0; i < 4; i++)
        *(bf16x8*)&s_u[n][t4 * 8 + 32 * i] = hr[t4 + 4 * i];
    }
    __syncthreads();
    for (int cp = 0; cp < 2; cp++) {
      f32x4 aA[4][2], aB[4][2];
      #pragma unroll
      for (int nt = 0; nt < 2; nt++) {
        float bv = nb1[cp * 128 + wv * 32 + nt * 16 + lc];
        #pragma unroll
        for (int mt = 0; mt < 4; mt++) {
          aA[mt][nt][0] = 0.f; aA[mt][nt][1] = 0.f;
          aA[mt][nt][2] = 0.f; aA[mt][nt][3] = 0.f;
          aB[mt][nt][0] = bv; aB[mt][nt][1] = bv;
          aB[mt][nt][2] = bv; aB[mt][nt][3] = bv;
        }
      }
      #pragma unroll
      for (int kt = 0; kt < 4; kt++) {
        bf16x8 af[4];
        #pragma unroll
        for (int mt = 0; mt < 4; mt++)
          af[mt] = *(const bf16x8*)&s_u[mt * 16 + lc][kt * 32 + qd * 8];
        bf16x8 bwA[2], bwB[2];
        #pragma unroll
        for (int nt = 0; nt < 2; nt++) {
          int c = cp * 128 + wv * 32 + nt * 16 + lc;
          bwA[nt] = *(const bf16x8*)(nW1at + (size_t)c * 128 + kt * 32 + qd * 8);
          bwB[nt] = *(const bf16x8*)(nW1bt + (size_t)c * 128 + kt * 32 + qd * 8);
        }
        #pragma unroll
        for (int mt = 0; mt < 4; mt++)
          #pragma unroll
          for (int nt = 0; nt < 2; nt++) {
            aA[mt][nt] = __builtin_amdgcn_mfma_f32_16x16x32_bf16(af[mt], bwA[nt], aA[mt][nt], 0, 0, 0);
            aB[mt][nt] = __builtin_amdgcn_mfma_f32_16x16x32_bf16(af[mt], bwB[nt], aB[mt][nt], 0, 0, 0);
          }
      }
      #pragma unroll
      for (int mt = 0; mt < 4; mt++)
        #pragma unroll
        for (int nt = 0; nt < 2; nt++) {
          int c = cp * 128 + wv * 32 + nt * 16 + lc;
          #pragma unroll
          for (int r = 0; r < 4; r++) {
            int n = n0 + mt * 16 + qd * 4 + r;
            z1b[(size_t)n * 256 + c] = (__bf16)aA[mt][nt][r];
            z2b[(size_t)n * 256 + c] = (__bf16)aB[mt][nt][r];
          }
        }
    }
  }
}

// ---------------- readout ----------------
__global__ __launch_bounds__(128) void readout_sum_kernel(
    const float* __restrict__ h, const int* __restrict__ batch,
    float* __restrict__ gsum, float* __restrict__ gcnt)
{
  int j = threadIdx.x;
  int n0 = blockIdx.x * 128;
  float acc = 0.f, cacc = 0.f;
  int cur = batch[n0];
  for (int i = 0; i < 128; i++) {
    int b = batch[n0 + i];
    if (b != cur) {
      atomicAdd(&gsum[cur * 128 + j], acc);
      if (j == 0) atomicAdd(&gcnt[cur], cacc);
      acc = 0.f; cacc = 0.f; cur = b;
    }
    acc += h[(size_t)(n0 + i) * 128 + j];
    cacc += 1.f;
  }
  atomicAdd(&gsum[cur * 128 + j], acc);
  if (j == 0) atomicAdd(&gcnt[cur], cacc);
}

__global__ __launch_bounds__(256) void readout_mlp_kernel(
    const float* __restrict__ gsum, const float* __restrict__ gcnt,
    const float* __restrict__ W1, const float* __restrict__ b1,
    const float* __restrict__ W2, const float* __restrict__ b2,
    float* __restrict__ out)
{
  __shared__ float g[8][128];
  __shared__ float hid[8][256];
  int tid = threadIdx.x;
  for (int i = tid; i < 8 * 128; i += 256) {
    int b = i >> 7, c = i & 127;
    g[b][c] = gsum[i] / fmaxf(gcnt[b], 1.0f);
  }
  __syncthreads();
  {
    float bb = b1[tid];
    float a[8];
    #pragma unroll
    for (int b = 0; b < 8; b++) a[b] = bb;
    for (int k = 0; k < 128; k++) {
      float w = W1[k * 256 + tid];
      #pragma unroll
      for (int b = 0; b < 8; b++) a[b] += g[b][k] * w;
    }
    #pragma unroll
    for (int b = 0; b < 8; b++) hid[b][tid] = silu_f(a[b]);
  }
  __syncthreads();
  int j = tid & 63, bg = tid >> 6;
  float a0 = b2[j], a1 = b2[j];
  for (int k = 0; k < 256; k++) {
    float w = W2[k * 64 + j];
    a0 += hid[bg * 2 + 0][k] * w;
    a1 += hid[bg * 2 + 1][k] * w;
  }
  out[(bg * 2 + 0) * 64 + j] = a0;
  out[(bg * 2 + 1) * 64 + j] = a1;
}

extern "C" void kernel_launch(void* const* d_in, const int* in_sizes, int n_in,
                              void* d_out, int out_size, void* d_ws, size_t ws_size,
                              hipStream_t stream) {
  const float* pos   = (const float*)d_in[0];
  const float* xfeat = (const float*)d_in[1];
  const int*   eidx  = (const int*)d_in[2];
  const int*   batch = (const int*)d_in[3];
  const float* eW1 = (const float*)d_in[4];
  const float* eb1 = (const float*)d_in[5];
  const float* eW2 = (const float*)d_in[6];
  const float* eb2 = (const float*)d_in[7];
  const float* mW1 = (const float*)d_in[8];
  const float* mb1 = (const float*)d_in[9];
  const float* mW2 = (const float*)d_in[10];
  const float* mb2 = (const float*)d_in[11];
  const float* uW1 = (const float*)d_in[12];
  const float* ub1 = (const float*)d_in[13];
  const float* uW2 = (const float*)d_in[14];
  const float* ub2 = (const float*)d_in[15];
  const float* rW1 = (const float*)d_in[16];
  const float* rb1 = (const float*)d_in[17];
  const float* rW2 = (const float*)d_in[18];
  const float* rb2 = (const float*)d_in[19];

  const int* srcI = eidx;
  const int* dstI = eidx + NEDGES;

  char* base = (char*)d_ws;
  float* h    = (float*)base;  base += (size_t)NATOMS * 128 * 4;
  float* aggH = (float*)base;  base += (size_t)NATOMS * 256 * 4;
  __bf16* z1b = (__bf16*)base; base += (size_t)NATOMS * 256 * 2;
  __bf16* z2b = (__bf16*)base; base += (size_t)NATOMS * 256 * 2;
  __bf16* hb  = (__bf16*)base; base += (size_t)NATOMS * 128 * 2;
  __bf16* efb = (__bf16*)base; base += (size_t)NEDGES * 16 * 2;
  __bf16* W1at = (__bf16*)base; base += (size_t)NLAYERS * 256 * 128 * 2;
  __bf16* W1bt = (__bf16*)base; base += (size_t)NLAYERS * 256 * 128 * 2;
  __bf16* B2c  = (__bf16*)base; base += (size_t)NLAYERS * 256 * 32 * 2;
  __bf16* uW1ft = (__bf16*)base; base += (size_t)NLAYERS * 256 * 384 * 2;
  __bf16* uW2t = (__bf16*)base; base += (size_t)NLAYERS * 128 * 256 * 2;
  float* W2u  = (float*)base;  base += (size_t)NLAYERS * 256 * 256 * 4;
  float* b2u  = (float*)base;  base += (size_t)NLAYERS * 256 * 4;
  float* degf = (float*)base;  base += (size_t)NATOMS * 4;
  float* gsum = (float*)base;  base += 8 * 128 * 4;
  float* gcnt = (float*)base;  base += 8 * 4;
  int* counts = (int*)base;    base += (size_t)NATOMS * 4;
  int* cursor = (int*)base;    base += (size_t)NATOMS * 4;
  int* esrc   = (int*)base;    base += (size_t)NEDGES * 4;
  int* edst   = (int*)base;    base += (size_t)NEDGES * 4;

  // --- CSR preprocessing ---
  hipMemsetAsync(counts, 0, NATOMS * sizeof(int), stream);
  hist_kernel<<<NEDGES / 256, 256, 0, stream>>>(dstI, counts);
  scan_kernel<<<1, 1024, 0, stream>>>(counts, cursor);
  scatter_kernel<<<NEDGES / 256, 256, 0, stream>>>(srcI, dstI, cursor, esrc, edst);
  degf_kernel<<<NATOMS / 256, 256, 0, stream>>>(counts, degf);

  // --- weight prep ---
  conv_t_kernel<<<dim3(128, NLAYERS), 256, 0, stream>>>(mW1, W1at, 256,   0, 128, 128, 272L*256, 256L*128);
  conv_t_kernel<<<dim3(128, NLAYERS), 256, 0, stream>>>(mW1, W1bt, 256, 128, 128, 128, 272L*256, 256L*128);
  build_b2c_kernel<<<dim3(32, NLAYERS), 256, 0, stream>>>(mW1, B2c);
  w2u_kernel<<<dim3(256, NLAYERS), 256, 0, stream>>>(mW2, uW1, W2u);
  b2u_kernel<<<NLAYERS, 256, 0, stream>>>(mb2, uW1, b2u);
  build_uw1ft_kernel<<<dim3(384, NLAYERS), 256, 0, stream>>>(uW1, W2u, uW1ft);
  conv_t_kernel<<<dim3(128, NLAYERS), 256, 0, stream>>>(uW2, uW2t, 128,   0, 256, 256, 256L*128, 128L*256);

  embed_kernel<<<NATOMS, 128, 0, stream>>>(xfeat, eW1, eb1, eW2, eb2, h, hb);
  rbf_kernel<<<NEDGES / 256, 256, 0, stream>>>(pos, esrc, edst, efb);

  // zprep for layer 0 (also zeros aggH)
  zprep_kernel<<<NATOMS / 64, 256, 0, stream>>>(
      hb, mb1, W1at, W1bt, z1b, z2b, aggH);

  for (int l = 0; l < NLAYERS; l++) {
    int ln = (l < NLAYERS - 1) ? (l + 1) : l;
    msg_mfma_kernel<<<NEDGES / TE, 256, 0, stream>>>(
        z1b, z2b, efb, esrc, edst,
        B2c + (size_t)l * 256 * 32, aggH);
    upd_mfma_kernel<<<NATOMS / 64, 256, 0, stream>>>(
        h, hb, aggH, degf,
        uW1ft + (size_t)l * 256 * 384, ub1 + (size_t)l * 256,
        b2u + (size_t)l * 256,
        uW2t + (size_t)l * 128 * 256, ub2 + (size_t)l * 128,
        (l < NLAYERS - 1) ? 1 : 0,
        mb1 + (size_t)ln * 256,
        W1at + (size_t)ln * 256 * 128, W1bt + (size_t)ln * 256 * 128,
        z1b, z2b);
  }

  hipMemsetAsync(gsum, 0, (8 * 128 + 8) * sizeof(float), stream);
  readout_sum_kernel<<<NATOMS / 128, 128, 0, stream>>>(h, batch, gsum, gcnt);
  readout_mlp_kernel<<<1, 256, 0, stream>>>(gsum, gcnt, rW1, rb1, rW2, rb2,
                                            (float*)d_out);
}